// Round 3
// baseline (413.640 us; speedup 1.0000x reference)
//
#include <hip/hip_runtime.h>
#include <hip/hip_fp16.h>

#define NF 128

__device__ __forceinline__ unsigned okey(float f) {
  unsigned u = __float_as_uint(f);
  return (u & 0x80000000u) ? ~u : (u | 0x80000000u);
}

__device__ __forceinline__ uint2 pack_half4(float4 v) {
  __half2 a = __floats2half2_rn(v.x, v.y);
  __half2 b = __floats2half2_rn(v.z, v.w);
  uint2 r;
  r.x = *reinterpret_cast<unsigned*>(&a);
  r.y = *reinterpret_cast<unsigned*>(&b);
  return r;
}

// ---------- prep: 1/||p||, transpose W_lin ----------
__global__ void prep_kernel(const float* __restrict__ p, const float* __restrict__ W_lin,
                            float* __restrict__ pninv, float* __restrict__ wlt) {
  __shared__ float red[128];
  int t = threadIdx.x;  // 256
  if (t < 128) { float v = p[t]; red[t] = v * v; }
  __syncthreads();
  for (int s = 64; s > 0; s >>= 1) {
    if (t < s) red[t] += red[t + s];
    __syncthreads();
  }
  if (t == 0) pninv[0] = 1.0f / sqrtf(red[0]);
  for (int i = t; i < NF * NF; i += 256) {
    int r = i >> 7, c = i & 127;
    wlt[c * NF + r] = W_lin[i];
  }
}

// ---------- scores (one wave per row) + node-array init ----------
__global__ void score_init_kernel(const float* __restrict__ x, const float* __restrict__ p,
                                  const float* __restrict__ pninv, float* __restrict__ score,
                                  unsigned* __restrict__ keys, float* __restrict__ deg,
                                  int* __restrict__ cnt, int n) {
  int wib = threadIdx.x >> 6, lane = threadIdx.x & 63;
  int r = blockIdx.x * 4 + wib;
  if (r >= n) return;
  if (lane == 1) deg[r] = 1.0f;  // self-loop weight
  if (lane == 2) cnt[r] = 0;
  float2 xv = *(const float2*)&x[(size_t)r * NF + lane * 2];
  float2 pv = *(const float2*)&p[lane * 2];
  float d = xv.x * pv.x + xv.y * pv.y;
#pragma unroll
  for (int off = 32; off > 0; off >>= 1) d += __shfl_down(d, off, 64);
  if (lane == 0) {
    float s = tanhf(d * pninv[0]);
    score[r] = s;
    keys[r] = okey(s);
  }
}

// ---------- top-128 radix select + stable sort, single block ----------
#define TK 128
#define LBCAP 2048
__global__ __launch_bounds__(1024) void topk_kernel(const unsigned* __restrict__ keys,
                                                    const float* __restrict__ score, int n,
                                                    int* __restrict__ perm, float* __restrict__ tsc) {
  __shared__ unsigned hist[256];
  __shared__ unsigned sh_prefix;
  __shared__ int sh_remaining;
  __shared__ int cntA, cntB;
  __shared__ unsigned selKey[TK];
  __shared__ int selIdx[TK];
  __shared__ int lbIdx[LBCAP];
  int t = threadIdx.x;
  if (t == 0) { sh_prefix = 0u; sh_remaining = TK; }
  for (int pos = 24; pos >= 0; pos -= 8) {
    if (t < 256) hist[t] = 0u;
    __syncthreads();
    unsigned pref = sh_prefix;
    unsigned hmask = (pos == 24) ? 0u : (0xFFFFFFFFu << (pos + 8));
    for (int i = t; i < n; i += 1024) {
      unsigned k = keys[i];
      if ((k & hmask) == pref) atomicAdd(&hist[(k >> pos) & 255], 1u);
    }
    __syncthreads();
    if (t == 0) {
      int rem = sh_remaining;
      unsigned c = 0;
      for (int b = 255; b >= 0; --b) {
        unsigned h = hist[b];
        if (c + h >= (unsigned)rem) {
          sh_prefix = pref | ((unsigned)b << pos);
          sh_remaining = rem - (int)c;
          break;
        }
        c += h;
      }
    }
    __syncthreads();
  }
  unsigned T = sh_prefix;
  int needEq = sh_remaining;
  if (t == 0) { cntA = 0; cntB = 0; }
  __syncthreads();
  for (int i = t; i < n; i += 1024) {
    unsigned k = keys[i];
    if (k > T) {
      int s = atomicAdd(&cntA, 1);
      if (s < TK) { selKey[s] = k; selIdx[s] = i; }
    } else if (k == T) {
      int s = atomicAdd(&cntB, 1);
      if (s < LBCAP) lbIdx[s] = i;
    }
  }
  __syncthreads();
  int nA = cntA;  // == TK - needEq
  int nb = cntB < LBCAP ? cntB : LBCAP;
  for (int ii = t; ii < nb; ii += 1024) {
    int my = lbIdx[ii];
    int rank = 0;
    for (int j = 0; j < nb; ++j) rank += (lbIdx[j] < my) ? 1 : 0;
    if (rank < needEq) { selKey[nA + rank] = T; selIdx[nA + rank] = my; }
  }
  __syncthreads();
  if (t < TK) {
    unsigned mk = selKey[t];
    int mi = selIdx[t];
    int rank = 0;
    for (int j = 0; j < TK; ++j) {
      unsigned kj = selKey[j];
      int ij = selIdx[j];
      rank += (kj > mk || (kj == mk && ij < mi)) ? 1 : 0;
    }
    perm[rank] = mi;
    tsc[rank] = score[mi];
  }
}

// ---------- GRU: block per row i, thread per col j ----------
__global__ void gru_kernel(const float* __restrict__ x, const int* __restrict__ perm,
                           const float* __restrict__ tsc, const float* __restrict__ W0,
                           const float* __restrict__ w_ih, const float* __restrict__ w_hh,
                           const float* __restrict__ b_ih, const float* __restrict__ b_hh,
                           float* __restrict__ W) {
  __shared__ float xs[NF], w0s[NF];
  int i = blockIdx.x, j = threadIdx.x;
  int pi = perm[i];
  float s = tsc[i];
  xs[j] = x[(size_t)pi * NF + j] * s;
  w0s[j] = W0[i * NF + j];
  __syncthreads();
  float gir = b_ih[j], giz = b_ih[NF + j], gin = b_ih[2 * NF + j];
  float ghr = b_hh[j], ghz = b_hh[NF + j], ghn = b_hh[2 * NF + j];
  const float* wr = w_ih + (size_t)j * NF;
  const float* wz = w_ih + (size_t)(NF + j) * NF;
  const float* wn = w_ih + (size_t)(2 * NF + j) * NF;
  const float* ur = w_hh + (size_t)j * NF;
  const float* uz = w_hh + (size_t)(NF + j) * NF;
  const float* un = w_hh + (size_t)(2 * NF + j) * NF;
#pragma unroll 4
  for (int k = 0; k < NF; ++k) {
    float xv = xs[k], wv = w0s[k];
    gir = fmaf(xv, wr[k], gir);
    giz = fmaf(xv, wz[k], giz);
    gin = fmaf(xv, wn[k], gin);
    ghr = fmaf(wv, ur[k], ghr);
    ghz = fmaf(wv, uz[k], ghz);
    ghn = fmaf(wv, un[k], ghn);
  }
  float r = 1.0f / (1.0f + expf(-(gir + ghr)));
  float z = 1.0f / (1.0f + expf(-(giz + ghz)));
  float nn = tanhf(gin + r * ghn);
  W[i * NF + j] = (1.0f - z) * nn + z * w0s[j];
}

// ---------- histogram of in-degree + weighted degree ----------
__global__ void hist_deg_kernel(const int* __restrict__ ei, const float* __restrict__ ew,
                                int* __restrict__ cnt, float* __restrict__ deg, int E) {
  int e = blockIdx.x * blockDim.x + threadIdx.x;
  if (e < E) {
    int c = ei[E + e];
    atomicAdd(&cnt[c], 1);
    unsafeAtomicAdd(&deg[c], ew[e]);
  }
}

// ---------- exclusive scan over cnt -> off (+ dinv fused) ----------
#define SCAN_B 1024
__global__ __launch_bounds__(1024) void scan1_kernel(const int* __restrict__ cnt,
                                                     int* __restrict__ off,
                                                     int* __restrict__ bsum,
                                                     const float* __restrict__ deg,
                                                     float* __restrict__ dinv, int n) {
  __shared__ int sd[SCAN_B];
  int t = threadIdx.x;
  int i = blockIdx.x * SCAN_B + t;
  if (i < n) {
    float d = deg[i];
    dinv[i] = (d > 0.0f) ? (1.0f / sqrtf(d)) : 0.0f;
  }
  int v = (i < n) ? cnt[i] : 0;
  sd[t] = v;
  __syncthreads();
  for (int s = 1; s < SCAN_B; s <<= 1) {
    int add = (t >= s) ? sd[t - s] : 0;
    __syncthreads();
    sd[t] += add;
    __syncthreads();
  }
  if (i < n) off[i] = sd[t] - v;  // exclusive
  if (t == SCAN_B - 1) bsum[blockIdx.x] = sd[t];
}
__global__ void scan2_kernel(const int* __restrict__ bsum, int* __restrict__ bexc, int nb) {
  if (threadIdx.x == 0 && blockIdx.x == 0) {
    int run = 0;
    for (int b = 0; b < nb; ++b) { bexc[b] = run; run += bsum[b]; }
    bexc[nb] = run;
  }
}
__global__ void scan3_kernel(int* __restrict__ off, const int* __restrict__ bexc,
                             int* __restrict__ cursor, int n, int nb) {
  int i = blockIdx.x * blockDim.x + threadIdx.x;
  if (i < n) {
    int v = off[i] + bexc[i >> 10];
    off[i] = v;
    cursor[i] = v;
  } else if (i == n) {
    off[n] = bexc[nb];
  }
}

// ---------- fill CSR: (row, coef) per incoming edge, grouped by col ----------
__global__ void fill_kernel(const int* __restrict__ ei, const float* __restrict__ ew,
                            const float* __restrict__ dinv, int* __restrict__ cursor,
                            int* __restrict__ erow, float* __restrict__ ecoef, int E) {
  int e = blockIdx.x * blockDim.x + threadIdx.x;
  if (e >= E) return;
  int r = ei[e], c = ei[E + e];
  int pos = atomicAdd(&cursor[c], 1);
  erow[pos] = r;
  ecoef[pos] = dinv[r] * ew[e] * dinv[c];
}

// ---------- aggregate: one wave per node, fp16 gather, atomic-free ----------
__global__ void aggregate_kernel(const int* __restrict__ erow, const float* __restrict__ ecoef,
                                 const int* __restrict__ off, const float* __restrict__ dinv,
                                 const unsigned* __restrict__ xwh, float* __restrict__ h, int n) {
  int w = (int)((blockIdx.x * (size_t)blockDim.x + threadIdx.x) >> 6);
  int lane = threadIdx.x & 63;
  if (w >= n) return;
  int n0 = off[w], n1 = off[w + 1];
  float dv = dinv[w];
  float c2 = dv * dv;  // self-loop: dinv[i]*1.0*dinv[i]
  unsigned su = xwh[(size_t)w * 64 + lane];
  float2 sv = __half22float2(*reinterpret_cast<__half2*>(&su));
  float2 acc = make_float2(c2 * sv.x, c2 * sv.y);
  for (int e = n0; e < n1; ++e) {
    int r = erow[e];
    float cf = ecoef[e];
    unsigned u = xwh[(size_t)r * 64 + lane];
    float2 v = __half22float2(*reinterpret_cast<__half2*>(&u));
    acc.x = fmaf(cf, v.x, acc.x);
    acc.y = fmaf(cf, v.y, acc.y);
  }
  *(float2*)&h[(size_t)w * NF + lane * 2] = acc;
}

// ---------- GEMM: C[r,c] = sum_k op(A[r,k]) * B[k,c] (+bias), B is 128x128 ----------
template <int RELU, int BIAS, int HOUT>
__global__ __launch_bounds__(256) void gemm128_kernel(const float* __restrict__ A,
                                                      const float* __restrict__ Bm,
                                                      const float* __restrict__ bias,
                                                      float* __restrict__ C, int nrows) {
  __shared__ float Bs[64][128];
  __shared__ float As[64][68];  // [k][r], padded
  const int t = threadIdx.x;
  const int ct = t & 31;   // 4-col group
  const int rt = t >> 5;   // 0..7 -> rows rt*8..rt*8+7
  const int row0 = blockIdx.x * 64;
  float4 acc[8];
#pragma unroll
  for (int j = 0; j < 8; ++j) acc[j] = make_float4(0.f, 0.f, 0.f, 0.f);

  for (int ph = 0; ph < 2; ++ph) {
    {
      const float4* B4 = (const float4*)(Bm + ph * 64 * NF);
#pragma unroll
      for (int pp = 0; pp < 8; ++pp) {
        int idx = pp * 256 + t;  // 0..2047
        int k = idx >> 5, c4 = idx & 31;
        *((float4*)&Bs[k][c4 * 4]) = B4[idx];
      }
    }
    {
#pragma unroll
      for (int pp = 0; pp < 4; ++pp) {
        int idx = pp * 256 + t;  // 0..1023
        int r = idx >> 4;        // 0..63
        int k4 = idx & 15;       // col group
        int gr = row0 + r;
        float4 v = make_float4(0.f, 0.f, 0.f, 0.f);
        if (gr < nrows) v = *((const float4*)&A[(size_t)gr * NF + ph * 64 + k4 * 4]);
        if (RELU) {
          v.x = fmaxf(v.x, 0.f); v.y = fmaxf(v.y, 0.f);
          v.z = fmaxf(v.z, 0.f); v.w = fmaxf(v.w, 0.f);
        }
        As[k4 * 4 + 0][r] = v.x;
        As[k4 * 4 + 1][r] = v.y;
        As[k4 * 4 + 2][r] = v.z;
        As[k4 * 4 + 3][r] = v.w;
      }
    }
    __syncthreads();
#pragma unroll 4
    for (int k = 0; k < 64; ++k) {
      float4 b = *((const float4*)&Bs[k][ct * 4]);
      float a[8];
      *((float4*)&a[0]) = *((const float4*)&As[k][rt * 8]);
      *((float4*)&a[4]) = *((const float4*)&As[k][rt * 8 + 4]);
#pragma unroll
      for (int j = 0; j < 8; ++j) {
        acc[j].x = fmaf(a[j], b.x, acc[j].x);
        acc[j].y = fmaf(a[j], b.y, acc[j].y);
        acc[j].z = fmaf(a[j], b.z, acc[j].z);
        acc[j].w = fmaf(a[j], b.w, acc[j].w);
      }
    }
    __syncthreads();
  }
  float4 bv = make_float4(0.f, 0.f, 0.f, 0.f);
  if (BIAS) bv = *((const float4*)&bias[ct * 4]);
#pragma unroll
  for (int j = 0; j < 8; ++j) {
    int gr = row0 + rt * 8 + j;
    if (gr < nrows) {
      float4 o = acc[j];
      if (BIAS) { o.x += bv.x; o.y += bv.y; o.z += bv.z; o.w += bv.w; }
      if (HOUT) {
        uint2 pk = pack_half4(o);
        *reinterpret_cast<uint2*>((char*)C + ((size_t)gr * NF + ct * 4) * 2) = pk;
      } else {
        *((float4*)&C[(size_t)gr * NF + ct * 4]) = o;
      }
    }
  }
}

extern "C" void kernel_launch(void* const* d_in, const int* in_sizes, int n_in,
                              void* d_out, int out_size, void* d_ws, size_t ws_size,
                              hipStream_t stream) {
  const float* x = (const float*)d_in[0];
  const int* ei = (const int*)d_in[1];
  const float* ew = (const float*)d_in[2];
  const float* p = (const float*)d_in[3];
  const float* w_ih = (const float*)d_in[4];
  const float* w_hh = (const float*)d_in[5];
  const float* b_ih = (const float*)d_in[6];
  const float* b_hh = (const float*)d_in[7];
  const float* W0 = (const float*)d_in[8];
  const float* W_lin = (const float*)d_in[9];
  const float* b_lin = (const float*)d_in[10];
  float* out = (float*)d_out;

  const int N = in_sizes[0] / NF;  // 50000
  const int E = in_sizes[1] / 2;   // 800000

  char* w = (char*)d_ws;
  unsigned* xwh = (unsigned*)w;                             // N*64 uints (fp16 xw)
  float* score = (float*)(xwh + (size_t)N * 64);            // N
  unsigned* keys = (unsigned*)(score + N);                  // N
  float* deg = (float*)(keys + N);                          // N
  float* dinv = deg + N;                                    // N
  int* cnt = (int*)(dinv + N);                              // N
  int* cursor = cnt + N;                                    // N
  int* off = cursor + N;                                    // N+1
  int* bsum = off + N + 1;                                  // 1024
  int* bexc = bsum + 1024;                                  // 1025
  int* erow = bexc + 1025;                                  // E
  float* ecoef = (float*)(erow + E);                        // E
  float* Wev = ecoef + E;                                   // 128*128
  float* wlt = Wev + NF * NF;                               // 128*128
  int* perm = (int*)(wlt + NF * NF);                        // 128
  float* tsc = (float*)(perm + NF);                         // 128
  float* pninv = tsc + NF;                                  // 1

  const int nb = (N + SCAN_B - 1) / SCAN_B;

  prep_kernel<<<1, 256, 0, stream>>>(p, W_lin, pninv, wlt);
  score_init_kernel<<<(N + 3) / 4, 256, 0, stream>>>(x, p, pninv, score, keys, deg, cnt, N);
  topk_kernel<<<1, 1024, 0, stream>>>(keys, score, N, perm, tsc);
  gru_kernel<<<NF, NF, 0, stream>>>(x, perm, tsc, W0, w_ih, w_hh, b_ih, b_hh, Wev);
  hist_deg_kernel<<<(E + 255) / 256, 256, 0, stream>>>(ei, ew, cnt, deg, E);
  scan1_kernel<<<nb, SCAN_B, 0, stream>>>(cnt, off, bsum, deg, dinv, N);
  scan2_kernel<<<1, 64, 0, stream>>>(bsum, bexc, nb);
  scan3_kernel<<<(N + 256) / 256, 256, 0, stream>>>(off, bexc, cursor, N, nb);
  fill_kernel<<<(E + 255) / 256, 256, 0, stream>>>(ei, ew, dinv, cursor, erow, ecoef, E);
  gemm128_kernel<0, 0, 1><<<(N + 63) / 64, 256, 0, stream>>>(x, Wev, nullptr, (float*)xwh, N);
  aggregate_kernel<<<(N + 3) / 4, 256, 0, stream>>>(erow, ecoef, off, dinv, xwh, out, N);
  gemm128_kernel<1, 1, 0><<<(N + 63) / 64, 256, 0, stream>>>(out, wlt, b_lin, out, N);
}

// Round 4
// 405.742 us; speedup vs baseline: 1.0195x; 1.0195x over previous
//
#include <hip/hip_runtime.h>
#include <hip/hip_fp16.h>

#define NF 128
#define TK 128

__device__ __forceinline__ unsigned okey(float f) {
  unsigned u = __float_as_uint(f);
  return (u & 0x80000000u) ? ~u : (u | 0x80000000u);
}

__device__ __forceinline__ uint2 pack_half4(float4 v) {
  __half2 a = __floats2half2_rn(v.x, v.y);
  __half2 b = __floats2half2_rn(v.z, v.w);
  uint2 r;
  r.x = *reinterpret_cast<unsigned*>(&a);
  r.y = *reinterpret_cast<unsigned*>(&b);
  return r;
}

// ---------- prep: 1/||p||, transpose W_lin ----------
__global__ void prep_kernel(const float* __restrict__ p, const float* __restrict__ W_lin,
                            float* __restrict__ pninv, float* __restrict__ wlt) {
  __shared__ float red[128];
  int t = threadIdx.x;  // 256
  if (t < 128) { float v = p[t]; red[t] = v * v; }
  __syncthreads();
  for (int s = 64; s > 0; s >>= 1) {
    if (t < s) red[t] += red[t + s];
    __syncthreads();
  }
  if (t == 0) pninv[0] = 1.0f / sqrtf(red[0]);
  for (int i = t; i < NF * NF; i += 256) {
    int r = i >> 7, c = i & 127;
    wlt[c * NF + r] = W_lin[i];
  }
}

// ---------- scores (one wave per row) + node-array init + key histogram ----------
__global__ void score_init_kernel(const float* __restrict__ x, const float* __restrict__ p,
                                  const float* __restrict__ pninv, float* __restrict__ score,
                                  unsigned* __restrict__ keys, float* __restrict__ deg,
                                  int* __restrict__ cnt, unsigned* __restrict__ bins, int n) {
  int wib = threadIdx.x >> 6, lane = threadIdx.x & 63;
  int r = blockIdx.x * 4 + wib;
  if (r >= n) return;
  if (lane == 1) deg[r] = 1.0f;  // self-loop weight
  if (lane == 2) cnt[r] = 0;
  float2 xv = *(const float2*)&x[(size_t)r * NF + lane * 2];
  float2 pv = *(const float2*)&p[lane * 2];
  float d = xv.x * pv.x + xv.y * pv.y;
#pragma unroll
  for (int off = 32; off > 0; off >>= 1) d += __shfl_down(d, off, 64);
  if (lane == 0) {
    float s = tanhf(d * pninv[0]);
    score[r] = s;
    unsigned k = okey(s);
    keys[r] = k;
    atomicAdd(&bins[k >> 16], 1u);
  }
}

// ---------- find threshold bin: smallest B with count(top16 >= B) >= TK ----------
__global__ __launch_bounds__(1024) void findbin_kernel(const unsigned* __restrict__ bins,
                                                       unsigned* __restrict__ thrB) {
  __shared__ unsigned csum[1024];
  int t = threadIdx.x;
  unsigned s = 0;
  const unsigned* bp = bins + t * 64;
#pragma unroll 8
  for (int b = 0; b < 64; ++b) s += bp[b];
  csum[t] = s;
  __syncthreads();
  if (t == 0) {
    unsigned cum = 0;
    int chunk = 1023;
    for (; chunk > 0; --chunk) {
      if (cum + csum[chunk] >= (unsigned)TK) break;
      cum += csum[chunk];
    }
    unsigned base = (unsigned)chunk * 64;
    int b = 63;
    for (; b > 0; --b) {
      unsigned h = bins[base + b];
      if (cum + h >= (unsigned)TK) break;
      cum += h;
    }
    thrB[0] = base + (unsigned)b;
  }
}

// ---------- compact candidates: top16 >= B ----------
__global__ void compact_kernel(const unsigned* __restrict__ keys, const unsigned* __restrict__ thrB,
                               int* __restrict__ nc, unsigned* __restrict__ candKey,
                               int* __restrict__ candIdx, int n) {
  unsigned B = thrB[0];
  int i = blockIdx.x * blockDim.x + threadIdx.x;
  if (i < n) {
    unsigned k = keys[i];
    if ((k >> 16) >= B) {
      int pos = atomicAdd(nc, 1);
      candKey[pos] = k;
      candIdx[pos] = i;
    }
  }
}

// ---------- exact select: rank under (key desc, idx asc) ----------
#define CCAP 6144
__global__ __launch_bounds__(1024) void select_kernel(const unsigned* __restrict__ candKey,
                                                      const int* __restrict__ candIdx,
                                                      const int* __restrict__ ncp,
                                                      const float* __restrict__ score,
                                                      int* __restrict__ perm, float* __restrict__ tsc) {
  __shared__ unsigned sk[CCAP];
  __shared__ int si[CCAP];
  int nc = ncp[0];
  int t = threadIdx.x;
  int m = nc < CCAP ? nc : CCAP;
  for (int i = t; i < m; i += 1024) { sk[i] = candKey[i]; si[i] = candIdx[i]; }
  __syncthreads();
  for (int ci = t; ci < nc; ci += 1024) {
    unsigned mk = (ci < CCAP) ? sk[ci] : candKey[ci];
    int mi = (ci < CCAP) ? si[ci] : candIdx[ci];
    int rank = 0;
    for (int j = 0; j < m; ++j) {
      unsigned kj = sk[j];
      int ij = si[j];
      rank += (kj > mk || (kj == mk && ij < mi)) ? 1 : 0;
    }
    for (int j = CCAP; j < nc; ++j) {
      unsigned kj = candKey[j];
      int ij = candIdx[j];
      rank += (kj > mk || (kj == mk && ij < mi)) ? 1 : 0;
    }
    if (rank < TK) {
      perm[rank] = mi;
      tsc[rank] = score[mi];
    }
  }
}

// ---------- GRU: block per row i, thread per col j ----------
__global__ void gru_kernel(const float* __restrict__ x, const int* __restrict__ perm,
                           const float* __restrict__ tsc, const float* __restrict__ W0,
                           const float* __restrict__ w_ih, const float* __restrict__ w_hh,
                           const float* __restrict__ b_ih, const float* __restrict__ b_hh,
                           float* __restrict__ W) {
  __shared__ float xs[NF], w0s[NF];
  int i = blockIdx.x, j = threadIdx.x;
  int pi = perm[i];
  float s = tsc[i];
  xs[j] = x[(size_t)pi * NF + j] * s;
  w0s[j] = W0[i * NF + j];
  __syncthreads();
  float gir = b_ih[j], giz = b_ih[NF + j], gin = b_ih[2 * NF + j];
  float ghr = b_hh[j], ghz = b_hh[NF + j], ghn = b_hh[2 * NF + j];
  const float* wr = w_ih + (size_t)j * NF;
  const float* wz = w_ih + (size_t)(NF + j) * NF;
  const float* wn = w_ih + (size_t)(2 * NF + j) * NF;
  const float* ur = w_hh + (size_t)j * NF;
  const float* uz = w_hh + (size_t)(NF + j) * NF;
  const float* un = w_hh + (size_t)(2 * NF + j) * NF;
#pragma unroll 4
  for (int k = 0; k < NF; ++k) {
    float xv = xs[k], wv = w0s[k];
    gir = fmaf(xv, wr[k], gir);
    giz = fmaf(xv, wz[k], giz);
    gin = fmaf(xv, wn[k], gin);
    ghr = fmaf(wv, ur[k], ghr);
    ghz = fmaf(wv, uz[k], ghz);
    ghn = fmaf(wv, un[k], ghn);
  }
  float r = 1.0f / (1.0f + expf(-(gir + ghr)));
  float z = 1.0f / (1.0f + expf(-(giz + ghz)));
  float nn = tanhf(gin + r * ghn);
  W[i * NF + j] = (1.0f - z) * nn + z * w0s[j];
}

// ---------- histogram of in-degree + weighted degree ----------
__global__ void hist_deg_kernel(const int* __restrict__ ei, const float* __restrict__ ew,
                                int* __restrict__ cnt, float* __restrict__ deg, int E) {
  int e = blockIdx.x * blockDim.x + threadIdx.x;
  if (e < E) {
    int c = ei[E + e];
    atomicAdd(&cnt[c], 1);
    unsafeAtomicAdd(&deg[c], ew[e]);
  }
}

// ---------- exclusive scan over cnt -> off (+ dinv fused) ----------
#define SCAN_B 1024
__global__ __launch_bounds__(1024) void scan1_kernel(const int* __restrict__ cnt,
                                                     int* __restrict__ off,
                                                     int* __restrict__ bsum,
                                                     const float* __restrict__ deg,
                                                     float* __restrict__ dinv, int n) {
  __shared__ int sd[SCAN_B];
  int t = threadIdx.x;
  int i = blockIdx.x * SCAN_B + t;
  if (i < n) {
    float d = deg[i];
    dinv[i] = (d > 0.0f) ? (1.0f / sqrtf(d)) : 0.0f;
  }
  int v = (i < n) ? cnt[i] : 0;
  sd[t] = v;
  __syncthreads();
  for (int s = 1; s < SCAN_B; s <<= 1) {
    int add = (t >= s) ? sd[t - s] : 0;
    __syncthreads();
    sd[t] += add;
    __syncthreads();
  }
  if (i < n) off[i] = sd[t] - v;  // exclusive
  if (t == SCAN_B - 1) bsum[blockIdx.x] = sd[t];
}
__global__ void scan2_kernel(const int* __restrict__ bsum, int* __restrict__ bexc, int nb) {
  if (threadIdx.x == 0 && blockIdx.x == 0) {
    int run = 0;
    for (int b = 0; b < nb; ++b) { bexc[b] = run; run += bsum[b]; }
    bexc[nb] = run;
  }
}
__global__ void scan3_kernel(int* __restrict__ off, const int* __restrict__ bexc,
                             int* __restrict__ cursor, int n, int nb) {
  int i = blockIdx.x * blockDim.x + threadIdx.x;
  if (i < n) {
    int v = off[i] + bexc[i >> 10];
    off[i] = v;
    cursor[i] = v;
  } else if (i == n) {
    off[n] = bexc[nb];
  }
}

// ---------- fill CSR: (row, coef) per incoming edge, grouped by col ----------
__global__ void fill_kernel(const int* __restrict__ ei, const float* __restrict__ ew,
                            const float* __restrict__ dinv, int* __restrict__ cursor,
                            int* __restrict__ erow, float* __restrict__ ecoef, int E) {
  int e = blockIdx.x * blockDim.x + threadIdx.x;
  if (e >= E) return;
  int r = ei[e], c = ei[E + e];
  int pos = atomicAdd(&cursor[c], 1);
  erow[pos] = r;
  ecoef[pos] = dinv[r] * ew[e] * dinv[c];
}

// ---------- aggregate: one wave per node, fp16 gather, atomic-free ----------
__global__ void aggregate_kernel(const int* __restrict__ erow, const float* __restrict__ ecoef,
                                 const int* __restrict__ off, const float* __restrict__ dinv,
                                 const unsigned* __restrict__ xwh, float* __restrict__ h, int n) {
  int w = (int)((blockIdx.x * (size_t)blockDim.x + threadIdx.x) >> 6);
  int lane = threadIdx.x & 63;
  if (w >= n) return;
  int n0 = off[w], n1 = off[w + 1];
  float dv = dinv[w];
  float c2 = dv * dv;  // self-loop: dinv[i]*1.0*dinv[i]
  unsigned su = xwh[(size_t)w * 64 + lane];
  float2 sv = __half22float2(*reinterpret_cast<__half2*>(&su));
  float2 acc = make_float2(c2 * sv.x, c2 * sv.y);
  for (int e = n0; e < n1; ++e) {
    int r = erow[e];
    float cf = ecoef[e];
    unsigned u = xwh[(size_t)r * 64 + lane];
    float2 v = __half22float2(*reinterpret_cast<__half2*>(&u));
    acc.x = fmaf(cf, v.x, acc.x);
    acc.y = fmaf(cf, v.y, acc.y);
  }
  *(float2*)&h[(size_t)w * NF + lane * 2] = acc;
}

// ---------- GEMM: C[r,c] = sum_k op(A[r,k]) * B[k,c] (+bias), B is 128x128 ----------
template <int RELU, int BIAS, int HOUT>
__global__ __launch_bounds__(256) void gemm128_kernel(const float* __restrict__ A,
                                                      const float* __restrict__ Bm,
                                                      const float* __restrict__ bias,
                                                      float* __restrict__ C, int nrows) {
  __shared__ float Bs[64][128];
  __shared__ float As[64][68];  // [k][r], padded
  const int t = threadIdx.x;
  const int ct = t & 31;   // 4-col group
  const int rt = t >> 5;   // 0..7 -> rows rt*8..rt*8+7
  const int row0 = blockIdx.x * 64;
  float4 acc[8];
#pragma unroll
  for (int j = 0; j < 8; ++j) acc[j] = make_float4(0.f, 0.f, 0.f, 0.f);

  for (int ph = 0; ph < 2; ++ph) {
    {
      const float4* B4 = (const float4*)(Bm + ph * 64 * NF);
#pragma unroll
      for (int pp = 0; pp < 8; ++pp) {
        int idx = pp * 256 + t;  // 0..2047
        int k = idx >> 5, c4 = idx & 31;
        *((float4*)&Bs[k][c4 * 4]) = B4[idx];
      }
    }
    {
#pragma unroll
      for (int pp = 0; pp < 4; ++pp) {
        int idx = pp * 256 + t;  // 0..1023
        int r = idx >> 4;        // 0..63
        int k4 = idx & 15;       // col group
        int gr = row0 + r;
        float4 v = make_float4(0.f, 0.f, 0.f, 0.f);
        if (gr < nrows) v = *((const float4*)&A[(size_t)gr * NF + ph * 64 + k4 * 4]);
        if (RELU) {
          v.x = fmaxf(v.x, 0.f); v.y = fmaxf(v.y, 0.f);
          v.z = fmaxf(v.z, 0.f); v.w = fmaxf(v.w, 0.f);
        }
        As[k4 * 4 + 0][r] = v.x;
        As[k4 * 4 + 1][r] = v.y;
        As[k4 * 4 + 2][r] = v.z;
        As[k4 * 4 + 3][r] = v.w;
      }
    }
    __syncthreads();
#pragma unroll 4
    for (int k = 0; k < 64; ++k) {
      float4 b = *((const float4*)&Bs[k][ct * 4]);
      float a[8];
      *((float4*)&a[0]) = *((const float4*)&As[k][rt * 8]);
      *((float4*)&a[4]) = *((const float4*)&As[k][rt * 8 + 4]);
#pragma unroll
      for (int j = 0; j < 8; ++j) {
        acc[j].x = fmaf(a[j], b.x, acc[j].x);
        acc[j].y = fmaf(a[j], b.y, acc[j].y);
        acc[j].z = fmaf(a[j], b.z, acc[j].z);
        acc[j].w = fmaf(a[j], b.w, acc[j].w);
      }
    }
    __syncthreads();
  }
  float4 bv = make_float4(0.f, 0.f, 0.f, 0.f);
  if (BIAS) bv = *((const float4*)&bias[ct * 4]);
#pragma unroll
  for (int j = 0; j < 8; ++j) {
    int gr = row0 + rt * 8 + j;
    if (gr < nrows) {
      float4 o = acc[j];
      if (BIAS) { o.x += bv.x; o.y += bv.y; o.z += bv.z; o.w += bv.w; }
      if (HOUT) {
        uint2 pk = pack_half4(o);
        *reinterpret_cast<uint2*>((char*)C + ((size_t)gr * NF + ct * 4) * 2) = pk;
      } else {
        *((float4*)&C[(size_t)gr * NF + ct * 4]) = o;
      }
    }
  }
}

extern "C" void kernel_launch(void* const* d_in, const int* in_sizes, int n_in,
                              void* d_out, int out_size, void* d_ws, size_t ws_size,
                              hipStream_t stream) {
  const float* x = (const float*)d_in[0];
  const int* ei = (const int*)d_in[1];
  const float* ew = (const float*)d_in[2];
  const float* p = (const float*)d_in[3];
  const float* w_ih = (const float*)d_in[4];
  const float* w_hh = (const float*)d_in[5];
  const float* b_ih = (const float*)d_in[6];
  const float* b_hh = (const float*)d_in[7];
  const float* W0 = (const float*)d_in[8];
  const float* W_lin = (const float*)d_in[9];
  const float* b_lin = (const float*)d_in[10];
  float* out = (float*)d_out;

  const int N = in_sizes[0] / NF;  // 50000
  const int E = in_sizes[1] / 2;   // 800000

  char* w = (char*)d_ws;
  unsigned* xwh = (unsigned*)w;                             // N*64 uints (fp16 xw)
  float* score = (float*)(xwh + (size_t)N * 64);            // N
  unsigned* keys = (unsigned*)(score + N);                  // N
  float* deg = (float*)(keys + N);                          // N
  float* dinv = deg + N;                                    // N
  int* cnt = (int*)(dinv + N);                              // N
  int* cursor = cnt + N;                                    // N
  int* off = cursor + N;                                    // N+1
  int* bsum = off + N + 1;                                  // 1024
  int* bexc = bsum + 1024;                                  // 1025
  unsigned* bins = (unsigned*)(bexc + 1025);                // 65536
  int* ncnt = (int*)(bins + 65536);                         // 1
  unsigned* thrB = (unsigned*)(ncnt + 1);                   // 1
  unsigned* candKey = thrB + 1;                             // N
  int* candIdx = (int*)(candKey + N);                       // N
  int* erow = candIdx + N;                                  // E
  float* ecoef = (float*)(erow + E);                        // E
  float* Wev = ecoef + E;                                   // 128*128
  float* wlt = Wev + NF * NF;                               // 128*128
  int* perm = (int*)(wlt + NF * NF);                        // 128
  float* tsc = (float*)(perm + NF);                         // 128
  float* pninv = tsc + NF;                                  // 1

  const int nb = (N + SCAN_B - 1) / SCAN_B;

  hipMemsetAsync(bins, 0, (65536 + 1) * sizeof(unsigned), stream);  // bins + ncnt
  prep_kernel<<<1, 256, 0, stream>>>(p, W_lin, pninv, wlt);
  score_init_kernel<<<(N + 3) / 4, 256, 0, stream>>>(x, p, pninv, score, keys, deg, cnt, bins, N);
  findbin_kernel<<<1, 1024, 0, stream>>>(bins, thrB);
  compact_kernel<<<(N + 255) / 256, 256, 0, stream>>>(keys, thrB, ncnt, candKey, candIdx, N);
  select_kernel<<<1, 1024, 0, stream>>>(candKey, candIdx, ncnt, score, perm, tsc);
  gru_kernel<<<NF, NF, 0, stream>>>(x, perm, tsc, W0, w_ih, w_hh, b_ih, b_hh, Wev);
  hist_deg_kernel<<<(E + 255) / 256, 256, 0, stream>>>(ei, ew, cnt, deg, E);
  scan1_kernel<<<nb, SCAN_B, 0, stream>>>(cnt, off, bsum, deg, dinv, N);
  scan2_kernel<<<1, 64, 0, stream>>>(bsum, bexc, nb);
  scan3_kernel<<<(N + 256) / 256, 256, 0, stream>>>(off, bexc, cursor, N, nb);
  fill_kernel<<<(E + 255) / 256, 256, 0, stream>>>(ei, ew, dinv, cursor, erow, ecoef, E);
  gemm128_kernel<0, 0, 1><<<(N + 63) / 64, 256, 0, stream>>>(x, Wev, nullptr, (float*)xwh, N);
  aggregate_kernel<<<(N + 3) / 4, 256, 0, stream>>>(erow, ecoef, off, dinv, xwh, out, N);
  gemm128_kernel<1, 1, 0><<<(N + 63) / 64, 256, 0, stream>>>(out, wlt, b_lin, out, N);
}

// Round 5
// 325.954 us; speedup vs baseline: 1.2690x; 1.2448x over previous
//
#include <hip/hip_runtime.h>
#include <hip/hip_fp16.h>

#define NF 128
#define TK 128

__device__ __forceinline__ unsigned okey(float f) {
  unsigned u = __float_as_uint(f);
  return (u & 0x80000000u) ? ~u : (u | 0x80000000u);
}

__device__ __forceinline__ uint2 pack_half4(float4 v) {
  __half2 a = __floats2half2_rn(v.x, v.y);
  __half2 b = __floats2half2_rn(v.z, v.w);
  uint2 r;
  r.x = *reinterpret_cast<unsigned*>(&a);
  r.y = *reinterpret_cast<unsigned*>(&b);
  return r;
}

// ---------- prep: transpose W_lin ----------
__global__ void prep_kernel(const float* __restrict__ W_lin, float* __restrict__ wlt) {
  int t = threadIdx.x;
  for (int i = t; i < NF * NF; i += 256) {
    int r = i >> 7, c = i & 127;
    wlt[c * NF + r] = W_lin[i];
  }
}

// ---------- fused: scores (+key histogram) over node blocks; edge degree/count over edge blocks ----------
__global__ void score_hist_kernel(const float* __restrict__ x, const float* __restrict__ p,
                                  float* __restrict__ score, unsigned* __restrict__ keys,
                                  unsigned* __restrict__ bins, const int* __restrict__ ei,
                                  const float* __restrict__ ew, float* __restrict__ deg,
                                  int* __restrict__ cnt, int n, int E, int nbScore) {
  if ((int)blockIdx.x >= nbScore) {
    int e = ((int)blockIdx.x - nbScore) * 256 + threadIdx.x;
    if (e < E) {
      int c = ei[E + e];
      atomicAdd(&cnt[c], 1);
      unsafeAtomicAdd(&deg[c], ew[e]);
    }
    return;
  }
  int wib = threadIdx.x >> 6, lane = threadIdx.x & 63;
  int r = blockIdx.x * 4 + wib;
  if (r >= n) return;
  float2 xv = *(const float2*)&x[(size_t)r * NF + lane * 2];
  float2 pv = *(const float2*)&p[lane * 2];
  float d = fmaf(xv.x, pv.x, xv.y * pv.y);
  float pp = fmaf(pv.x, pv.x, pv.y * pv.y);
#pragma unroll
  for (int off = 32; off > 0; off >>= 1) {
    d += __shfl_down(d, off, 64);
    pp += __shfl_down(pp, off, 64);
  }
  if (lane == 0) {
    float s = tanhf(d / sqrtf(pp));
    score[r] = s;
    unsigned k = okey(s);
    keys[r] = k;
    atomicAdd(&bins[k >> 16], 1u);
  }
}

// ---------- find threshold bin: smallest B with count(top16 >= B) >= TK ----------
__global__ __launch_bounds__(1024) void findbin_kernel(const unsigned* __restrict__ bins,
                                                       unsigned* __restrict__ thrB) {
  __shared__ unsigned csum[1024];
  int t = threadIdx.x;
  unsigned s = 0;
  const unsigned* bp = bins + t * 64;
#pragma unroll 8
  for (int b = 0; b < 64; ++b) s += bp[b];
  csum[t] = s;
  __syncthreads();
  if (t == 0) {
    unsigned cum = 0;
    int chunk = 1023;
    for (; chunk > 0; --chunk) {
      if (cum + csum[chunk] >= (unsigned)TK) break;
      cum += csum[chunk];
    }
    unsigned base = (unsigned)chunk * 64;
    int b = 63;
    for (; b > 0; --b) {
      unsigned h = bins[base + b];
      if (cum + h >= (unsigned)TK) break;
      cum += h;
    }
    thrB[0] = base + (unsigned)b;
  }
}

// ---------- scan over cnt (block-local exclusive) + dinv + candidate compaction ----------
#define SCAN_B 1024
__global__ __launch_bounds__(1024) void scan1_kernel(const int* __restrict__ cnt,
                                                     int* __restrict__ offL, int* __restrict__ bsum,
                                                     const float* __restrict__ deg,
                                                     float* __restrict__ dinv,
                                                     const unsigned* __restrict__ keys,
                                                     const unsigned* __restrict__ thrB,
                                                     int* __restrict__ ncnt,
                                                     unsigned* __restrict__ candKey,
                                                     int* __restrict__ candIdx, int n) {
  __shared__ int sd[SCAN_B];
  int t = threadIdx.x;
  int i = blockIdx.x * SCAN_B + t;
  int v = 0;
  if (i < n) {
    float dsum = deg[i] + 1.0f;  // + self-loop weight
    dinv[i] = 1.0f / sqrtf(dsum);
    v = cnt[i];
    unsigned k = keys[i];
    if ((k >> 16) >= thrB[0]) {
      int pos = atomicAdd(ncnt, 1);
      candKey[pos] = k;
      candIdx[pos] = i;
    }
  }
  sd[t] = v;
  __syncthreads();
  for (int s = 1; s < SCAN_B; s <<= 1) {
    int add = (t >= s) ? sd[t - s] : 0;
    __syncthreads();
    sd[t] += add;
    __syncthreads();
  }
  if (i <= n) offL[i] = sd[t] - v;  // block-local exclusive
  if (t == SCAN_B - 1) bsum[blockIdx.x] = sd[t];
}

// ---------- block 0: wave-scan of bsum -> bexc; block 1: exact top-K select ----------
#define CCAP 6144
__global__ __launch_bounds__(1024) void scan2_select_kernel(const int* __restrict__ bsum,
                                                            int* __restrict__ bexc, int nb,
                                                            const unsigned* __restrict__ candKey,
                                                            const int* __restrict__ candIdx,
                                                            const int* __restrict__ ncp,
                                                            const float* __restrict__ score,
                                                            int* __restrict__ perm,
                                                            float* __restrict__ tsc) {
  if (blockIdx.x == 0) {
    int t = threadIdx.x;
    if (t < 64) {  // requires nb <= 63 (N <= 64K)
      int v = (t < nb) ? bsum[t] : 0;
      int incl = v;
#pragma unroll
      for (int s = 1; s < 64; s <<= 1) {
        int u = __shfl_up(incl, s, 64);
        if (t >= s) incl += u;
      }
      if (t <= nb) bexc[t] = incl - v;
    }
    return;
  }
  __shared__ unsigned sk[CCAP];
  __shared__ int si[CCAP];
  int nc = ncp[0];
  int t = threadIdx.x;
  int m = nc < CCAP ? nc : CCAP;
  for (int i = t; i < m; i += 1024) { sk[i] = candKey[i]; si[i] = candIdx[i]; }
  __syncthreads();
  for (int ci = t; ci < nc; ci += 1024) {
    unsigned mk = (ci < CCAP) ? sk[ci] : candKey[ci];
    int mi = (ci < CCAP) ? si[ci] : candIdx[ci];
    int rank = 0;
    for (int j = 0; j < m; ++j) {
      unsigned kj = sk[j];
      int ij = si[j];
      rank += (kj > mk || (kj == mk && ij < mi)) ? 1 : 0;
    }
    for (int j = CCAP; j < nc; ++j) {
      unsigned kj = candKey[j];
      int ij = candIdx[j];
      rank += (kj > mk || (kj == mk && ij < mi)) ? 1 : 0;
    }
    if (rank < TK) {
      perm[rank] = mi;
      tsc[rank] = score[mi];
    }
  }
}

// ---------- GRU: block per row i, thread per col j ----------
__global__ void gru_kernel(const float* __restrict__ x, const int* __restrict__ perm,
                           const float* __restrict__ tsc, const float* __restrict__ W0,
                           const float* __restrict__ w_ih, const float* __restrict__ w_hh,
                           const float* __restrict__ b_ih, const float* __restrict__ b_hh,
                           float* __restrict__ W) {
  __shared__ float xs[NF], w0s[NF];
  int i = blockIdx.x, j = threadIdx.x;
  int pi = perm[i];
  float s = tsc[i];
  xs[j] = x[(size_t)pi * NF + j] * s;
  w0s[j] = W0[i * NF + j];
  __syncthreads();
  float gir = b_ih[j], giz = b_ih[NF + j], gin = b_ih[2 * NF + j];
  float ghr = b_hh[j], ghz = b_hh[NF + j], ghn = b_hh[2 * NF + j];
  const float* wr = w_ih + (size_t)j * NF;
  const float* wz = w_ih + (size_t)(NF + j) * NF;
  const float* wn = w_ih + (size_t)(2 * NF + j) * NF;
  const float* ur = w_hh + (size_t)j * NF;
  const float* uz = w_hh + (size_t)(NF + j) * NF;
  const float* un = w_hh + (size_t)(2 * NF + j) * NF;
#pragma unroll 4
  for (int k = 0; k < NF; ++k) {
    float xv = xs[k], wv = w0s[k];
    gir = fmaf(xv, wr[k], gir);
    giz = fmaf(xv, wz[k], giz);
    gin = fmaf(xv, wn[k], gin);
    ghr = fmaf(wv, ur[k], ghr);
    ghz = fmaf(wv, uz[k], ghz);
    ghn = fmaf(wv, un[k], ghn);
  }
  float r = 1.0f / (1.0f + expf(-(gir + ghr)));
  float z = 1.0f / (1.0f + expf(-(giz + ghz)));
  float nn = tanhf(gin + r * ghn);
  W[i * NF + j] = (1.0f - z) * nn + z * w0s[j];
}

// ---------- fill CSR: packed (row, coef), cnt used as countdown cursor ----------
__global__ void fill_kernel(const int* __restrict__ ei, const float* __restrict__ ew,
                            const float* __restrict__ dinv, const int* __restrict__ offL,
                            const int* __restrict__ bexc, int* __restrict__ cnt,
                            uint2* __restrict__ epair, int E) {
  int e = blockIdx.x * 256 + threadIdx.x;
  if (e >= E) return;
  int r = ei[e], c = ei[E + e];
  int slot = atomicSub(&cnt[c], 1) - 1;
  int pos = offL[c] + bexc[c >> 10] + slot;
  float cf = dinv[r] * ew[e] * dinv[c];
  epair[pos] = make_uint2((unsigned)r, __float_as_uint(cf));
}

// ---------- aggregate: one wave per node, 4 edges in flight (quarter-wave gathers) ----------
__global__ void aggregate_kernel(const uint2* __restrict__ epair, const int* __restrict__ offL,
                                 const int* __restrict__ bexc, const float* __restrict__ dinv,
                                 const uint4* __restrict__ xw4, float* __restrict__ h, int n) {
  int w = (int)((blockIdx.x * (size_t)blockDim.x + threadIdx.x) >> 6);
  if (w >= n) return;
  int lane = threadIdx.x & 63;
  int q = lane >> 4, l16 = lane & 15;
  int n0 = offL[w] + bexc[w >> 10];
  int n1 = offL[w + 1] + bexc[(w + 1) >> 10];
  float acc[8] = {0.f, 0.f, 0.f, 0.f, 0.f, 0.f, 0.f, 0.f};
  if (q == 0) {
    float dv = dinv[w];
    float c2 = dv * dv;  // self-loop: dinv[i]*1.0*dinv[i]
    uint4 su = xw4[(size_t)w * 16 + l16];
    float2 f0 = __half22float2(*(const __half2*)&su.x);
    float2 f1 = __half22float2(*(const __half2*)&su.y);
    float2 f2 = __half22float2(*(const __half2*)&su.z);
    float2 f3 = __half22float2(*(const __half2*)&su.w);
    acc[0] = c2 * f0.x; acc[1] = c2 * f0.y; acc[2] = c2 * f1.x; acc[3] = c2 * f1.y;
    acc[4] = c2 * f2.x; acc[5] = c2 * f2.y; acc[6] = c2 * f3.x; acc[7] = c2 * f3.y;
  }
  for (int e = n0 + q; e < n1; e += 4) {
    uint2 pr = epair[e];
    float cf = __uint_as_float(pr.y);
    uint4 u = xw4[(size_t)pr.x * 16 + l16];
    float2 f0 = __half22float2(*(const __half2*)&u.x);
    float2 f1 = __half22float2(*(const __half2*)&u.y);
    float2 f2 = __half22float2(*(const __half2*)&u.z);
    float2 f3 = __half22float2(*(const __half2*)&u.w);
    acc[0] = fmaf(cf, f0.x, acc[0]); acc[1] = fmaf(cf, f0.y, acc[1]);
    acc[2] = fmaf(cf, f1.x, acc[2]); acc[3] = fmaf(cf, f1.y, acc[3]);
    acc[4] = fmaf(cf, f2.x, acc[4]); acc[5] = fmaf(cf, f2.y, acc[5]);
    acc[6] = fmaf(cf, f3.x, acc[6]); acc[7] = fmaf(cf, f3.y, acc[7]);
  }
#pragma unroll
  for (int j = 0; j < 8; ++j) {
    float a = acc[j];
    a += __shfl_xor(a, 16, 64);
    a += __shfl_xor(a, 32, 64);
    acc[j] = a;
  }
  if (q == 0) {
    *(float4*)&h[(size_t)w * NF + l16 * 8] = make_float4(acc[0], acc[1], acc[2], acc[3]);
    *(float4*)&h[(size_t)w * NF + l16 * 8 + 4] = make_float4(acc[4], acc[5], acc[6], acc[7]);
  }
}

// ---------- GEMM: C[r,c] = sum_k op(A[r,k]) * B[k,c] (+bias), B is 128x128 ----------
template <int RELU, int BIAS, int HOUT>
__global__ __launch_bounds__(256) void gemm128_kernel(const float* __restrict__ A,
                                                      const float* __restrict__ Bm,
                                                      const float* __restrict__ bias,
                                                      float* __restrict__ C, int nrows) {
  __shared__ float Bs[64][128];
  __shared__ float As[64][68];  // [k][r], padded
  const int t = threadIdx.x;
  const int ct = t & 31;   // 4-col group
  const int rt = t >> 5;   // 0..7 -> rows rt*8..rt*8+7
  const int row0 = blockIdx.x * 64;
  float4 acc[8];
#pragma unroll
  for (int j = 0; j < 8; ++j) acc[j] = make_float4(0.f, 0.f, 0.f, 0.f);

  for (int ph = 0; ph < 2; ++ph) {
    {
      const float4* B4 = (const float4*)(Bm + ph * 64 * NF);
#pragma unroll
      for (int pp = 0; pp < 8; ++pp) {
        int idx = pp * 256 + t;  // 0..2047
        int k = idx >> 5, c4 = idx & 31;
        *((float4*)&Bs[k][c4 * 4]) = B4[idx];
      }
    }
    {
#pragma unroll
      for (int pp = 0; pp < 4; ++pp) {
        int idx = pp * 256 + t;  // 0..1023
        int r = idx >> 4;        // 0..63
        int k4 = idx & 15;       // col group
        int gr = row0 + r;
        float4 v = make_float4(0.f, 0.f, 0.f, 0.f);
        if (gr < nrows) v = *((const float4*)&A[(size_t)gr * NF + ph * 64 + k4 * 4]);
        if (RELU) {
          v.x = fmaxf(v.x, 0.f); v.y = fmaxf(v.y, 0.f);
          v.z = fmaxf(v.z, 0.f); v.w = fmaxf(v.w, 0.f);
        }
        As[k4 * 4 + 0][r] = v.x;
        As[k4 * 4 + 1][r] = v.y;
        As[k4 * 4 + 2][r] = v.z;
        As[k4 * 4 + 3][r] = v.w;
      }
    }
    __syncthreads();
#pragma unroll 4
    for (int k = 0; k < 64; ++k) {
      float4 b = *((const float4*)&Bs[k][ct * 4]);
      float a[8];
      *((float4*)&a[0]) = *((const float4*)&As[k][rt * 8]);
      *((float4*)&a[4]) = *((const float4*)&As[k][rt * 8 + 4]);
#pragma unroll
      for (int j = 0; j < 8; ++j) {
        acc[j].x = fmaf(a[j], b.x, acc[j].x);
        acc[j].y = fmaf(a[j], b.y, acc[j].y);
        acc[j].z = fmaf(a[j], b.z, acc[j].z);
        acc[j].w = fmaf(a[j], b.w, acc[j].w);
      }
    }
    __syncthreads();
  }
  float4 bv = make_float4(0.f, 0.f, 0.f, 0.f);
  if (BIAS) bv = *((const float4*)&bias[ct * 4]);
#pragma unroll
  for (int j = 0; j < 8; ++j) {
    int gr = row0 + rt * 8 + j;
    if (gr < nrows) {
      float4 o = acc[j];
      if (BIAS) { o.x += bv.x; o.y += bv.y; o.z += bv.z; o.w += bv.w; }
      if (HOUT) {
        uint2 pk = pack_half4(o);
        *reinterpret_cast<uint2*>((char*)C + ((size_t)gr * NF + ct * 4) * 2) = pk;
      } else {
        *((float4*)&C[(size_t)gr * NF + ct * 4]) = o;
      }
    }
  }
}

extern "C" void kernel_launch(void* const* d_in, const int* in_sizes, int n_in,
                              void* d_out, int out_size, void* d_ws, size_t ws_size,
                              hipStream_t stream) {
  const float* x = (const float*)d_in[0];
  const int* ei = (const int*)d_in[1];
  const float* ew = (const float*)d_in[2];
  const float* p = (const float*)d_in[3];
  const float* w_ih = (const float*)d_in[4];
  const float* w_hh = (const float*)d_in[5];
  const float* b_ih = (const float*)d_in[6];
  const float* b_hh = (const float*)d_in[7];
  const float* W0 = (const float*)d_in[8];
  const float* W_lin = (const float*)d_in[9];
  const float* b_lin = (const float*)d_in[10];
  float* out = (float*)d_out;

  const int N = in_sizes[0] / NF;  // 50000
  const int E = in_sizes[1] / 2;   // 800000

  char* w = (char*)d_ws;
  unsigned* xwh = (unsigned*)w;                             // N*64 uints (fp16 xw)
  float* score = (float*)(xwh + (size_t)N * 64);            // N
  unsigned* keys = (unsigned*)(score + N);                  // N
  float* deg = (float*)(keys + N);                          // ZERO region: N
  int* cnt = (int*)(deg + N);                               // N
  unsigned* bins = (unsigned*)(cnt + N);                    // 65536
  int* ncnt = (int*)(bins + 65536);                         // 1 (end of ZERO region)
  float* dinv = (float*)(ncnt + 1);                         // N
  unsigned* thrB = (unsigned*)(dinv + N);                   // 1
  unsigned* candKey = thrB + 1;                             // N
  int* candIdx = (int*)(candKey + N);                       // N
  int* offL = candIdx + N;                                  // N+1
  int* bsum = offL + N + 1;                                 // 64
  int* bexc = bsum + 64;                                    // 64
  uint2* epair = (uint2*)(((uintptr_t)(bexc + 64) + 15) & ~(uintptr_t)15);  // E
  float* Wev = (float*)(epair + E);                         // 128*128
  float* wlt = Wev + NF * NF;                               // 128*128
  int* perm = (int*)(wlt + NF * NF);                        // 128
  float* tsc = (float*)(perm + NF);                         // 128

  const int nb = (N + SCAN_B - 1) / SCAN_B;
  const int nbScore = (N + 3) / 4;
  const int nbEdge = (E + 255) / 256;

  hipMemsetAsync(deg, 0, (size_t)(2 * N + 65536 + 1) * 4, stream);  // deg,cnt,bins,ncnt
  prep_kernel<<<1, 256, 0, stream>>>(W_lin, wlt);
  score_hist_kernel<<<nbScore + nbEdge, 256, 0, stream>>>(x, p, score, keys, bins, ei, ew,
                                                          deg, cnt, N, E, nbScore);
  findbin_kernel<<<1, 1024, 0, stream>>>(bins, thrB);
  scan1_kernel<<<nb, SCAN_B, 0, stream>>>(cnt, offL, bsum, deg, dinv, keys, thrB, ncnt,
                                          candKey, candIdx, N);
  scan2_select_kernel<<<2, 1024, 0, stream>>>(bsum, bexc, nb, candKey, candIdx, ncnt, score,
                                              perm, tsc);
  gru_kernel<<<NF, NF, 0, stream>>>(x, perm, tsc, W0, w_ih, w_hh, b_ih, b_hh, Wev);
  fill_kernel<<<nbEdge, 256, 0, stream>>>(ei, ew, dinv, offL, bexc, cnt, epair, E);
  gemm128_kernel<0, 0, 1><<<(N + 63) / 64, 256, 0, stream>>>(x, Wev, nullptr, (float*)xwh, N);
  aggregate_kernel<<<(N + 3) / 4, 256, 0, stream>>>(epair, offL, bexc, dinv,
                                                    (const uint4*)xwh, out, N);
  gemm128_kernel<1, 1, 0><<<(N + 63) / 64, 256, 0, stream>>>(out, wlt, b_lin, out, N);
}

// Round 6
// 269.110 us; speedup vs baseline: 1.5371x; 1.2112x over previous
//
#include <hip/hip_runtime.h>
#include <hip/hip_fp16.h>

#define NF 128
#define TK 128

__device__ __forceinline__ unsigned okey(float f) {
  unsigned u = __float_as_uint(f);
  return (u & 0x80000000u) ? ~u : (u | 0x80000000u);
}

__device__ __forceinline__ uint2 pack_half4(float4 v) {
  __half2 a = __floats2half2_rn(v.x, v.y);
  __half2 b = __floats2half2_rn(v.z, v.w);
  uint2 r;
  r.x = *reinterpret_cast<unsigned*>(&a);
  r.y = *reinterpret_cast<unsigned*>(&b);
  return r;
}

// ---------- prep: transpose W_lin ----------
__global__ void prep_kernel(const float* __restrict__ W_lin, float* __restrict__ wlt) {
  int t = threadIdx.x;
  for (int i = t; i < NF * NF; i += 256) {
    int r = i >> 7, c = i & 127;
    wlt[c * NF + r] = W_lin[i];
  }
}

// ---------- fused: scores (+key histogram) over node blocks; edge degree+count+slot over edge blocks ----------
__global__ void score_hist_kernel(const float* __restrict__ x, const float* __restrict__ p,
                                  float* __restrict__ score, unsigned* __restrict__ keys,
                                  unsigned* __restrict__ bins, const int* __restrict__ ei,
                                  const float* __restrict__ ew,
                                  unsigned long long* __restrict__ cnt64,
                                  int* __restrict__ eslot, int n, int E, int nbScore) {
  if ((int)blockIdx.x >= nbScore) {
    int e = ((int)blockIdx.x - nbScore) * 256 + threadIdx.x;
    if (e < E) {
      int c = ei[E + e];
      unsigned fx = __float2uint_rn(ew[e] * 16777216.0f);  // 2^24 fixed point
      unsigned long long old =
          atomicAdd(&cnt64[c], ((unsigned long long)1 << 32) | (unsigned long long)fx);
      eslot[e] = (int)(old >> 32);  // slot within this col's segment
    }
    return;
  }
  int wib = threadIdx.x >> 6, lane = threadIdx.x & 63;
  int r = blockIdx.x * 4 + wib;
  if (r >= n) return;
  float2 xv = *(const float2*)&x[(size_t)r * NF + lane * 2];
  float2 pv = *(const float2*)&p[lane * 2];
  float d = fmaf(xv.x, pv.x, xv.y * pv.y);
  float pp = fmaf(pv.x, pv.x, pv.y * pv.y);
#pragma unroll
  for (int off = 32; off > 0; off >>= 1) {
    d += __shfl_down(d, off, 64);
    pp += __shfl_down(pp, off, 64);
  }
  if (lane == 0) {
    float s = tanhf(d / sqrtf(pp));
    score[r] = s;
    unsigned k = okey(s);
    keys[r] = k;
    atomicAdd(&bins[k >> 16], 1u);
  }
}

// ---------- find threshold bin: smallest B with count(top16 >= B) >= TK ----------
__global__ __launch_bounds__(1024) void findbin_kernel(const unsigned* __restrict__ bins,
                                                       unsigned* __restrict__ thrB) {
  __shared__ unsigned csum[1024];
  int t = threadIdx.x;
  unsigned s = 0;
  const unsigned* bp = bins + t * 64;
#pragma unroll 8
  for (int b = 0; b < 64; ++b) s += bp[b];
  csum[t] = s;
  __syncthreads();
  if (t == 0) {
    unsigned cum = 0;
    int chunk = 1023;
    for (; chunk > 0; --chunk) {
      if (cum + csum[chunk] >= (unsigned)TK) break;
      cum += csum[chunk];
    }
    unsigned base = (unsigned)chunk * 64;
    int b = 63;
    for (; b > 0; --b) {
      unsigned h = bins[base + b];
      if (cum + h >= (unsigned)TK) break;
      cum += h;
    }
    thrB[0] = base + (unsigned)b;
  }
}

// ---------- scan over counts (block-local exclusive) + dinv + candidate compaction ----------
#define SCAN_B 1024
__global__ __launch_bounds__(1024) void scan1_kernel(const unsigned long long* __restrict__ cnt64,
                                                     int* __restrict__ offL, int* __restrict__ bsum,
                                                     float* __restrict__ dinv,
                                                     const unsigned* __restrict__ keys,
                                                     const unsigned* __restrict__ thrB,
                                                     int* __restrict__ ncnt,
                                                     unsigned* __restrict__ candKey,
                                                     int* __restrict__ candIdx, int n) {
  __shared__ int sd[SCAN_B];
  int t = threadIdx.x;
  int i = blockIdx.x * SCAN_B + t;
  int v = 0;
  if (i < n) {
    unsigned long long cv = cnt64[i];
    v = (int)(cv >> 32);
    float dsum = (float)((unsigned)cv) * (1.0f / 16777216.0f) + 1.0f;  // + self-loop
    dinv[i] = 1.0f / sqrtf(dsum);
    unsigned k = keys[i];
    if ((k >> 16) >= thrB[0]) {
      int pos = atomicAdd(ncnt, 1);
      candKey[pos] = k;
      candIdx[pos] = i;
    }
  }
  sd[t] = v;
  __syncthreads();
  for (int s = 1; s < SCAN_B; s <<= 1) {
    int add = (t >= s) ? sd[t - s] : 0;
    __syncthreads();
    sd[t] += add;
    __syncthreads();
  }
  if (i <= n) offL[i] = sd[t] - v;  // block-local exclusive
  if (t == SCAN_B - 1) bsum[blockIdx.x] = sd[t];
}

// ---------- block 0: wave-scan of bsum -> bexc; block 1: exact top-K select ----------
#define CCAP 6144
__global__ __launch_bounds__(1024) void scan2_select_kernel(const int* __restrict__ bsum,
                                                            int* __restrict__ bexc, int nb,
                                                            const unsigned* __restrict__ candKey,
                                                            const int* __restrict__ candIdx,
                                                            const int* __restrict__ ncp,
                                                            const float* __restrict__ score,
                                                            int* __restrict__ perm,
                                                            float* __restrict__ tsc) {
  if (blockIdx.x == 0) {
    int t = threadIdx.x;
    if (t < 64) {  // requires nb <= 63 (N <= 64K)
      int v = (t < nb) ? bsum[t] : 0;
      int incl = v;
#pragma unroll
      for (int s = 1; s < 64; s <<= 1) {
        int u = __shfl_up(incl, s, 64);
        if (t >= s) incl += u;
      }
      if (t <= nb) bexc[t] = incl - v;
    }
    return;
  }
  __shared__ unsigned sk[CCAP];
  __shared__ int si[CCAP];
  int nc = ncp[0];
  int t = threadIdx.x;
  int m = nc < CCAP ? nc : CCAP;
  for (int i = t; i < m; i += 1024) { sk[i] = candKey[i]; si[i] = candIdx[i]; }
  __syncthreads();
  for (int ci = t; ci < nc; ci += 1024) {
    unsigned mk = (ci < CCAP) ? sk[ci] : candKey[ci];
    int mi = (ci < CCAP) ? si[ci] : candIdx[ci];
    int rank = 0;
    for (int j = 0; j < m; ++j) {
      unsigned kj = sk[j];
      int ij = si[j];
      rank += (kj > mk || (kj == mk && ij < mi)) ? 1 : 0;
    }
    for (int j = CCAP; j < nc; ++j) {
      unsigned kj = candKey[j];
      int ij = candIdx[j];
      rank += (kj > mk || (kj == mk && ij < mi)) ? 1 : 0;
    }
    if (rank < TK) {
      perm[rank] = mi;
      tsc[rank] = score[mi];
    }
  }
}

// ---------- GRU: block per row i, thread per col j ----------
__global__ void gru_kernel(const float* __restrict__ x, const int* __restrict__ perm,
                           const float* __restrict__ tsc, const float* __restrict__ W0,
                           const float* __restrict__ w_ih, const float* __restrict__ w_hh,
                           const float* __restrict__ b_ih, const float* __restrict__ b_hh,
                           float* __restrict__ W) {
  __shared__ float xs[NF], w0s[NF];
  int i = blockIdx.x, j = threadIdx.x;
  int pi = perm[i];
  float s = tsc[i];
  xs[j] = x[(size_t)pi * NF + j] * s;
  w0s[j] = W0[i * NF + j];
  __syncthreads();
  float gir = b_ih[j], giz = b_ih[NF + j], gin = b_ih[2 * NF + j];
  float ghr = b_hh[j], ghz = b_hh[NF + j], ghn = b_hh[2 * NF + j];
  const float* wr = w_ih + (size_t)j * NF;
  const float* wz = w_ih + (size_t)(NF + j) * NF;
  const float* wn = w_ih + (size_t)(2 * NF + j) * NF;
  const float* ur = w_hh + (size_t)j * NF;
  const float* uz = w_hh + (size_t)(NF + j) * NF;
  const float* un = w_hh + (size_t)(2 * NF + j) * NF;
#pragma unroll 4
  for (int k = 0; k < NF; ++k) {
    float xv = xs[k], wv = w0s[k];
    gir = fmaf(xv, wr[k], gir);
    giz = fmaf(xv, wz[k], giz);
    gin = fmaf(xv, wn[k], gin);
    ghr = fmaf(wv, ur[k], ghr);
    ghz = fmaf(wv, uz[k], ghz);
    ghn = fmaf(wv, un[k], ghn);
  }
  float r = 1.0f / (1.0f + expf(-(gir + ghr)));
  float z = 1.0f / (1.0f + expf(-(giz + ghz)));
  float nn = tanhf(gin + r * ghn);
  W[i * NF + j] = (1.0f - z) * nn + z * w0s[j];
}

// ---------- fill CSR: packed (row, coef), slot precomputed -> NO atomics ----------
__global__ void fill_kernel(const int* __restrict__ ei, const float* __restrict__ ew,
                            const float* __restrict__ dinv, const int* __restrict__ offL,
                            const int* __restrict__ bexc, const int* __restrict__ eslot,
                            uint2* __restrict__ epair, int E) {
  int e = blockIdx.x * 256 + threadIdx.x;
  if (e >= E) return;
  int r = ei[e], c = ei[E + e];
  int pos = offL[c] + bexc[c >> 10] + eslot[e];
  float cf = dinv[r] * ew[e] * dinv[c];
  epair[pos] = make_uint2((unsigned)r, __float_as_uint(cf));
}

// ---------- aggregate: one wave per node, 4 edges in flight (quarter-wave gathers) ----------
__global__ void aggregate_kernel(const uint2* __restrict__ epair, const int* __restrict__ offL,
                                 const int* __restrict__ bexc, const float* __restrict__ dinv,
                                 const uint4* __restrict__ xw4, float* __restrict__ h, int n) {
  int w = (int)((blockIdx.x * (size_t)blockDim.x + threadIdx.x) >> 6);
  if (w >= n) return;
  int lane = threadIdx.x & 63;
  int q = lane >> 4, l16 = lane & 15;
  int n0 = offL[w] + bexc[w >> 10];
  int n1 = offL[w + 1] + bexc[(w + 1) >> 10];
  float acc[8] = {0.f, 0.f, 0.f, 0.f, 0.f, 0.f, 0.f, 0.f};
  if (q == 0) {
    float dv = dinv[w];
    float c2 = dv * dv;  // self-loop: dinv[i]*1.0*dinv[i]
    uint4 su = xw4[(size_t)w * 16 + l16];
    float2 f0 = __half22float2(*(const __half2*)&su.x);
    float2 f1 = __half22float2(*(const __half2*)&su.y);
    float2 f2 = __half22float2(*(const __half2*)&su.z);
    float2 f3 = __half22float2(*(const __half2*)&su.w);
    acc[0] = c2 * f0.x; acc[1] = c2 * f0.y; acc[2] = c2 * f1.x; acc[3] = c2 * f1.y;
    acc[4] = c2 * f2.x; acc[5] = c2 * f2.y; acc[6] = c2 * f3.x; acc[7] = c2 * f3.y;
  }
  for (int e = n0 + q; e < n1; e += 4) {
    uint2 pr = epair[e];
    float cf = __uint_as_float(pr.y);
    uint4 u = xw4[(size_t)pr.x * 16 + l16];
    float2 f0 = __half22float2(*(const __half2*)&u.x);
    float2 f1 = __half22float2(*(const __half2*)&u.y);
    float2 f2 = __half22float2(*(const __half2*)&u.z);
    float2 f3 = __half22float2(*(const __half2*)&u.w);
    acc[0] = fmaf(cf, f0.x, acc[0]); acc[1] = fmaf(cf, f0.y, acc[1]);
    acc[2] = fmaf(cf, f1.x, acc[2]); acc[3] = fmaf(cf, f1.y, acc[3]);
    acc[4] = fmaf(cf, f2.x, acc[4]); acc[5] = fmaf(cf, f2.y, acc[5]);
    acc[6] = fmaf(cf, f3.x, acc[6]); acc[7] = fmaf(cf, f3.y, acc[7]);
  }
#pragma unroll
  for (int j = 0; j < 8; ++j) {
    float a = acc[j];
    a += __shfl_xor(a, 16, 64);
    a += __shfl_xor(a, 32, 64);
    acc[j] = a;
  }
  if (q == 0) {
    *(float4*)&h[(size_t)w * NF + l16 * 8] = make_float4(acc[0], acc[1], acc[2], acc[3]);
    *(float4*)&h[(size_t)w * NF + l16 * 8 + 4] = make_float4(acc[4], acc[5], acc[6], acc[7]);
  }
}

// ---------- GEMM: C[r,c] = sum_k op(A[r,k]) * B[k,c] (+bias), B is 128x128 ----------
template <int RELU, int BIAS, int HOUT>
__global__ __launch_bounds__(256) void gemm128_kernel(const float* __restrict__ A,
                                                      const float* __restrict__ Bm,
                                                      const float* __restrict__ bias,
                                                      float* __restrict__ C, int nrows) {
  __shared__ float Bs[64][128];
  __shared__ float As[64][68];  // [k][r], padded
  const int t = threadIdx.x;
  const int ct = t & 31;   // 4-col group
  const int rt = t >> 5;   // 0..7 -> rows rt*8..rt*8+7
  const int row0 = blockIdx.x * 64;
  float4 acc[8];
#pragma unroll
  for (int j = 0; j < 8; ++j) acc[j] = make_float4(0.f, 0.f, 0.f, 0.f);

  for (int ph = 0; ph < 2; ++ph) {
    {
      const float4* B4 = (const float4*)(Bm + ph * 64 * NF);
#pragma unroll
      for (int pp = 0; pp < 8; ++pp) {
        int idx = pp * 256 + t;  // 0..2047
        int k = idx >> 5, c4 = idx & 31;
        *((float4*)&Bs[k][c4 * 4]) = B4[idx];
      }
    }
    {
#pragma unroll
      for (int pp = 0; pp < 4; ++pp) {
        int idx = pp * 256 + t;  // 0..1023
        int r = idx >> 4;        // 0..63
        int k4 = idx & 15;       // col group
        int gr = row0 + r;
        float4 v = make_float4(0.f, 0.f, 0.f, 0.f);
        if (gr < nrows) v = *((const float4*)&A[(size_t)gr * NF + ph * 64 + k4 * 4]);
        if (RELU) {
          v.x = fmaxf(v.x, 0.f); v.y = fmaxf(v.y, 0.f);
          v.z = fmaxf(v.z, 0.f); v.w = fmaxf(v.w, 0.f);
        }
        As[k4 * 4 + 0][r] = v.x;
        As[k4 * 4 + 1][r] = v.y;
        As[k4 * 4 + 2][r] = v.z;
        As[k4 * 4 + 3][r] = v.w;
      }
    }
    __syncthreads();
#pragma unroll 4
    for (int k = 0; k < 64; ++k) {
      float4 b = *((const float4*)&Bs[k][ct * 4]);
      float a[8];
      *((float4*)&a[0]) = *((const float4*)&As[k][rt * 8]);
      *((float4*)&a[4]) = *((const float4*)&As[k][rt * 8 + 4]);
#pragma unroll
      for (int j = 0; j < 8; ++j) {
        acc[j].x = fmaf(a[j], b.x, acc[j].x);
        acc[j].y = fmaf(a[j], b.y, acc[j].y);
        acc[j].z = fmaf(a[j], b.z, acc[j].z);
        acc[j].w = fmaf(a[j], b.w, acc[j].w);
      }
    }
    __syncthreads();
  }
  float4 bv = make_float4(0.f, 0.f, 0.f, 0.f);
  if (BIAS) bv = *((const float4*)&bias[ct * 4]);
#pragma unroll
  for (int j = 0; j < 8; ++j) {
    int gr = row0 + rt * 8 + j;
    if (gr < nrows) {
      float4 o = acc[j];
      if (BIAS) { o.x += bv.x; o.y += bv.y; o.z += bv.z; o.w += bv.w; }
      if (HOUT) {
        uint2 pk = pack_half4(o);
        *reinterpret_cast<uint2*>((char*)C + ((size_t)gr * NF + ct * 4) * 2) = pk;
      } else {
        *((float4*)&C[(size_t)gr * NF + ct * 4]) = o;
      }
    }
  }
}

extern "C" void kernel_launch(void* const* d_in, const int* in_sizes, int n_in,
                              void* d_out, int out_size, void* d_ws, size_t ws_size,
                              hipStream_t stream) {
  const float* x = (const float*)d_in[0];
  const int* ei = (const int*)d_in[1];
  const float* ew = (const float*)d_in[2];
  const float* p = (const float*)d_in[3];
  const float* w_ih = (const float*)d_in[4];
  const float* w_hh = (const float*)d_in[5];
  const float* b_ih = (const float*)d_in[6];
  const float* b_hh = (const float*)d_in[7];
  const float* W0 = (const float*)d_in[8];
  const float* W_lin = (const float*)d_in[9];
  const float* b_lin = (const float*)d_in[10];
  float* out = (float*)d_out;

  const int N = in_sizes[0] / NF;  // 50000
  const int E = in_sizes[1] / 2;   // 800000

  char* w = (char*)d_ws;
  unsigned* xwh = (unsigned*)w;                             // N*64 uints (fp16 xw)
  float* score = (float*)(xwh + (size_t)N * 64);            // N
  unsigned* keys = (unsigned*)(score + N);                  // N
  unsigned long long* cnt64 = (unsigned long long*)(keys + N);  // ZERO region: N x 8B (8-aligned)
  unsigned* bins = (unsigned*)(cnt64 + N);                  // 65536
  int* ncnt = (int*)(bins + 65536);                         // 1 (end of ZERO region)
  float* dinv = (float*)(ncnt + 1);                         // N
  unsigned* thrB = (unsigned*)(dinv + N);                   // 1
  unsigned* candKey = thrB + 1;                             // N
  int* candIdx = (int*)(candKey + N);                       // N
  int* offL = candIdx + N;                                  // N+1
  int* bsum = offL + N + 1;                                 // 64
  int* bexc = bsum + 64;                                    // 64
  int* eslot = bexc + 64;                                   // E
  uint2* epair = (uint2*)(((uintptr_t)(eslot + E) + 15) & ~(uintptr_t)15);  // E
  float* Wev = (float*)(epair + E);                         // 128*128
  float* wlt = Wev + NF * NF;                               // 128*128
  int* perm = (int*)(wlt + NF * NF);                        // 128
  float* tsc = (float*)(perm + NF);                         // 128

  const int nb = (N + SCAN_B - 1) / SCAN_B;
  const int nbScore = (N + 3) / 4;
  const int nbEdge = (E + 255) / 256;

  hipMemsetAsync(cnt64, 0, (size_t)N * 8 + 65536 * 4 + 4, stream);  // cnt64,bins,ncnt
  prep_kernel<<<1, 256, 0, stream>>>(W_lin, wlt);
  score_hist_kernel<<<nbScore + nbEdge, 256, 0, stream>>>(x, p, score, keys, bins, ei, ew,
                                                          cnt64, eslot, N, E, nbScore);
  findbin_kernel<<<1, 1024, 0, stream>>>(bins, thrB);
  scan1_kernel<<<nb, SCAN_B, 0, stream>>>(cnt64, offL, bsum, dinv, keys, thrB, ncnt,
                                          candKey, candIdx, N);
  scan2_select_kernel<<<2, 1024, 0, stream>>>(bsum, bexc, nb, candKey, candIdx, ncnt, score,
                                              perm, tsc);
  gru_kernel<<<NF, NF, 0, stream>>>(x, perm, tsc, W0, w_ih, w_hh, b_ih, b_hh, Wev);
  fill_kernel<<<nbEdge, 256, 0, stream>>>(ei, ew, dinv, offL, bexc, eslot, epair, E);
  gemm128_kernel<0, 0, 1><<<(N + 63) / 64, 256, 0, stream>>>(x, Wev, nullptr, (float*)xwh, N);
  aggregate_kernel<<<(N + 3) / 4, 256, 0, stream>>>(epair, offL, bexc, dinv,
                                                    (const uint4*)xwh, out, N);
  gemm128_kernel<1, 1, 0><<<(N + 63) / 64, 256, 0, stream>>>(out, wlt, b_lin, out, N);
}

// Round 7
// 220.027 us; speedup vs baseline: 1.8800x; 1.2231x over previous
//
#include <hip/hip_runtime.h>
#include <hip/hip_fp16.h>

#define NF 128
#define TK 128

typedef _Float16 f16;
typedef f16 half8 __attribute__((ext_vector_type(8)));
typedef float floatx4 __attribute__((ext_vector_type(4)));

__device__ __forceinline__ unsigned okey(float f) {
  unsigned u = __float_as_uint(f);
  return (u & 0x80000000u) ? ~u : (u | 0x80000000u);
}

// ---------- fused: scores (+key histogram) over node blocks; edge degree+count+slot over edge blocks ----------
__global__ void score_hist_kernel(const float* __restrict__ x, const float* __restrict__ p,
                                  float* __restrict__ score, unsigned* __restrict__ keys,
                                  unsigned* __restrict__ bins, const int* __restrict__ ei,
                                  const float* __restrict__ ew,
                                  unsigned long long* __restrict__ cnt64,
                                  unsigned short* __restrict__ eslot, int n, int E, int nbScore) {
  if ((int)blockIdx.x >= nbScore) {
    int e = ((int)blockIdx.x - nbScore) * 256 + threadIdx.x;
    if (e < E) {
      int c = ei[E + e];
      unsigned fx = __float2uint_rn(ew[e] * 16777216.0f);  // 2^24 fixed point
      unsigned long long old =
          atomicAdd(&cnt64[c], ((unsigned long long)1 << 32) | (unsigned long long)fx);
      eslot[e] = (unsigned short)(old >> 32);  // slot within this col's segment
    }
    return;
  }
  int wib = threadIdx.x >> 6, lane = threadIdx.x & 63;
  int r = blockIdx.x * 4 + wib;
  if (r >= n) return;
  float2 xv = *(const float2*)&x[(size_t)r * NF + lane * 2];
  float2 pv = *(const float2*)&p[lane * 2];
  float d = fmaf(xv.x, pv.x, xv.y * pv.y);
  float pp = fmaf(pv.x, pv.x, pv.y * pv.y);
#pragma unroll
  for (int off = 32; off > 0; off >>= 1) {
    d += __shfl_down(d, off, 64);
    pp += __shfl_down(pp, off, 64);
  }
  if (lane == 0) {
    float s = tanhf(d / sqrtf(pp));
    score[r] = s;
    unsigned k = okey(s);
    keys[r] = k;
    atomicAdd(&bins[k >> 16], 1u);
  }
}

// ---------- find threshold bin (parallel suffix scan) ----------
__global__ __launch_bounds__(1024) void findbin_kernel(const unsigned* __restrict__ bins,
                                                       unsigned* __restrict__ thrB) {
  __shared__ unsigned csum[1024];
  int t = threadIdx.x;
  unsigned hv[64];
  unsigned s = 0;
  const unsigned* bp = bins + t * 64;
#pragma unroll
  for (int b = 0; b < 64; ++b) { hv[b] = bp[b]; s += hv[b]; }
  csum[t] = s;
  __syncthreads();
  for (int st = 1; st < 1024; st <<= 1) {
    unsigned add = (t + st < 1024) ? csum[t + st] : 0u;
    __syncthreads();
    csum[t] += add;
    __syncthreads();
  }
  unsigned mySum = csum[t];
  unsigned above = (t == 1023) ? 0u : csum[t + 1];
  if (mySum >= (unsigned)TK && above < (unsigned)TK) {
    unsigned cum = above;
    int b = 63;
    for (; b > 0; --b) {
      unsigned h = hv[b];
      if (cum + h >= (unsigned)TK) break;
      cum += h;
    }
    thrB[0] = (unsigned)(t * 64 + b);
  }
}

// ---------- scan over counts (block-local exclusive) + dinv + candidate compaction ----------
#define SCAN_B 1024
__global__ __launch_bounds__(1024) void scan1_kernel(const unsigned long long* __restrict__ cnt64,
                                                     int* __restrict__ offL, int* __restrict__ bsum,
                                                     float* __restrict__ dinv,
                                                     const unsigned* __restrict__ keys,
                                                     const unsigned* __restrict__ thrB,
                                                     int* __restrict__ ncnt,
                                                     int* __restrict__ candIdx, int n) {
  __shared__ int sd[SCAN_B];
  int t = threadIdx.x;
  int i = blockIdx.x * SCAN_B + t;
  int v = 0;
  if (i < n) {
    unsigned long long cv = cnt64[i];
    v = (int)(cv >> 32);
    float dsum = (float)((unsigned)cv) * (1.0f / 16777216.0f) + 1.0f;  // + self-loop
    dinv[i] = 1.0f / sqrtf(dsum);
    if ((keys[i] >> 16) >= thrB[0]) {
      int pos = atomicAdd(ncnt, 1);
      candIdx[pos] = i;
    }
  }
  sd[t] = v;
  __syncthreads();
  for (int s = 1; s < SCAN_B; s <<= 1) {
    int add = (t >= s) ? sd[t - s] : 0;
    __syncthreads();
    sd[t] += add;
    __syncthreads();
  }
  if (i <= n) offL[i] = sd[t] - v;  // block-local exclusive
  if (t == SCAN_B - 1) bsum[blockIdx.x] = sd[t];
}

// ---------- block 0: wave-scan of bsum -> bexc; block 1: exact top-K select ----------
#define CCAP 6144
__global__ __launch_bounds__(1024) void scan2_select_kernel(const int* __restrict__ bsum,
                                                            int* __restrict__ bexc, int nb,
                                                            const unsigned* __restrict__ keys,
                                                            const int* __restrict__ candIdx,
                                                            const int* __restrict__ ncp,
                                                            const float* __restrict__ score,
                                                            int* __restrict__ perm,
                                                            float* __restrict__ tsc) {
  if (blockIdx.x == 0) {
    int t = threadIdx.x;
    if (t < 64) {  // requires nb <= 63 (N <= 64K)
      int v = (t < nb) ? bsum[t] : 0;
      int incl = v;
#pragma unroll
      for (int s = 1; s < 64; s <<= 1) {
        int u = __shfl_up(incl, s, 64);
        if (t >= s) incl += u;
      }
      if (t <= nb) bexc[t] = incl - v;
    }
    return;
  }
  __shared__ unsigned sk[CCAP];
  __shared__ int si[CCAP];
  int nc = ncp[0];
  int t = threadIdx.x;
  int m = nc < CCAP ? nc : CCAP;
  for (int i = t; i < m; i += 1024) {
    int ci = candIdx[i];
    si[i] = ci;
    sk[i] = keys[ci];
  }
  __syncthreads();
  for (int ci = t; ci < nc; ci += 1024) {
    unsigned mk;
    int mi;
    if (ci < CCAP) { mk = sk[ci]; mi = si[ci]; }
    else { mi = candIdx[ci]; mk = keys[mi]; }
    int rank = 0;
    for (int j = 0; j < m; ++j) {
      unsigned kj = sk[j];
      int ij = si[j];
      rank += (kj > mk || (kj == mk && ij < mi)) ? 1 : 0;
    }
    for (int j = CCAP; j < nc; ++j) {
      int ij = candIdx[j];
      unsigned kj = keys[ij];
      rank += (kj > mk || (kj == mk && ij < mi)) ? 1 : 0;
    }
    if (rank < TK) {
      perm[rank] = mi;
      tsc[rank] = score[mi];
    }
  }
}

// ---------- GRU: block per row i, thread per col j; writes W TRANSPOSED ----------
__global__ void gru_kernel(const float* __restrict__ x, const int* __restrict__ perm,
                           const float* __restrict__ tsc, const float* __restrict__ W0,
                           const float* __restrict__ w_ih, const float* __restrict__ w_hh,
                           const float* __restrict__ b_ih, const float* __restrict__ b_hh,
                           float* __restrict__ WT) {
  __shared__ float xs[NF], w0s[NF];
  int i = blockIdx.x, j = threadIdx.x;
  int pi = perm[i];
  float s = tsc[i];
  xs[j] = x[(size_t)pi * NF + j] * s;
  w0s[j] = W0[i * NF + j];
  __syncthreads();
  float gir = b_ih[j], giz = b_ih[NF + j], gin = b_ih[2 * NF + j];
  float ghr = b_hh[j], ghz = b_hh[NF + j], ghn = b_hh[2 * NF + j];
  const float* wr = w_ih + (size_t)j * NF;
  const float* wz = w_ih + (size_t)(NF + j) * NF;
  const float* wn = w_ih + (size_t)(2 * NF + j) * NF;
  const float* ur = w_hh + (size_t)j * NF;
  const float* uz = w_hh + (size_t)(NF + j) * NF;
  const float* un = w_hh + (size_t)(2 * NF + j) * NF;
#pragma unroll 4
  for (int k = 0; k < NF; ++k) {
    float xv = xs[k], wv = w0s[k];
    gir = fmaf(xv, wr[k], gir);
    giz = fmaf(xv, wz[k], giz);
    gin = fmaf(xv, wn[k], gin);
    ghr = fmaf(wv, ur[k], ghr);
    ghz = fmaf(wv, uz[k], ghz);
    ghn = fmaf(wv, un[k], ghn);
  }
  float r = 1.0f / (1.0f + expf(-(gir + ghr)));
  float z = 1.0f / (1.0f + expf(-(giz + ghz)));
  float nn = tanhf(gin + r * ghn);
  WT[(size_t)j * NF + i] = (1.0f - z) * nn + z * w0s[j];  // transposed: WT[n][k]
}

// ---------- fill CSR: packed 4B (row:16 | coef:fp16), slot precomputed -> NO atomics ----------
__global__ void fill_kernel(const int* __restrict__ ei, const float* __restrict__ ew,
                            const float* __restrict__ dinv, const int* __restrict__ offL,
                            const int* __restrict__ bexc, const unsigned short* __restrict__ eslot,
                            unsigned* __restrict__ epair, int E) {
  int e = blockIdx.x * 256 + threadIdx.x;
  if (e >= E) return;
  int r = ei[e], c = ei[E + e];
  int pos = offL[c] + bexc[c >> 10] + (int)eslot[e];
  float cf = dinv[r] * ew[e] * dinv[c];
  unsigned hb = (unsigned)__builtin_bit_cast(unsigned short, __float2half(cf));
  epair[pos] = (unsigned)r | (hb << 16);
}

// ---------- aggregate: one wave per node, 8 gathers in flight, relu + fp16 out ----------
__global__ void aggregate_kernel(const unsigned* __restrict__ epair, const int* __restrict__ offL,
                                 const int* __restrict__ bexc, const float* __restrict__ dinv,
                                 const uint4* __restrict__ xw4, unsigned* __restrict__ hh, int n) {
  int w = (int)((blockIdx.x * (size_t)blockDim.x + threadIdx.x) >> 6);
  if (w >= n) return;
  int lane = threadIdx.x & 63;
  int q = lane >> 4, l16 = lane & 15;
  int n0 = offL[w] + bexc[w >> 10];
  int n1 = offL[w + 1] + bexc[(w + 1) >> 10];
  float acc[8] = {0.f, 0.f, 0.f, 0.f, 0.f, 0.f, 0.f, 0.f};
  if (q == 0) {
    float dv = dinv[w];
    float c2 = dv * dv;  // self-loop: dinv[i]*1.0*dinv[i]
    uint4 su = xw4[(size_t)w * 16 + l16];
    float2 f0 = __half22float2(*(const __half2*)&su.x);
    float2 f1 = __half22float2(*(const __half2*)&su.y);
    float2 f2 = __half22float2(*(const __half2*)&su.z);
    float2 f3 = __half22float2(*(const __half2*)&su.w);
    acc[0] = c2 * f0.x; acc[1] = c2 * f0.y; acc[2] = c2 * f1.x; acc[3] = c2 * f1.y;
    acc[4] = c2 * f2.x; acc[5] = c2 * f2.y; acc[6] = c2 * f3.x; acc[7] = c2 * f3.y;
  }
  int e = n0 + q;
  for (; e + 4 < n1; e += 8) {
    unsigned p0 = epair[e], p1 = epair[e + 4];
    uint4 u0 = xw4[(size_t)(p0 & 0xFFFFu) * 16 + l16];
    uint4 u1 = xw4[(size_t)(p1 & 0xFFFFu) * 16 + l16];
    float c0 = __half2float(__builtin_bit_cast(__half, (unsigned short)(p0 >> 16)));
    float c1 = __half2float(__builtin_bit_cast(__half, (unsigned short)(p1 >> 16)));
    float2 f0, f1, f2, f3;
    f0 = __half22float2(*(const __half2*)&u0.x); f1 = __half22float2(*(const __half2*)&u0.y);
    f2 = __half22float2(*(const __half2*)&u0.z); f3 = __half22float2(*(const __half2*)&u0.w);
    acc[0] = fmaf(c0, f0.x, acc[0]); acc[1] = fmaf(c0, f0.y, acc[1]);
    acc[2] = fmaf(c0, f1.x, acc[2]); acc[3] = fmaf(c0, f1.y, acc[3]);
    acc[4] = fmaf(c0, f2.x, acc[4]); acc[5] = fmaf(c0, f2.y, acc[5]);
    acc[6] = fmaf(c0, f3.x, acc[6]); acc[7] = fmaf(c0, f3.y, acc[7]);
    f0 = __half22float2(*(const __half2*)&u1.x); f1 = __half22float2(*(const __half2*)&u1.y);
    f2 = __half22float2(*(const __half2*)&u1.z); f3 = __half22float2(*(const __half2*)&u1.w);
    acc[0] = fmaf(c1, f0.x, acc[0]); acc[1] = fmaf(c1, f0.y, acc[1]);
    acc[2] = fmaf(c1, f1.x, acc[2]); acc[3] = fmaf(c1, f1.y, acc[3]);
    acc[4] = fmaf(c1, f2.x, acc[4]); acc[5] = fmaf(c1, f2.y, acc[5]);
    acc[6] = fmaf(c1, f3.x, acc[6]); acc[7] = fmaf(c1, f3.y, acc[7]);
  }
  for (; e < n1; e += 4) {
    unsigned p0 = epair[e];
    uint4 u0 = xw4[(size_t)(p0 & 0xFFFFu) * 16 + l16];
    float c0 = __half2float(__builtin_bit_cast(__half, (unsigned short)(p0 >> 16)));
    float2 f0 = __half22float2(*(const __half2*)&u0.x);
    float2 f1 = __half22float2(*(const __half2*)&u0.y);
    float2 f2 = __half22float2(*(const __half2*)&u0.z);
    float2 f3 = __half22float2(*(const __half2*)&u0.w);
    acc[0] = fmaf(c0, f0.x, acc[0]); acc[1] = fmaf(c0, f0.y, acc[1]);
    acc[2] = fmaf(c0, f1.x, acc[2]); acc[3] = fmaf(c0, f1.y, acc[3]);
    acc[4] = fmaf(c0, f2.x, acc[4]); acc[5] = fmaf(c0, f2.y, acc[5]);
    acc[6] = fmaf(c0, f3.x, acc[6]); acc[7] = fmaf(c0, f3.y, acc[7]);
  }
#pragma unroll
  for (int j = 0; j < 8; ++j) {
    float a = acc[j];
    a += __shfl_xor(a, 16, 64);
    a += __shfl_xor(a, 32, 64);
    acc[j] = a;
  }
  if (q == 0) {
    __half2 h0 = __floats2half2_rn(fmaxf(acc[0], 0.f), fmaxf(acc[1], 0.f));
    __half2 h1 = __floats2half2_rn(fmaxf(acc[2], 0.f), fmaxf(acc[3], 0.f));
    __half2 h2 = __floats2half2_rn(fmaxf(acc[4], 0.f), fmaxf(acc[5], 0.f));
    __half2 h3 = __floats2half2_rn(fmaxf(acc[6], 0.f), fmaxf(acc[7], 0.f));
    uint4 o;
    o.x = *(unsigned*)&h0; o.y = *(unsigned*)&h1; o.z = *(unsigned*)&h2; o.w = *(unsigned*)&h3;
    *(uint4*)&hh[(size_t)w * 64 + l16 * 4] = o;
  }
}

// ---------- MFMA GEMM: C[m][n] = sum_k A[m][k]*Bt[n][k]  (fp16 mfma, f32 accum) ----------
// HIN: A is fp16 (uint-packed) else f32. HOUT: C fp16 else f32. BIAS adds bias[n].
template <int HIN, int HOUT, int BIAS>
__global__ __launch_bounds__(256) void gemm_mfma_kernel(const void* __restrict__ Ap,
                                                        const float* __restrict__ Bt,
                                                        const float* __restrict__ bias,
                                                        void* __restrict__ Cp, int nrows) {
  __shared__ char ldsA[64 * 256];   // 64 rows x 128 f16, XOR-swizzled
  __shared__ char ldsB[128 * 256];  // 128 n-rows x 128 f16, XOR-swizzled
  const int t = threadIdx.x;
  const int row0 = blockIdx.x * 64;
  {  // stage Bt -> fp16 LDS
    const float2* B2 = (const float2*)Bt;
#pragma unroll
    for (int i = 0; i < 32; ++i) {
      int idx = i * 256 + t;  // 0..8191
      int nn = idx >> 6, kp = idx & 63;
      float2 v = B2[idx];
      __half2 h = __floats2half2_rn(v.x, v.y);
      int byte = (nn * 256 + kp * 4) ^ ((nn & 7) << 4);
      *(unsigned*)&ldsB[byte] = *(unsigned*)&h;
    }
  }
  if (HIN) {  // A already fp16
    const unsigned* Ah = (const unsigned*)Ap;
#pragma unroll
    for (int i = 0; i < 16; ++i) {
      int idx = i * 256 + t;  // 0..4095
      int r = idx >> 6, cp = idx & 63;
      int gr = row0 + r;
      unsigned v = (gr < nrows) ? Ah[(size_t)gr * 64 + cp] : 0u;
      int byte = (r * 256 + cp * 4) ^ ((r & 7) << 4);
      *(unsigned*)&ldsA[byte] = v;
    }
  } else {  // A f32 -> fp16
    const float2* A2 = (const float2*)Ap;
#pragma unroll
    for (int i = 0; i < 16; ++i) {
      int idx = i * 256 + t;
      int r = idx >> 6, cp = idx & 63;
      int gr = row0 + r;
      float2 v = make_float2(0.f, 0.f);
      if (gr < nrows) v = A2[(size_t)gr * 64 + cp];
      __half2 h = __floats2half2_rn(v.x, v.y);
      int byte = (r * 256 + cp * 4) ^ ((r & 7) << 4);
      *(unsigned*)&ldsA[byte] = *(unsigned*)&h;
    }
  }
  __syncthreads();
  const int wave = t >> 6, l = t & 63;
  const int wr0 = wave * 16;
  const int lm = l & 15, q = l >> 4;
  floatx4 acc[8];
#pragma unroll
  for (int nt = 0; nt < 8; ++nt) acc[nt] = (floatx4){0.f, 0.f, 0.f, 0.f};
#pragma unroll
  for (int ks = 0; ks < 4; ++ks) {
    int arow = wr0 + lm;
    half8 a = *(const half8*)&ldsA[(arow * 256 + ks * 64 + q * 16) ^ ((arow & 7) << 4)];
#pragma unroll
    for (int nt = 0; nt < 8; ++nt) {
      int nn = nt * 16 + lm;
      half8 b = *(const half8*)&ldsB[(nn * 256 + ks * 64 + q * 16) ^ ((nn & 7) << 4)];
      acc[nt] = __builtin_amdgcn_mfma_f32_16x16x32_f16(a, b, acc[nt], 0, 0, 0);
    }
  }
#pragma unroll
  for (int nt = 0; nt < 8; ++nt) {
    int col = nt * 16 + lm;
    float bv = BIAS ? bias[col] : 0.f;
#pragma unroll
    for (int r = 0; r < 4; ++r) {
      int gr = row0 + wr0 + q * 4 + r;
      if (gr < nrows) {
        float v = acc[nt][r] + bv;
        if (HOUT) ((__half*)Cp)[(size_t)gr * NF + col] = __float2half(v);
        else ((float*)Cp)[(size_t)gr * NF + col] = v;
      }
    }
  }
}

extern "C" void kernel_launch(void* const* d_in, const int* in_sizes, int n_in,
                              void* d_out, int out_size, void* d_ws, size_t ws_size,
                              hipStream_t stream) {
  const float* x = (const float*)d_in[0];
  const int* ei = (const int*)d_in[1];
  const float* ew = (const float*)d_in[2];
  const float* p = (const float*)d_in[3];
  const float* w_ih = (const float*)d_in[4];
  const float* w_hh = (const float*)d_in[5];
  const float* b_ih = (const float*)d_in[6];
  const float* b_hh = (const float*)d_in[7];
  const float* W0 = (const float*)d_in[8];
  const float* W_lin = (const float*)d_in[9];
  const float* b_lin = (const float*)d_in[10];
  float* out = (float*)d_out;

  const int N = in_sizes[0] / NF;  // 50000 (< 65536 required for 16-bit rows)
  const int E = in_sizes[1] / 2;   // 800000

  char* w = (char*)d_ws;
  unsigned* xwh = (unsigned*)w;                                 // N*64 (fp16 xw)
  unsigned* hh = xwh + (size_t)N * 64;                          // N*64 (fp16 relu(h))
  float* score = (float*)(hh + (size_t)N * 64);                 // N
  unsigned* keys = (unsigned*)(score + N);                      // N
  unsigned long long* cnt64 = (unsigned long long*)(keys + N);  // ZERO region: N x 8B
  unsigned* bins = (unsigned*)(cnt64 + N);                      // 65536
  int* ncnt = (int*)(bins + 65536);                             // 1 (end of ZERO region)
  float* dinv = (float*)(ncnt + 1);                             // N
  unsigned* thrB = (unsigned*)(dinv + N);                       // 1
  int* candIdx = (int*)(thrB + 1);                              // N
  int* offL = candIdx + N;                                      // N+1
  int* bsum = offL + N + 1;                                     // 64
  int* bexc = bsum + 64;                                        // 64
  unsigned short* eslot = (unsigned short*)(bexc + 64);         // E x 2B
  unsigned* epair = (unsigned*)(eslot + E);                     // E x 4B
  float* WevT = (float*)(epair + E);                            // 128*128
  int* perm = (int*)(WevT + NF * NF);                           // 128
  float* tsc = (float*)(perm + NF);                             // 128

  const int nb = (N + SCAN_B - 1) / SCAN_B;
  const int nbScore = (N + 3) / 4;
  const int nbEdge = (E + 255) / 256;
  const int nbGemm = (N + 63) / 64;

  hipMemsetAsync(cnt64, 0, (size_t)N * 8 + 65536 * 4 + 4, stream);  // cnt64,bins,ncnt
  score_hist_kernel<<<nbScore + nbEdge, 256, 0, stream>>>(x, p, score, keys, bins, ei, ew,
                                                          cnt64, eslot, N, E, nbScore);
  findbin_kernel<<<1, 1024, 0, stream>>>(bins, thrB);
  scan1_kernel<<<nb, SCAN_B, 0, stream>>>(cnt64, offL, bsum, dinv, keys, thrB, ncnt,
                                          candIdx, N);
  scan2_select_kernel<<<2, 1024, 0, stream>>>(bsum, bexc, nb, keys, candIdx, ncnt, score,
                                              perm, tsc);
  gru_kernel<<<NF, NF, 0, stream>>>(x, perm, tsc, W0, w_ih, w_hh, b_ih, b_hh, WevT);
  fill_kernel<<<nbEdge, 256, 0, stream>>>(ei, ew, dinv, offL, bexc, eslot, epair, E);
  gemm_mfma_kernel<0, 1, 0><<<nbGemm, 256, 0, stream>>>(x, WevT, nullptr, xwh, N);
  aggregate_kernel<<<(N + 3) / 4, 256, 0, stream>>>(epair, offL, bexc, dinv,
                                                    (const uint4*)xwh, hh, N);
  gemm_mfma_kernel<1, 0, 1><<<nbGemm, 256, 0, stream>>>(hh, W_lin, b_lin, out, N);
}

// Round 8
// 217.906 us; speedup vs baseline: 1.8982x; 1.0097x over previous
//
#include <hip/hip_runtime.h>
#include <hip/hip_fp16.h>

#define NF 128
#define TK 128

typedef _Float16 f16;
typedef f16 half8 __attribute__((ext_vector_type(8)));
typedef float floatx4 __attribute__((ext_vector_type(4)));

__device__ __forceinline__ unsigned okey(float f) {
  unsigned u = __float_as_uint(f);
  return (u & 0x80000000u) ? ~u : (u | 0x80000000u);
}

// edge-histogram slice: one edge per thread
__device__ __forceinline__ void edge_slice(const int* __restrict__ ei, const float* __restrict__ ew,
                                           unsigned long long* __restrict__ cnt64,
                                           unsigned short* __restrict__ eslot, int E, int e, int elim) {
  if (e < elim) {
    int c = ei[E + e];
    unsigned fx = __float2uint_rn(ew[e] * 16777216.0f);  // 2^24 fixed point
    unsigned long long old =
        atomicAdd(&cnt64[c], ((unsigned long long)1 << 32) | (unsigned long long)fx);
    eslot[e] = (unsigned short)(old >> 32);
  }
}

// ---------- scores + key histogram (node-only) ----------
__global__ void score_kernel(const float* __restrict__ x, const float* __restrict__ p,
                             float* __restrict__ score, unsigned* __restrict__ keys,
                             unsigned* __restrict__ bins, int n) {
  int wib = threadIdx.x >> 6, lane = threadIdx.x & 63;
  int r = blockIdx.x * 4 + wib;
  if (r >= n) return;
  float2 xv = *(const float2*)&x[(size_t)r * NF + lane * 2];
  float2 pv = *(const float2*)&p[lane * 2];
  float d = fmaf(xv.x, pv.x, xv.y * pv.y);
  float pp = fmaf(pv.x, pv.x, pv.y * pv.y);
#pragma unroll
  for (int off = 32; off > 0; off >>= 1) {
    d += __shfl_down(d, off, 64);
    pp += __shfl_down(pp, off, 64);
  }
  if (lane == 0) {
    float s = tanhf(d / sqrtf(pp));
    score[r] = s;
    unsigned k = okey(s);
    keys[r] = k;
    atomicAdd(&bins[k >> 16], 1u);
  }
}

// ---------- findbin (block 0) + edge slice ----------
__global__ __launch_bounds__(1024) void findbin_edge_kernel(const unsigned* __restrict__ bins,
                                                            unsigned* __restrict__ thrB,
                                                            const int* __restrict__ ei,
                                                            const float* __restrict__ ew,
                                                            unsigned long long* __restrict__ cnt64,
                                                            unsigned short* __restrict__ eslot,
                                                            int E, int ebase, int elim) {
  if (blockIdx.x > 0) {
    edge_slice(ei, ew, cnt64, eslot, E, ebase + ((int)blockIdx.x - 1) * 1024 + (int)threadIdx.x, elim);
    return;
  }
  __shared__ unsigned csum[1024];
  int t = threadIdx.x;
  unsigned hv[64];
  unsigned s = 0;
  const unsigned* bp = bins + t * 64;
#pragma unroll
  for (int b = 0; b < 64; ++b) { hv[b] = bp[b]; s += hv[b]; }
  csum[t] = s;
  __syncthreads();
  for (int st = 1; st < 1024; st <<= 1) {
    unsigned add = (t + st < 1024) ? csum[t + st] : 0u;
    __syncthreads();
    csum[t] += add;
    __syncthreads();
  }
  unsigned mySum = csum[t];
  unsigned above = (t == 1023) ? 0u : csum[t + 1];
  if (mySum >= (unsigned)TK && above < (unsigned)TK) {
    unsigned cum = above;
    int b = 63;
    for (; b > 0; --b) {
      unsigned h = hv[b];
      if (cum + h >= (unsigned)TK) break;
      cum += h;
    }
    thrB[0] = (unsigned)(t * 64 + b);
  }
}

// ---------- compact candidates (blocks < nOwn) + edge slice ----------
__global__ __launch_bounds__(1024) void compact_edge_kernel(const unsigned* __restrict__ keys,
                                                            const unsigned* __restrict__ thrB,
                                                            int* __restrict__ ncnt,
                                                            int* __restrict__ candIdx, int n, int nOwn,
                                                            const int* __restrict__ ei,
                                                            const float* __restrict__ ew,
                                                            unsigned long long* __restrict__ cnt64,
                                                            unsigned short* __restrict__ eslot,
                                                            int E, int ebase, int elim) {
  if ((int)blockIdx.x >= nOwn) {
    edge_slice(ei, ew, cnt64, eslot, E,
               ebase + ((int)blockIdx.x - nOwn) * 1024 + (int)threadIdx.x, elim);
    return;
  }
  int i = blockIdx.x * 1024 + threadIdx.x;
  if (i < n) {
    if ((keys[i] >> 16) >= thrB[0]) {
      int pos = atomicAdd(ncnt, 1);
      candIdx[pos] = i;
    }
  }
}

// ---------- exact top-K select (block 0) + edge slice ----------
#define CCAP 6144
__global__ __launch_bounds__(1024) void select_edge_kernel(const unsigned* __restrict__ keys,
                                                           const int* __restrict__ candIdx,
                                                           const int* __restrict__ ncp,
                                                           const float* __restrict__ score,
                                                           int* __restrict__ perm,
                                                           float* __restrict__ tsc,
                                                           const int* __restrict__ ei,
                                                           const float* __restrict__ ew,
                                                           unsigned long long* __restrict__ cnt64,
                                                           unsigned short* __restrict__ eslot,
                                                           int E, int ebase, int elim) {
  if (blockIdx.x > 0) {
    edge_slice(ei, ew, cnt64, eslot, E, ebase + ((int)blockIdx.x - 1) * 1024 + (int)threadIdx.x, elim);
    return;
  }
  __shared__ unsigned sk[CCAP];
  __shared__ int si[CCAP];
  int nc = ncp[0];
  int t = threadIdx.x;
  int m = nc < CCAP ? nc : CCAP;
  for (int i = t; i < m; i += 1024) {
    int ci = candIdx[i];
    si[i] = ci;
    sk[i] = keys[ci];
  }
  __syncthreads();
  for (int ci = t; ci < nc; ci += 1024) {
    unsigned mk;
    int mi;
    if (ci < CCAP) { mk = sk[ci]; mi = si[ci]; }
    else { mi = candIdx[ci]; mk = keys[mi]; }
    int rank = 0;
    for (int j = 0; j < m; ++j) {
      unsigned kj = sk[j];
      int ij = si[j];
      rank += (kj > mk || (kj == mk && ij < mi)) ? 1 : 0;
    }
    for (int j = CCAP; j < nc; ++j) {
      int ij = candIdx[j];
      unsigned kj = keys[ij];
      rank += (kj > mk || (kj == mk && ij < mi)) ? 1 : 0;
    }
    if (rank < TK) {
      perm[rank] = mi;
      tsc[rank] = score[mi];
    }
  }
}

// ---------- GRU (blocks < 128, 128 thr) + edge slice; writes W transposed ----------
__global__ void gru_edge_kernel(const float* __restrict__ x, const int* __restrict__ perm,
                                const float* __restrict__ tsc, const float* __restrict__ W0,
                                const float* __restrict__ w_ih, const float* __restrict__ w_hh,
                                const float* __restrict__ b_ih, const float* __restrict__ b_hh,
                                float* __restrict__ WT,
                                const int* __restrict__ ei, const float* __restrict__ ew,
                                unsigned long long* __restrict__ cnt64,
                                unsigned short* __restrict__ eslot, int E, int ebase, int elim) {
  if ((int)blockIdx.x >= NF) {
    edge_slice(ei, ew, cnt64, eslot, E, ebase + ((int)blockIdx.x - NF) * 128 + (int)threadIdx.x, elim);
    return;
  }
  __shared__ float xs[NF], w0s[NF];
  int i = blockIdx.x, j = threadIdx.x;
  int pi = perm[i];
  float s = tsc[i];
  xs[j] = x[(size_t)pi * NF + j] * s;
  w0s[j] = W0[i * NF + j];
  __syncthreads();
  float gir = b_ih[j], giz = b_ih[NF + j], gin = b_ih[2 * NF + j];
  float ghr = b_hh[j], ghz = b_hh[NF + j], ghn = b_hh[2 * NF + j];
  const float* wr = w_ih + (size_t)j * NF;
  const float* wz = w_ih + (size_t)(NF + j) * NF;
  const float* wn = w_ih + (size_t)(2 * NF + j) * NF;
  const float* ur = w_hh + (size_t)j * NF;
  const float* uz = w_hh + (size_t)(NF + j) * NF;
  const float* un = w_hh + (size_t)(2 * NF + j) * NF;
#pragma unroll 4
  for (int k = 0; k < NF; ++k) {
    float xv = xs[k], wv = w0s[k];
    gir = fmaf(xv, wr[k], gir);
    giz = fmaf(xv, wz[k], giz);
    gin = fmaf(xv, wn[k], gin);
    ghr = fmaf(wv, ur[k], ghr);
    ghz = fmaf(wv, uz[k], ghz);
    ghn = fmaf(wv, un[k], ghn);
  }
  float r = 1.0f / (1.0f + expf(-(gir + ghr)));
  float z = 1.0f / (1.0f + expf(-(giz + ghz)));
  float nn = tanhf(gin + r * ghn);
  WT[(size_t)j * NF + i] = (1.0f - z) * nn + z * w0s[j];  // transposed: WT[n][k]
}

// ---------- scan over counts (block-local exclusive) + dinv ----------
#define SCAN_B 1024
__global__ __launch_bounds__(1024) void scan1_kernel(const unsigned long long* __restrict__ cnt64,
                                                     int* __restrict__ offL, int* __restrict__ bsum,
                                                     float* __restrict__ dinv, int n) {
  __shared__ int sd[SCAN_B];
  int t = threadIdx.x;
  int i = blockIdx.x * SCAN_B + t;
  int v = 0;
  if (i < n) {
    unsigned long long cv = cnt64[i];
    v = (int)(cv >> 32);
    float dsum = (float)((unsigned)cv) * (1.0f / 16777216.0f) + 1.0f;  // + self-loop
    dinv[i] = 1.0f / sqrtf(dsum);
  }
  sd[t] = v;
  __syncthreads();
  for (int s = 1; s < SCAN_B; s <<= 1) {
    int add = (t >= s) ? sd[t - s] : 0;
    __syncthreads();
    sd[t] += add;
    __syncthreads();
  }
  if (i <= n) offL[i] = sd[t] - v;  // block-local exclusive
  if (t == SCAN_B - 1) bsum[blockIdx.x] = sd[t];
}

// ---------- tiny: wave-scan of bsum -> bexc ----------
__global__ void scan2_kernel(const int* __restrict__ bsum, int* __restrict__ bexc, int nb) {
  int t = threadIdx.x;
  if (t < 64) {  // requires nb <= 63 (N <= 64K)
    int v = (t < nb) ? bsum[t] : 0;
    int incl = v;
#pragma unroll
    for (int s = 1; s < 64; s <<= 1) {
      int u = __shfl_up(incl, s, 64);
      if (t >= s) incl += u;
    }
    if (t <= nb) bexc[t] = incl - v;
  }
}

// ---------- fill CSR: packed 4B (row:16 | coef:fp16), slot precomputed -> NO atomics ----------
__global__ void fill_kernel(const int* __restrict__ ei, const float* __restrict__ ew,
                            const float* __restrict__ dinv, const int* __restrict__ offL,
                            const int* __restrict__ bexc, const unsigned short* __restrict__ eslot,
                            unsigned* __restrict__ epair, int E) {
  int e = blockIdx.x * 256 + threadIdx.x;
  if (e >= E) return;
  int r = ei[e], c = ei[E + e];
  int pos = offL[c] + bexc[c >> 10] + (int)eslot[e];
  float cf = dinv[r] * ew[e] * dinv[c];
  unsigned hb = (unsigned)__builtin_bit_cast(unsigned short, __float2half(cf));
  epair[pos] = (unsigned)r | (hb << 16);
}

// ---------- aggregate: one wave per node, 8 gathers in flight, relu + fp16 out ----------
__global__ void aggregate_kernel(const unsigned* __restrict__ epair, const int* __restrict__ offL,
                                 const int* __restrict__ bexc, const float* __restrict__ dinv,
                                 const uint4* __restrict__ xw4, unsigned* __restrict__ hh, int n) {
  int w = (int)((blockIdx.x * (size_t)blockDim.x + threadIdx.x) >> 6);
  if (w >= n) return;
  int lane = threadIdx.x & 63;
  int q = lane >> 4, l16 = lane & 15;
  int n0 = offL[w] + bexc[w >> 10];
  int n1 = offL[w + 1] + bexc[(w + 1) >> 10];
  float acc[8] = {0.f, 0.f, 0.f, 0.f, 0.f, 0.f, 0.f, 0.f};
  if (q == 0) {
    float dv = dinv[w];
    float c2 = dv * dv;  // self-loop: dinv[i]*1.0*dinv[i]
    uint4 su = xw4[(size_t)w * 16 + l16];
    float2 f0 = __half22float2(*(const __half2*)&su.x);
    float2 f1 = __half22float2(*(const __half2*)&su.y);
    float2 f2 = __half22float2(*(const __half2*)&su.z);
    float2 f3 = __half22float2(*(const __half2*)&su.w);
    acc[0] = c2 * f0.x; acc[1] = c2 * f0.y; acc[2] = c2 * f1.x; acc[3] = c2 * f1.y;
    acc[4] = c2 * f2.x; acc[5] = c2 * f2.y; acc[6] = c2 * f3.x; acc[7] = c2 * f3.y;
  }
  int e = n0 + q;
  for (; e + 4 < n1; e += 8) {
    unsigned p0 = epair[e], p1 = epair[e + 4];
    uint4 u0 = xw4[(size_t)(p0 & 0xFFFFu) * 16 + l16];
    uint4 u1 = xw4[(size_t)(p1 & 0xFFFFu) * 16 + l16];
    float c0 = __half2float(__builtin_bit_cast(__half, (unsigned short)(p0 >> 16)));
    float c1 = __half2float(__builtin_bit_cast(__half, (unsigned short)(p1 >> 16)));
    float2 f0, f1, f2, f3;
    f0 = __half22float2(*(const __half2*)&u0.x); f1 = __half22float2(*(const __half2*)&u0.y);
    f2 = __half22float2(*(const __half2*)&u0.z); f3 = __half22float2(*(const __half2*)&u0.w);
    acc[0] = fmaf(c0, f0.x, acc[0]); acc[1] = fmaf(c0, f0.y, acc[1]);
    acc[2] = fmaf(c0, f1.x, acc[2]); acc[3] = fmaf(c0, f1.y, acc[3]);
    acc[4] = fmaf(c0, f2.x, acc[4]); acc[5] = fmaf(c0, f2.y, acc[5]);
    acc[6] = fmaf(c0, f3.x, acc[6]); acc[7] = fmaf(c0, f3.y, acc[7]);
    f0 = __half22float2(*(const __half2*)&u1.x); f1 = __half22float2(*(const __half2*)&u1.y);
    f2 = __half22float2(*(const __half2*)&u1.z); f3 = __half22float2(*(const __half2*)&u1.w);
    acc[0] = fmaf(c1, f0.x, acc[0]); acc[1] = fmaf(c1, f0.y, acc[1]);
    acc[2] = fmaf(c1, f1.x, acc[2]); acc[3] = fmaf(c1, f1.y, acc[3]);
    acc[4] = fmaf(c1, f2.x, acc[4]); acc[5] = fmaf(c1, f2.y, acc[5]);
    acc[6] = fmaf(c1, f3.x, acc[6]); acc[7] = fmaf(c1, f3.y, acc[7]);
  }
  for (; e < n1; e += 4) {
    unsigned p0 = epair[e];
    uint4 u0 = xw4[(size_t)(p0 & 0xFFFFu) * 16 + l16];
    float c0 = __half2float(__builtin_bit_cast(__half, (unsigned short)(p0 >> 16)));
    float2 f0 = __half22float2(*(const __half2*)&u0.x);
    float2 f1 = __half22float2(*(const __half2*)&u0.y);
    float2 f2 = __half22float2(*(const __half2*)&u0.z);
    float2 f3 = __half22float2(*(const __half2*)&u0.w);
    acc[0] = fmaf(c0, f0.x, acc[0]); acc[1] = fmaf(c0, f0.y, acc[1]);
    acc[2] = fmaf(c0, f1.x, acc[2]); acc[3] = fmaf(c0, f1.y, acc[3]);
    acc[4] = fmaf(c0, f2.x, acc[4]); acc[5] = fmaf(c0, f2.y, acc[5]);
    acc[6] = fmaf(c0, f3.x, acc[6]); acc[7] = fmaf(c0, f3.y, acc[7]);
  }
#pragma unroll
  for (int j = 0; j < 8; ++j) {
    float a = acc[j];
    a += __shfl_xor(a, 16, 64);
    a += __shfl_xor(a, 32, 64);
    acc[j] = a;
  }
  if (q == 0) {
    __half2 h0 = __floats2half2_rn(fmaxf(acc[0], 0.f), fmaxf(acc[1], 0.f));
    __half2 h1 = __floats2half2_rn(fmaxf(acc[2], 0.f), fmaxf(acc[3], 0.f));
    __half2 h2 = __floats2half2_rn(fmaxf(acc[4], 0.f), fmaxf(acc[5], 0.f));
    __half2 h3 = __floats2half2_rn(fmaxf(acc[6], 0.f), fmaxf(acc[7], 0.f));
    uint4 o;
    o.x = *(unsigned*)&h0; o.y = *(unsigned*)&h1; o.z = *(unsigned*)&h2; o.w = *(unsigned*)&h3;
    *(uint4*)&hh[(size_t)w * 64 + l16 * 4] = o;
  }
}

// ---------- MFMA GEMM: C[m][n] = sum_k A[m][k]*Bt[n][k]  (fp16 mfma, f32 accum) ----------
template <int HIN, int HOUT, int BIAS>
__global__ __launch_bounds__(256) void gemm_mfma_kernel(const void* __restrict__ Ap,
                                                        const float* __restrict__ Bt,
                                                        const float* __restrict__ bias,
                                                        void* __restrict__ Cp, int nrows) {
  __shared__ char ldsA[64 * 256];   // 64 rows x 128 f16, XOR-swizzled
  __shared__ char ldsB[128 * 256];  // 128 n-rows x 128 f16, XOR-swizzled
  const int t = threadIdx.x;
  const int row0 = blockIdx.x * 64;
  {  // stage Bt -> fp16 LDS
    const float2* B2 = (const float2*)Bt;
#pragma unroll
    for (int i = 0; i < 32; ++i) {
      int idx = i * 256 + t;  // 0..8191
      int nn = idx >> 6, kp = idx & 63;
      float2 v = B2[idx];
      __half2 h = __floats2half2_rn(v.x, v.y);
      int byte = (nn * 256 + kp * 4) ^ ((nn & 7) << 4);
      *(unsigned*)&ldsB[byte] = *(unsigned*)&h;
    }
  }
  if (HIN) {  // A already fp16
    const unsigned* Ah = (const unsigned*)Ap;
#pragma unroll
    for (int i = 0; i < 16; ++i) {
      int idx = i * 256 + t;  // 0..4095
      int r = idx >> 6, cp = idx & 63;
      int gr = row0 + r;
      unsigned v = (gr < nrows) ? Ah[(size_t)gr * 64 + cp] : 0u;
      int byte = (r * 256 + cp * 4) ^ ((r & 7) << 4);
      *(unsigned*)&ldsA[byte] = v;
    }
  } else {  // A f32 -> fp16
    const float2* A2 = (const float2*)Ap;
#pragma unroll
    for (int i = 0; i < 16; ++i) {
      int idx = i * 256 + t;
      int r = idx >> 6, cp = idx & 63;
      int gr = row0 + r;
      float2 v = make_float2(0.f, 0.f);
      if (gr < nrows) v = A2[(size_t)gr * 64 + cp];
      __half2 h = __floats2half2_rn(v.x, v.y);
      int byte = (r * 256 + cp * 4) ^ ((r & 7) << 4);
      *(unsigned*)&ldsA[byte] = *(unsigned*)&h;
    }
  }
  __syncthreads();
  const int wave = t >> 6, l = t & 63;
  const int wr0 = wave * 16;
  const int lm = l & 15, q = l >> 4;
  floatx4 acc[8];
#pragma unroll
  for (int nt = 0; nt < 8; ++nt) acc[nt] = (floatx4){0.f, 0.f, 0.f, 0.f};
#pragma unroll
  for (int ks = 0; ks < 4; ++ks) {
    int arow = wr0 + lm;
    half8 a = *(const half8*)&ldsA[(arow * 256 + ks * 64 + q * 16) ^ ((arow & 7) << 4)];
#pragma unroll
    for (int nt = 0; nt < 8; ++nt) {
      int nn = nt * 16 + lm;
      half8 b = *(const half8*)&ldsB[(nn * 256 + ks * 64 + q * 16) ^ ((nn & 7) << 4)];
      acc[nt] = __builtin_amdgcn_mfma_f32_16x16x32_f16(a, b, acc[nt], 0, 0, 0);
    }
  }
#pragma unroll
  for (int nt = 0; nt < 8; ++nt) {
    int col = nt * 16 + lm;
    float bv = BIAS ? bias[col] : 0.f;
#pragma unroll
    for (int r = 0; r < 4; ++r) {
      int gr = row0 + wr0 + q * 4 + r;
      if (gr < nrows) {
        float v = acc[nt][r] + bv;
        if (HOUT) ((__half*)Cp)[(size_t)gr * NF + col] = __float2half(v);
        else ((float*)Cp)[(size_t)gr * NF + col] = v;
      }
    }
  }
}

extern "C" void kernel_launch(void* const* d_in, const int* in_sizes, int n_in,
                              void* d_out, int out_size, void* d_ws, size_t ws_size,
                              hipStream_t stream) {
  const float* x = (const float*)d_in[0];
  const int* ei = (const int*)d_in[1];
  const float* ew = (const float*)d_in[2];
  const float* p = (const float*)d_in[3];
  const float* w_ih = (const float*)d_in[4];
  const float* w_hh = (const float*)d_in[5];
  const float* b_ih = (const float*)d_in[6];
  const float* b_hh = (const float*)d_in[7];
  const float* W0 = (const float*)d_in[8];
  const float* W_lin = (const float*)d_in[9];
  const float* b_lin = (const float*)d_in[10];
  float* out = (float*)d_out;

  const int N = in_sizes[0] / NF;  // 50000 (< 65536 required for 16-bit rows)
  const int E = in_sizes[1] / 2;   // 800000

  char* w = (char*)d_ws;
  unsigned* xwh = (unsigned*)w;                                 // N*64 (fp16 xw)
  unsigned* hh = xwh + (size_t)N * 64;                          // N*64 (fp16 relu(h))
  float* score = (float*)(hh + (size_t)N * 64);                 // N
  unsigned* keys = (unsigned*)(score + N);                      // N
  unsigned long long* cnt64 = (unsigned long long*)(keys + N);  // ZERO region: N x 8B
  unsigned* bins = (unsigned*)(cnt64 + N);                      // 65536
  int* ncnt = (int*)(bins + 65536);                             // 1 (end of ZERO region)
  float* dinv = (float*)(ncnt + 1);                             // N
  unsigned* thrB = (unsigned*)(dinv + N);                       // 1
  int* candIdx = (int*)(thrB + 1);                              // N
  int* offL = candIdx + N;                                      // N+1
  int* bsum = offL + N + 1;                                     // 64
  int* bexc = bsum + 64;                                        // 64
  unsigned short* eslot = (unsigned short*)(bexc + 64);         // E x 2B
  unsigned* epair = (unsigned*)(eslot + E);                     // E x 4B
  float* WevT = (float*)(epair + E);                            // 128*128
  int* perm = (int*)(WevT + NF * NF);                           // 128
  float* tsc = (float*)(perm + NF);                             // 128

  const int nb = (N + SCAN_B - 1) / SCAN_B;
  const int nbEdge = (E + 255) / 256;
  const int nbGemm = (N + 63) / 64;
  const int nOwnC = (N + 1023) / 1024;

  // edge-slice partition across 4 overlap stages
  const int per = (E + 3) / 4;
  const int bA = (per + 1023) / 1024;
  const int eA0 = 0, eA1 = (bA * 1024 < E) ? bA * 1024 : E;
  const int bB = (per + 1023) / 1024;
  const int eB0 = eA1, eB1 = (eB0 + bB * 1024 < E) ? eB0 + bB * 1024 : E;
  const int bC = (per + 1023) / 1024;
  const int eC0 = eB1, eC1 = (eC0 + bC * 1024 < E) ? eC0 + bC * 1024 : E;
  const int eD0 = eC1;
  const int bD = (E - eD0 + 127) / 128;

  hipMemsetAsync(cnt64, 0, (size_t)N * 8 + 65536 * 4 + 4, stream);  // cnt64,bins,ncnt
  score_kernel<<<(N + 3) / 4, 256, 0, stream>>>(x, p, score, keys, bins, N);
  findbin_edge_kernel<<<1 + bA, 1024, 0, stream>>>(bins, thrB, ei, ew, cnt64, eslot, E, eA0, eA1);
  compact_edge_kernel<<<nOwnC + bB, 1024, 0, stream>>>(keys, thrB, ncnt, candIdx, N, nOwnC,
                                                       ei, ew, cnt64, eslot, E, eB0, eB1);
  select_edge_kernel<<<1 + bC, 1024, 0, stream>>>(keys, candIdx, ncnt, score, perm, tsc,
                                                  ei, ew, cnt64, eslot, E, eC0, eC1);
  gru_edge_kernel<<<NF + bD, NF, 0, stream>>>(x, perm, tsc, W0, w_ih, w_hh, b_ih, b_hh, WevT,
                                              ei, ew, cnt64, eslot, E, eD0, E);
  gemm_mfma_kernel<0, 1, 0><<<nbGemm, 256, 0, stream>>>(x, WevT, nullptr, xwh, N);
  scan1_kernel<<<nb, SCAN_B, 0, stream>>>(cnt64, offL, bsum, dinv, N);
  scan2_kernel<<<1, 64, 0, stream>>>(bsum, bexc, nb);
  fill_kernel<<<nbEdge, 256, 0, stream>>>(ei, ew, dinv, offL, bexc, eslot, epair, E);
  aggregate_kernel<<<(N + 3) / 4, 256, 0, stream>>>(epair, offL, bexc, dinv,
                                                    (const uint4*)xwh, hh, N);
  gemm_mfma_kernel<1, 0, 1><<<nbGemm, 256, 0, stream>>>(hh, W_lin, b_lin, out, N);
}

// Round 9
// 212.554 us; speedup vs baseline: 1.9460x; 1.0252x over previous
//
#include <hip/hip_runtime.h>
#include <hip/hip_fp16.h>

#define NF 128
#define TK 128

typedef _Float16 f16;
typedef f16 half8 __attribute__((ext_vector_type(8)));
typedef float floatx4 __attribute__((ext_vector_type(4)));

__device__ __forceinline__ unsigned okey(float f) {
  unsigned u = __float_as_uint(f);
  return (u & 0x80000000u) ? ~u : (u | 0x80000000u);
}

// edge-histogram slice: one edge per thread
__device__ __forceinline__ void edge_slice(const int* __restrict__ ei, const float* __restrict__ ew,
                                           unsigned long long* __restrict__ cnt64,
                                           unsigned short* __restrict__ eslot, int E, int e, int elim) {
  if (e < elim) {
    int c = ei[E + e];
    unsigned fx = __float2uint_rn(ew[e] * 16777216.0f);  // 2^24 fixed point
    unsigned long long old =
        atomicAdd(&cnt64[c], ((unsigned long long)1 << 32) | (unsigned long long)fx);
    eslot[e] = (unsigned short)(old >> 32);
  }
}

// ---------- scores + key histogram: 32 rows/block, 8 lanes/row, 64B/thread ----------
__global__ void score_kernel(const float* __restrict__ x, const float* __restrict__ p,
                             float* __restrict__ score, unsigned* __restrict__ keys,
                             unsigned* __restrict__ bins, int n) {
  int t = threadIdx.x;
  int rib = t >> 3;   // row in block: 0..31
  int l8 = t & 7;     // 8 lanes per row
  int r = blockIdx.x * 32 + rib;
  if (r >= n) return;
  const float4* xr = (const float4*)&x[(size_t)r * NF + l8 * 16];
  const float4* pr = (const float4*)&p[l8 * 16];
  float d = 0.f, pp = 0.f;
#pragma unroll
  for (int i = 0; i < 4; ++i) {
    float4 xv = xr[i];
    float4 pv = pr[i];
    d = fmaf(xv.x, pv.x, d); d = fmaf(xv.y, pv.y, d);
    d = fmaf(xv.z, pv.z, d); d = fmaf(xv.w, pv.w, d);
    pp = fmaf(pv.x, pv.x, pp); pp = fmaf(pv.y, pv.y, pp);
    pp = fmaf(pv.z, pv.z, pp); pp = fmaf(pv.w, pv.w, pp);
  }
#pragma unroll
  for (int off = 4; off > 0; off >>= 1) {
    d += __shfl_down(d, off, 8);
    pp += __shfl_down(pp, off, 8);
  }
  if (l8 == 0) {
    float s = tanhf(d / sqrtf(pp));
    score[r] = s;
    unsigned k = okey(s);
    keys[r] = k;
    atomicAdd(&bins[k >> 16], 1u);
  }
}

// ---------- findbin (block 0) + edge slice ----------
__global__ __launch_bounds__(1024) void findbin_edge_kernel(const unsigned* __restrict__ bins,
                                                            unsigned* __restrict__ thrB,
                                                            const int* __restrict__ ei,
                                                            const float* __restrict__ ew,
                                                            unsigned long long* __restrict__ cnt64,
                                                            unsigned short* __restrict__ eslot,
                                                            int E, int ebase, int elim) {
  if (blockIdx.x > 0) {
    edge_slice(ei, ew, cnt64, eslot, E, ebase + ((int)blockIdx.x - 1) * 1024 + (int)threadIdx.x, elim);
    return;
  }
  __shared__ unsigned csum[1024];
  int t = threadIdx.x;
  unsigned hv[64];
  unsigned s = 0;
  const unsigned* bp = bins + t * 64;
#pragma unroll
  for (int b = 0; b < 64; ++b) { hv[b] = bp[b]; s += hv[b]; }
  csum[t] = s;
  __syncthreads();
  for (int st = 1; st < 1024; st <<= 1) {
    unsigned add = (t + st < 1024) ? csum[t + st] : 0u;
    __syncthreads();
    csum[t] += add;
    __syncthreads();
  }
  unsigned mySum = csum[t];
  unsigned above = (t == 1023) ? 0u : csum[t + 1];
  if (mySum >= (unsigned)TK && above < (unsigned)TK) {
    unsigned cum = above;
    int b = 63;
    for (; b > 0; --b) {
      unsigned h = hv[b];
      if (cum + h >= (unsigned)TK) break;
      cum += h;
    }
    thrB[0] = (unsigned)(t * 64 + b);
  }
}

// ---------- compact candidates (blocks < nOwn) + edge slice ----------
__global__ __launch_bounds__(1024) void compact_edge_kernel(const unsigned* __restrict__ keys,
                                                            const unsigned* __restrict__ thrB,
                                                            int* __restrict__ ncnt,
                                                            int* __restrict__ candIdx, int n, int nOwn,
                                                            const int* __restrict__ ei,
                                                            const float* __restrict__ ew,
                                                            unsigned long long* __restrict__ cnt64,
                                                            unsigned short* __restrict__ eslot,
                                                            int E, int ebase, int elim) {
  if ((int)blockIdx.x >= nOwn) {
    edge_slice(ei, ew, cnt64, eslot, E,
               ebase + ((int)blockIdx.x - nOwn) * 1024 + (int)threadIdx.x, elim);
    return;
  }
  int i = blockIdx.x * 1024 + threadIdx.x;
  if (i < n) {
    if ((keys[i] >> 16) >= thrB[0]) {
      int pos = atomicAdd(ncnt, 1);
      candIdx[pos] = i;
    }
  }
}

// ---------- exact top-K select (block 0) + edge slice ----------
#define CCAP 6144
__global__ __launch_bounds__(1024) void select_edge_kernel(const unsigned* __restrict__ keys,
                                                           const int* __restrict__ candIdx,
                                                           const int* __restrict__ ncp,
                                                           const float* __restrict__ score,
                                                           int* __restrict__ perm,
                                                           float* __restrict__ tsc,
                                                           const int* __restrict__ ei,
                                                           const float* __restrict__ ew,
                                                           unsigned long long* __restrict__ cnt64,
                                                           unsigned short* __restrict__ eslot,
                                                           int E, int ebase, int elim) {
  if (blockIdx.x > 0) {
    edge_slice(ei, ew, cnt64, eslot, E, ebase + ((int)blockIdx.x - 1) * 1024 + (int)threadIdx.x, elim);
    return;
  }
  __shared__ unsigned sk[CCAP];
  __shared__ int si[CCAP];
  int nc = ncp[0];
  int t = threadIdx.x;
  int m = nc < CCAP ? nc : CCAP;
  for (int i = t; i < m; i += 1024) {
    int ci = candIdx[i];
    si[i] = ci;
    sk[i] = keys[ci];
  }
  __syncthreads();
  for (int ci = t; ci < nc; ci += 1024) {
    unsigned mk;
    int mi;
    if (ci < CCAP) { mk = sk[ci]; mi = si[ci]; }
    else { mi = candIdx[ci]; mk = keys[mi]; }
    int rank = 0;
    for (int j = 0; j < m; ++j) {
      unsigned kj = sk[j];
      int ij = si[j];
      rank += (kj > mk || (kj == mk && ij < mi)) ? 1 : 0;
    }
    for (int j = CCAP; j < nc; ++j) {
      int ij = candIdx[j];
      unsigned kj = keys[ij];
      rank += (kj > mk || (kj == mk && ij < mi)) ? 1 : 0;
    }
    if (rank < TK) {
      perm[rank] = mi;
      tsc[rank] = score[mi];
    }
  }
}

// ---------- GRU (blocks < 128, 128 thr) + edge slice; writes W transposed ----------
__global__ void gru_edge_kernel(const float* __restrict__ x, const int* __restrict__ perm,
                                const float* __restrict__ tsc, const float* __restrict__ W0,
                                const float* __restrict__ w_ih, const float* __restrict__ w_hh,
                                const float* __restrict__ b_ih, const float* __restrict__ b_hh,
                                float* __restrict__ WT,
                                const int* __restrict__ ei, const float* __restrict__ ew,
                                unsigned long long* __restrict__ cnt64,
                                unsigned short* __restrict__ eslot, int E, int ebase, int elim) {
  if ((int)blockIdx.x >= NF) {
    edge_slice(ei, ew, cnt64, eslot, E, ebase + ((int)blockIdx.x - NF) * 128 + (int)threadIdx.x, elim);
    return;
  }
  __shared__ float xs[NF], w0s[NF];
  int i = blockIdx.x, j = threadIdx.x;
  int pi = perm[i];
  float s = tsc[i];
  xs[j] = x[(size_t)pi * NF + j] * s;
  w0s[j] = W0[i * NF + j];
  __syncthreads();
  float gir = b_ih[j], giz = b_ih[NF + j], gin = b_ih[2 * NF + j];
  float ghr = b_hh[j], ghz = b_hh[NF + j], ghn = b_hh[2 * NF + j];
  const float* wr = w_ih + (size_t)j * NF;
  const float* wz = w_ih + (size_t)(NF + j) * NF;
  const float* wn = w_ih + (size_t)(2 * NF + j) * NF;
  const float* ur = w_hh + (size_t)j * NF;
  const float* uz = w_hh + (size_t)(NF + j) * NF;
  const float* un = w_hh + (size_t)(2 * NF + j) * NF;
#pragma unroll 4
  for (int k = 0; k < NF; ++k) {
    float xv = xs[k], wv = w0s[k];
    gir = fmaf(xv, wr[k], gir);
    giz = fmaf(xv, wz[k], giz);
    gin = fmaf(xv, wn[k], gin);
    ghr = fmaf(wv, ur[k], ghr);
    ghz = fmaf(wv, uz[k], ghz);
    ghn = fmaf(wv, un[k], ghn);
  }
  float r = 1.0f / (1.0f + expf(-(gir + ghr)));
  float z = 1.0f / (1.0f + expf(-(giz + ghz)));
  float nn = tanhf(gin + r * ghn);
  WT[(size_t)j * NF + i] = (1.0f - z) * nn + z * w0s[j];  // transposed: WT[n][k]
}

// ---------- scan over counts (block-local exclusive) + dinv ----------
#define SCAN_B 1024
__global__ __launch_bounds__(1024) void scan1_kernel(const unsigned long long* __restrict__ cnt64,
                                                     int* __restrict__ offL, int* __restrict__ bsum,
                                                     float* __restrict__ dinv, int n) {
  __shared__ int sd[SCAN_B];
  int t = threadIdx.x;
  int i = blockIdx.x * SCAN_B + t;
  int v = 0;
  if (i < n) {
    unsigned long long cv = cnt64[i];
    v = (int)(cv >> 32);
    float dsum = (float)((unsigned)cv) * (1.0f / 16777216.0f) + 1.0f;  // + self-loop
    dinv[i] = 1.0f / sqrtf(dsum);
  }
  sd[t] = v;
  __syncthreads();
  for (int s = 1; s < SCAN_B; s <<= 1) {
    int add = (t >= s) ? sd[t - s] : 0;
    __syncthreads();
    sd[t] += add;
    __syncthreads();
  }
  if (i <= n) offL[i] = sd[t] - v;  // block-local exclusive
  if (t == SCAN_B - 1) bsum[blockIdx.x] = sd[t];
}

// ---------- tiny: wave-scan of bsum -> bexc ----------
__global__ void scan2_kernel(const int* __restrict__ bsum, int* __restrict__ bexc, int nb) {
  int t = threadIdx.x;
  if (t < 64) {  // requires nb <= 63 (N <= 64K)
    int v = (t < nb) ? bsum[t] : 0;
    int incl = v;
#pragma unroll
    for (int s = 1; s < 64; s <<= 1) {
      int u = __shfl_up(incl, s, 64);
      if (t >= s) incl += u;
    }
    if (t <= nb) bexc[t] = incl - v;
  }
}

// ---------- fill CSR: packed 4B (row:16 | coef:fp16), slot precomputed -> NO atomics ----------
__global__ void fill_kernel(const int* __restrict__ ei, const float* __restrict__ ew,
                            const float* __restrict__ dinv, const int* __restrict__ offL,
                            const int* __restrict__ bexc, const unsigned short* __restrict__ eslot,
                            unsigned* __restrict__ epair, int E) {
  int e = blockIdx.x * 256 + threadIdx.x;
  if (e >= E) return;
  int r = ei[e], c = ei[E + e];
  int pos = offL[c] + bexc[c >> 10] + (int)eslot[e];
  float cf = dinv[r] * ew[e] * dinv[c];
  unsigned hb = (unsigned)__builtin_bit_cast(unsigned short, __float2half(cf));
  epair[pos] = (unsigned)r | (hb << 16);
}

// ---------- aggregate: one wave per node, 8 gathers in flight, relu + fp16 out ----------
__global__ void aggregate_kernel(const unsigned* __restrict__ epair, const int* __restrict__ offL,
                                 const int* __restrict__ bexc, const float* __restrict__ dinv,
                                 const uint4* __restrict__ xw4, unsigned* __restrict__ hh, int n) {
  int w = (int)((blockIdx.x * (size_t)blockDim.x + threadIdx.x) >> 6);
  if (w >= n) return;
  int lane = threadIdx.x & 63;
  int q = lane >> 4, l16 = lane & 15;
  int n0 = offL[w] + bexc[w >> 10];
  int n1 = offL[w + 1] + bexc[(w + 1) >> 10];
  float acc[8] = {0.f, 0.f, 0.f, 0.f, 0.f, 0.f, 0.f, 0.f};
  if (q == 0) {
    float dv = dinv[w];
    float c2 = dv * dv;  // self-loop: dinv[i]*1.0*dinv[i]
    uint4 su = xw4[(size_t)w * 16 + l16];
    float2 f0 = __half22float2(*(const __half2*)&su.x);
    float2 f1 = __half22float2(*(const __half2*)&su.y);
    float2 f2 = __half22float2(*(const __half2*)&su.z);
    float2 f3 = __half22float2(*(const __half2*)&su.w);
    acc[0] = c2 * f0.x; acc[1] = c2 * f0.y; acc[2] = c2 * f1.x; acc[3] = c2 * f1.y;
    acc[4] = c2 * f2.x; acc[5] = c2 * f2.y; acc[6] = c2 * f3.x; acc[7] = c2 * f3.y;
  }
  int e = n0 + q;
  for (; e + 4 < n1; e += 8) {
    unsigned p0 = epair[e], p1 = epair[e + 4];
    uint4 u0 = xw4[(size_t)(p0 & 0xFFFFu) * 16 + l16];
    uint4 u1 = xw4[(size_t)(p1 & 0xFFFFu) * 16 + l16];
    float c0 = __half2float(__builtin_bit_cast(__half, (unsigned short)(p0 >> 16)));
    float c1 = __half2float(__builtin_bit_cast(__half, (unsigned short)(p1 >> 16)));
    float2 f0, f1, f2, f3;
    f0 = __half22float2(*(const __half2*)&u0.x); f1 = __half22float2(*(const __half2*)&u0.y);
    f2 = __half22float2(*(const __half2*)&u0.z); f3 = __half22float2(*(const __half2*)&u0.w);
    acc[0] = fmaf(c0, f0.x, acc[0]); acc[1] = fmaf(c0, f0.y, acc[1]);
    acc[2] = fmaf(c0, f1.x, acc[2]); acc[3] = fmaf(c0, f1.y, acc[3]);
    acc[4] = fmaf(c0, f2.x, acc[4]); acc[5] = fmaf(c0, f2.y, acc[5]);
    acc[6] = fmaf(c0, f3.x, acc[6]); acc[7] = fmaf(c0, f3.y, acc[7]);
    f0 = __half22float2(*(const __half2*)&u1.x); f1 = __half22float2(*(const __half2*)&u1.y);
    f2 = __half22float2(*(const __half2*)&u1.z); f3 = __half22float2(*(const __half2*)&u1.w);
    acc[0] = fmaf(c1, f0.x, acc[0]); acc[1] = fmaf(c1, f0.y, acc[1]);
    acc[2] = fmaf(c1, f1.x, acc[2]); acc[3] = fmaf(c1, f1.y, acc[3]);
    acc[4] = fmaf(c1, f2.x, acc[4]); acc[5] = fmaf(c1, f2.y, acc[5]);
    acc[6] = fmaf(c1, f3.x, acc[6]); acc[7] = fmaf(c1, f3.y, acc[7]);
  }
  for (; e < n1; e += 4) {
    unsigned p0 = epair[e];
    uint4 u0 = xw4[(size_t)(p0 & 0xFFFFu) * 16 + l16];
    float c0 = __half2float(__builtin_bit_cast(__half, (unsigned short)(p0 >> 16)));
    float2 f0 = __half22float2(*(const __half2*)&u0.x);
    float2 f1 = __half22float2(*(const __half2*)&u0.y);
    float2 f2 = __half22float2(*(const __half2*)&u0.z);
    float2 f3 = __half22float2(*(const __half2*)&u0.w);
    acc[0] = fmaf(c0, f0.x, acc[0]); acc[1] = fmaf(c0, f0.y, acc[1]);
    acc[2] = fmaf(c0, f1.x, acc[2]); acc[3] = fmaf(c0, f1.y, acc[3]);
    acc[4] = fmaf(c0, f2.x, acc[4]); acc[5] = fmaf(c0, f2.y, acc[5]);
    acc[6] = fmaf(c0, f3.x, acc[6]); acc[7] = fmaf(c0, f3.y, acc[7]);
  }
#pragma unroll
  for (int j = 0; j < 8; ++j) {
    float a = acc[j];
    a += __shfl_xor(a, 16, 64);
    a += __shfl_xor(a, 32, 64);
    acc[j] = a;
  }
  if (q == 0) {
    __half2 h0 = __floats2half2_rn(fmaxf(acc[0], 0.f), fmaxf(acc[1], 0.f));
    __half2 h1 = __floats2half2_rn(fmaxf(acc[2], 0.f), fmaxf(acc[3], 0.f));
    __half2 h2 = __floats2half2_rn(fmaxf(acc[4], 0.f), fmaxf(acc[5], 0.f));
    __half2 h3 = __floats2half2_rn(fmaxf(acc[6], 0.f), fmaxf(acc[7], 0.f));
    uint4 o;
    o.x = *(unsigned*)&h0; o.y = *(unsigned*)&h1; o.z = *(unsigned*)&h2; o.w = *(unsigned*)&h3;
    *(uint4*)&hh[(size_t)w * 64 + l16 * 4] = o;
  }
}

// ---------- MFMA GEMM: C[m][n] = sum_k A[m][k]*Bt[n][k]  (fp16 mfma, f32 accum) ----------
template <int HIN, int HOUT, int BIAS>
__global__ __launch_bounds__(256) void gemm_mfma_kernel(const void* __restrict__ Ap,
                                                        const float* __restrict__ Bt,
                                                        const float* __restrict__ bias,
                                                        void* __restrict__ Cp, int nrows) {
  __shared__ char ldsA[64 * 256];   // 64 rows x 128 f16, XOR-swizzled
  __shared__ char ldsB[128 * 256];  // 128 n-rows x 128 f16, XOR-swizzled
  const int t = threadIdx.x;
  const int row0 = blockIdx.x * 64;
  {  // stage Bt -> fp16 LDS
    const float2* B2 = (const float2*)Bt;
#pragma unroll
    for (int i = 0; i < 32; ++i) {
      int idx = i * 256 + t;  // 0..8191
      int nn = idx >> 6, kp = idx & 63;
      float2 v = B2[idx];
      __half2 h = __floats2half2_rn(v.x, v.y);
      int byte = (nn * 256 + kp * 4) ^ ((nn & 7) << 4);
      *(unsigned*)&ldsB[byte] = *(unsigned*)&h;
    }
  }
  if (HIN) {  // A already fp16
    const unsigned* Ah = (const unsigned*)Ap;
#pragma unroll
    for (int i = 0; i < 16; ++i) {
      int idx = i * 256 + t;  // 0..4095
      int r = idx >> 6, cp = idx & 63;
      int gr = row0 + r;
      unsigned v = (gr < nrows) ? Ah[(size_t)gr * 64 + cp] : 0u;
      int byte = (r * 256 + cp * 4) ^ ((r & 7) << 4);
      *(unsigned*)&ldsA[byte] = v;
    }
  } else {  // A f32 -> fp16
    const float2* A2 = (const float2*)Ap;
#pragma unroll
    for (int i = 0; i < 16; ++i) {
      int idx = i * 256 + t;
      int r = idx >> 6, cp = idx & 63;
      int gr = row0 + r;
      float2 v = make_float2(0.f, 0.f);
      if (gr < nrows) v = A2[(size_t)gr * 64 + cp];
      __half2 h = __floats2half2_rn(v.x, v.y);
      int byte = (r * 256 + cp * 4) ^ ((r & 7) << 4);
      *(unsigned*)&ldsA[byte] = *(unsigned*)&h;
    }
  }
  __syncthreads();
  const int wave = t >> 6, l = t & 63;
  const int wr0 = wave * 16;
  const int lm = l & 15, q = l >> 4;
  floatx4 acc[8];
#pragma unroll
  for (int nt = 0; nt < 8; ++nt) acc[nt] = (floatx4){0.f, 0.f, 0.f, 0.f};
#pragma unroll
  for (int ks = 0; ks < 4; ++ks) {
    int arow = wr0 + lm;
    half8 a = *(const half8*)&ldsA[(arow * 256 + ks * 64 + q * 16) ^ ((arow & 7) << 4)];
#pragma unroll
    for (int nt = 0; nt < 8; ++nt) {
      int nn = nt * 16 + lm;
      half8 b = *(const half8*)&ldsB[(nn * 256 + ks * 64 + q * 16) ^ ((nn & 7) << 4)];
      acc[nt] = __builtin_amdgcn_mfma_f32_16x16x32_f16(a, b, acc[nt], 0, 0, 0);
    }
  }
#pragma unroll
  for (int nt = 0; nt < 8; ++nt) {
    int col = nt * 16 + lm;
    float bv = BIAS ? bias[col] : 0.f;
#pragma unroll
    for (int r = 0; r < 4; ++r) {
      int gr = row0 + wr0 + q * 4 + r;
      if (gr < nrows) {
        float v = acc[nt][r] + bv;
        if (HOUT) ((__half*)Cp)[(size_t)gr * NF + col] = __float2half(v);
        else ((float*)Cp)[(size_t)gr * NF + col] = v;
      }
    }
  }
}

extern "C" void kernel_launch(void* const* d_in, const int* in_sizes, int n_in,
                              void* d_out, int out_size, void* d_ws, size_t ws_size,
                              hipStream_t stream) {
  const float* x = (const float*)d_in[0];
  const int* ei = (const int*)d_in[1];
  const float* ew = (const float*)d_in[2];
  const float* p = (const float*)d_in[3];
  const float* w_ih = (const float*)d_in[4];
  const float* w_hh = (const float*)d_in[5];
  const float* b_ih = (const float*)d_in[6];
  const float* b_hh = (const float*)d_in[7];
  const float* W0 = (const float*)d_in[8];
  const float* W_lin = (const float*)d_in[9];
  const float* b_lin = (const float*)d_in[10];
  float* out = (float*)d_out;

  const int N = in_sizes[0] / NF;  // 50000 (< 65536 required for 16-bit rows)
  const int E = in_sizes[1] / 2;   // 800000

  char* w = (char*)d_ws;
  unsigned* xwh = (unsigned*)w;                                 // N*64 (fp16 xw)
  unsigned* hh = xwh + (size_t)N * 64;                          // N*64 (fp16 relu(h))
  float* score = (float*)(hh + (size_t)N * 64);                 // N
  unsigned* keys = (unsigned*)(score + N);                      // N
  unsigned long long* cnt64 = (unsigned long long*)(keys + N);  // ZERO region: N x 8B
  unsigned* bins = (unsigned*)(cnt64 + N);                      // 65536
  int* ncnt = (int*)(bins + 65536);                             // 1 (end of ZERO region)
  float* dinv = (float*)(ncnt + 1);                             // N
  unsigned* thrB = (unsigned*)(dinv + N);                       // 1
  int* candIdx = (int*)(thrB + 1);                              // N
  int* offL = candIdx + N;                                      // N+1
  int* bsum = offL + N + 1;                                     // 64
  int* bexc = bsum + 64;                                        // 64
  unsigned short* eslot = (unsigned short*)(bexc + 64);         // E x 2B
  unsigned* epair = (unsigned*)(eslot + E);                     // E x 4B
  float* WevT = (float*)(epair + E);                            // 128*128
  int* perm = (int*)(WevT + NF * NF);                           // 128
  float* tsc = (float*)(perm + NF);                             // 128

  const int nb = (N + SCAN_B - 1) / SCAN_B;
  const int nbEdge = (E + 255) / 256;
  const int nbGemm = (N + 63) / 64;
  const int nOwnC = (N + 1023) / 1024;

  // edge-slice partition across 4 overlap stages
  const int per = (E + 3) / 4;
  const int bA = (per + 1023) / 1024;
  const int eA0 = 0, eA1 = (bA * 1024 < E) ? bA * 1024 : E;
  const int bB = (per + 1023) / 1024;
  const int eB0 = eA1, eB1 = (eB0 + bB * 1024 < E) ? eB0 + bB * 1024 : E;
  const int bC = (per + 1023) / 1024;
  const int eC0 = eB1, eC1 = (eC0 + bC * 1024 < E) ? eC0 + bC * 1024 : E;
  const int eD0 = eC1;
  const int bD = (E - eD0 + 127) / 128;

  hipMemsetAsync(cnt64, 0, (size_t)N * 8 + 65536 * 4 + 4, stream);  // cnt64,bins,ncnt
  score_kernel<<<(N + 31) / 32, 256, 0, stream>>>(x, p, score, keys, bins, N);
  findbin_edge_kernel<<<1 + bA, 1024, 0, stream>>>(bins, thrB, ei, ew, cnt64, eslot, E, eA0, eA1);
  compact_edge_kernel<<<nOwnC + bB, 1024, 0, stream>>>(keys, thrB, ncnt, candIdx, N, nOwnC,
                                                       ei, ew, cnt64, eslot, E, eB0, eB1);
  select_edge_kernel<<<1 + bC, 1024, 0, stream>>>(keys, candIdx, ncnt, score, perm, tsc,
                                                  ei, ew, cnt64, eslot, E, eC0, eC1);
  gru_edge_kernel<<<NF + bD, NF, 0, stream>>>(x, perm, tsc, W0, w_ih, w_hh, b_ih, b_hh, WevT,
                                              ei, ew, cnt64, eslot, E, eD0, E);
  gemm_mfma_kernel<0, 1, 0><<<nbGemm, 256, 0, stream>>>(x, WevT, nullptr, xwh, N);
  scan1_kernel<<<nb, SCAN_B, 0, stream>>>(cnt64, offL, bsum, dinv, N);
  scan2_kernel<<<1, 64, 0, stream>>>(bsum, bexc, nb);
  fill_kernel<<<nbEdge, 256, 0, stream>>>(ei, ew, dinv, offL, bexc, eslot, epair, E);
  aggregate_kernel<<<(N + 3) / 4, 256, 0, stream>>>(epair, offL, bexc, dinv,
                                                    (const uint4*)xwh, hh, N);
  gemm_mfma_kernel<1, 0, 1><<<nbGemm, 256, 0, stream>>>(hh, W_lin, b_lin, out, N);
}

// Round 10
// 198.680 us; speedup vs baseline: 2.0819x; 1.0698x over previous
//
#include <hip/hip_runtime.h>
#include <hip/hip_fp16.h>

#define NF 128
#define TK 128

typedef _Float16 f16;
typedef f16 half8 __attribute__((ext_vector_type(8)));
typedef float floatx4 __attribute__((ext_vector_type(4)));

__device__ __forceinline__ unsigned okey(float f) {
  unsigned u = __float_as_uint(f);
  return (u & 0x80000000u) ? ~u : (u | 0x80000000u);
}

// edge-histogram slice: one edge per thread
__device__ __forceinline__ void edge_slice(const int* __restrict__ ei, const float* __restrict__ ew,
                                           unsigned long long* __restrict__ cnt64,
                                           unsigned short* __restrict__ eslot, int E, int e, int elim) {
  if (e < elim) {
    int c = ei[E + e];
    unsigned fx = __float2uint_rn(ew[e] * 16777216.0f);  // 2^24 fixed point
    unsigned long long old =
        atomicAdd(&cnt64[c], ((unsigned long long)1 << 32) | (unsigned long long)fx);
    eslot[e] = (unsigned short)(old >> 32);
  }
}

// ---------- zero workspace region ----------
__global__ void zero_kernel(uint4* __restrict__ dst, int n4) {
  int i = blockIdx.x * blockDim.x + threadIdx.x;
  int stride = gridDim.x * blockDim.x;
  uint4 z = make_uint4(0u, 0u, 0u, 0u);
  for (; i < n4; i += stride) dst[i] = z;
}

// ---------- scores (+key histogram) co-scheduled with edge slice A ----------
__global__ void score_edge_kernel(const float* __restrict__ x, const float* __restrict__ p,
                                  float* __restrict__ score, unsigned* __restrict__ keys,
                                  unsigned* __restrict__ bins, int n, int nbScore,
                                  const int* __restrict__ ei, const float* __restrict__ ew,
                                  unsigned long long* __restrict__ cnt64,
                                  unsigned short* __restrict__ eslot, int E, int ebase, int elim) {
  if ((int)blockIdx.x >= nbScore) {
    edge_slice(ei, ew, cnt64, eslot, E,
               ebase + ((int)blockIdx.x - nbScore) * 256 + (int)threadIdx.x, elim);
    return;
  }
  int t = threadIdx.x;
  int rib = t >> 3;   // row in block: 0..31
  int l8 = t & 7;     // 8 lanes per row
  int r = blockIdx.x * 32 + rib;
  if (r >= n) return;
  const float4* xr = (const float4*)&x[(size_t)r * NF + l8 * 16];
  const float4* pr = (const float4*)&p[l8 * 16];
  float d = 0.f, pp = 0.f;
#pragma unroll
  for (int i = 0; i < 4; ++i) {
    float4 xv = xr[i];
    float4 pv = pr[i];
    d = fmaf(xv.x, pv.x, d); d = fmaf(xv.y, pv.y, d);
    d = fmaf(xv.z, pv.z, d); d = fmaf(xv.w, pv.w, d);
    pp = fmaf(pv.x, pv.x, pp); pp = fmaf(pv.y, pv.y, pp);
    pp = fmaf(pv.z, pv.z, pp); pp = fmaf(pv.w, pv.w, pp);
  }
#pragma unroll
  for (int off = 4; off > 0; off >>= 1) {
    d += __shfl_down(d, off, 8);
    pp += __shfl_down(pp, off, 8);
  }
  if (l8 == 0) {
    float s = tanhf(d / sqrtf(pp));
    score[r] = s;
    unsigned k = okey(s);
    keys[r] = k;
    atomicAdd(&bins[k >> 16], 1u);
  }
}

// ---------- findbin (block 0) + edge slice ----------
__global__ __launch_bounds__(1024) void findbin_edge_kernel(const unsigned* __restrict__ bins,
                                                            unsigned* __restrict__ thrB,
                                                            const int* __restrict__ ei,
                                                            const float* __restrict__ ew,
                                                            unsigned long long* __restrict__ cnt64,
                                                            unsigned short* __restrict__ eslot,
                                                            int E, int ebase, int elim) {
  if (blockIdx.x > 0) {
    edge_slice(ei, ew, cnt64, eslot, E, ebase + ((int)blockIdx.x - 1) * 1024 + (int)threadIdx.x, elim);
    return;
  }
  __shared__ unsigned csum[1024];
  int t = threadIdx.x;
  unsigned hv[64];
  unsigned s = 0;
  const unsigned* bp = bins + t * 64;
#pragma unroll
  for (int b = 0; b < 64; ++b) { hv[b] = bp[b]; s += hv[b]; }
  csum[t] = s;
  __syncthreads();
  for (int st = 1; st < 1024; st <<= 1) {
    unsigned add = (t + st < 1024) ? csum[t + st] : 0u;
    __syncthreads();
    csum[t] += add;
    __syncthreads();
  }
  unsigned mySum = csum[t];
  unsigned above = (t == 1023) ? 0u : csum[t + 1];
  if (mySum >= (unsigned)TK && above < (unsigned)TK) {
    unsigned cum = above;
    int b = 63;
    for (; b > 0; --b) {
      unsigned h = hv[b];
      if (cum + h >= (unsigned)TK) break;
      cum += h;
    }
    thrB[0] = (unsigned)(t * 64 + b);
  }
}

// ---------- compact candidates (blocks < nOwn) + edge slice ----------
__global__ __launch_bounds__(1024) void compact_edge_kernel(const unsigned* __restrict__ keys,
                                                            const unsigned* __restrict__ thrB,
                                                            int* __restrict__ ncnt,
                                                            int* __restrict__ candIdx, int n, int nOwn,
                                                            const int* __restrict__ ei,
                                                            const float* __restrict__ ew,
                                                            unsigned long long* __restrict__ cnt64,
                                                            unsigned short* __restrict__ eslot,
                                                            int E, int ebase, int elim) {
  if ((int)blockIdx.x >= nOwn) {
    edge_slice(ei, ew, cnt64, eslot, E,
               ebase + ((int)blockIdx.x - nOwn) * 1024 + (int)threadIdx.x, elim);
    return;
  }
  int i = blockIdx.x * 1024 + threadIdx.x;
  if (i < n) {
    if ((keys[i] >> 16) >= thrB[0]) {
      int pos = atomicAdd(ncnt, 1);
      candIdx[pos] = i;
    }
  }
}

// ---------- exact top-K select (block 0) + edge slice ----------
#define CCAP 6144
__global__ __launch_bounds__(1024) void select_edge_kernel(const unsigned* __restrict__ keys,
                                                           const int* __restrict__ candIdx,
                                                           const int* __restrict__ ncp,
                                                           const float* __restrict__ score,
                                                           int* __restrict__ perm,
                                                           float* __restrict__ tsc,
                                                           const int* __restrict__ ei,
                                                           const float* __restrict__ ew,
                                                           unsigned long long* __restrict__ cnt64,
                                                           unsigned short* __restrict__ eslot,
                                                           int E, int ebase, int elim) {
  if (blockIdx.x > 0) {
    edge_slice(ei, ew, cnt64, eslot, E, ebase + ((int)blockIdx.x - 1) * 1024 + (int)threadIdx.x, elim);
    return;
  }
  __shared__ unsigned sk[CCAP];
  __shared__ int si[CCAP];
  int nc = ncp[0];
  int t = threadIdx.x;
  int m = nc < CCAP ? nc : CCAP;
  for (int i = t; i < m; i += 1024) {
    int ci = candIdx[i];
    si[i] = ci;
    sk[i] = keys[ci];
  }
  __syncthreads();
  for (int ci = t; ci < nc; ci += 1024) {
    unsigned mk;
    int mi;
    if (ci < CCAP) { mk = sk[ci]; mi = si[ci]; }
    else { mi = candIdx[ci]; mk = keys[mi]; }
    int rank = 0;
    for (int j = 0; j < m; ++j) {
      unsigned kj = sk[j];
      int ij = si[j];
      rank += (kj > mk || (kj == mk && ij < mi)) ? 1 : 0;
    }
    for (int j = CCAP; j < nc; ++j) {
      int ij = candIdx[j];
      unsigned kj = keys[ij];
      rank += (kj > mk || (kj == mk && ij < mi)) ? 1 : 0;
    }
    if (rank < TK) {
      perm[rank] = mi;
      tsc[rank] = score[mi];
    }
  }
}

// ---------- GRU (blocks < 128, 128 thr) + edge slice; writes W transposed ----------
__global__ void gru_edge_kernel(const float* __restrict__ x, const int* __restrict__ perm,
                                const float* __restrict__ tsc, const float* __restrict__ W0,
                                const float* __restrict__ w_ih, const float* __restrict__ w_hh,
                                const float* __restrict__ b_ih, const float* __restrict__ b_hh,
                                float* __restrict__ WT,
                                const int* __restrict__ ei, const float* __restrict__ ew,
                                unsigned long long* __restrict__ cnt64,
                                unsigned short* __restrict__ eslot, int E, int ebase, int elim) {
  if ((int)blockIdx.x >= NF) {
    edge_slice(ei, ew, cnt64, eslot, E, ebase + ((int)blockIdx.x - NF) * 128 + (int)threadIdx.x, elim);
    return;
  }
  __shared__ float xs[NF], w0s[NF];
  int i = blockIdx.x, j = threadIdx.x;
  int pi = perm[i];
  float s = tsc[i];
  xs[j] = x[(size_t)pi * NF + j] * s;
  w0s[j] = W0[i * NF + j];
  __syncthreads();
  float gir = b_ih[j], giz = b_ih[NF + j], gin = b_ih[2 * NF + j];
  float ghr = b_hh[j], ghz = b_hh[NF + j], ghn = b_hh[2 * NF + j];
  const float* wr = w_ih + (size_t)j * NF;
  const float* wz = w_ih + (size_t)(NF + j) * NF;
  const float* wn = w_ih + (size_t)(2 * NF + j) * NF;
  const float* ur = w_hh + (size_t)j * NF;
  const float* uz = w_hh + (size_t)(NF + j) * NF;
  const float* un = w_hh + (size_t)(2 * NF + j) * NF;
#pragma unroll 4
  for (int k = 0; k < NF; ++k) {
    float xv = xs[k], wv = w0s[k];
    gir = fmaf(xv, wr[k], gir);
    giz = fmaf(xv, wz[k], giz);
    gin = fmaf(xv, wn[k], gin);
    ghr = fmaf(wv, ur[k], ghr);
    ghz = fmaf(wv, uz[k], ghz);
    ghn = fmaf(wv, un[k], ghn);
  }
  float r = 1.0f / (1.0f + expf(-(gir + ghr)));
  float z = 1.0f / (1.0f + expf(-(giz + ghz)));
  float nn = tanhf(gin + r * ghn);
  WT[(size_t)j * NF + i] = (1.0f - z) * nn + z * w0s[j];  // transposed: WT[n][k]
}

// ---------- scan over counts (block-local exclusive) + dinv ----------
#define SCAN_B 1024
__global__ __launch_bounds__(1024) void scan1_kernel(const unsigned long long* __restrict__ cnt64,
                                                     int* __restrict__ offL, int* __restrict__ bsum,
                                                     float* __restrict__ dinv, int n) {
  __shared__ int sd[SCAN_B];
  int t = threadIdx.x;
  int i = blockIdx.x * SCAN_B + t;
  int v = 0;
  if (i < n) {
    unsigned long long cv = cnt64[i];
    v = (int)(cv >> 32);
    float dsum = (float)((unsigned)cv) * (1.0f / 16777216.0f) + 1.0f;  // + self-loop
    dinv[i] = 1.0f / sqrtf(dsum);
  }
  sd[t] = v;
  __syncthreads();
  for (int s = 1; s < SCAN_B; s <<= 1) {
    int add = (t >= s) ? sd[t - s] : 0;
    __syncthreads();
    sd[t] += add;
    __syncthreads();
  }
  if (i <= n) offL[i] = sd[t] - v;  // block-local exclusive
  if (t == SCAN_B - 1) bsum[blockIdx.x] = sd[t];
}

// ---------- tiny: wave-scan of bsum -> bexc ----------
__global__ void scan2_kernel(const int* __restrict__ bsum, int* __restrict__ bexc, int nb) {
  int t = threadIdx.x;
  if (t < 64) {  // requires nb <= 63 (N <= 64K)
    int v = (t < nb) ? bsum[t] : 0;
    int incl = v;
#pragma unroll
    for (int s = 1; s < 64; s <<= 1) {
      int u = __shfl_up(incl, s, 64);
      if (t >= s) incl += u;
    }
    if (t <= nb) bexc[t] = incl - v;
  }
}

// ---------- GEMM1 (x f32 -> xw fp16) fused with CSR fill ----------
__global__ __launch_bounds__(256) void gemm1_fill_kernel(const float* __restrict__ x,
                                                         const float* __restrict__ Bt,
                                                         unsigned* __restrict__ Ch, int nrows,
                                                         int nbGemm,
                                                         const int* __restrict__ ei,
                                                         const float* __restrict__ ew,
                                                         const float* __restrict__ dinv,
                                                         const int* __restrict__ offL,
                                                         const int* __restrict__ bexc,
                                                         const unsigned short* __restrict__ eslot,
                                                         unsigned* __restrict__ epair, int E) {
  __shared__ char ldsA[64 * 256];
  __shared__ char ldsB[128 * 256];
  if ((int)blockIdx.x >= nbGemm) {
    int e = ((int)blockIdx.x - nbGemm) * 256 + (int)threadIdx.x;
    if (e < E) {
      int r = ei[e], c = ei[E + e];
      int pos = offL[c] + bexc[c >> 10] + (int)eslot[e];
      float cf = dinv[r] * ew[e] * dinv[c];
      unsigned hb = (unsigned)__builtin_bit_cast(unsigned short, __float2half(cf));
      epair[pos] = (unsigned)r | (hb << 16);
    }
    return;
  }
  const int t = threadIdx.x;
  const int row0 = blockIdx.x * 64;
  {  // stage Bt -> fp16 LDS
    const float2* B2 = (const float2*)Bt;
#pragma unroll
    for (int i = 0; i < 32; ++i) {
      int idx = i * 256 + t;
      int nn = idx >> 6, kp = idx & 63;
      float2 v = B2[idx];
      __half2 h = __floats2half2_rn(v.x, v.y);
      int byte = (nn * 256 + kp * 4) ^ ((nn & 7) << 4);
      *(unsigned*)&ldsB[byte] = *(unsigned*)&h;
    }
  }
  {  // stage A (f32 -> fp16)
    const float2* A2 = (const float2*)x;
#pragma unroll
    for (int i = 0; i < 16; ++i) {
      int idx = i * 256 + t;
      int r = idx >> 6, cp = idx & 63;
      int gr = row0 + r;
      float2 v = make_float2(0.f, 0.f);
      if (gr < nrows) v = A2[(size_t)gr * 64 + cp];
      __half2 h = __floats2half2_rn(v.x, v.y);
      int byte = (r * 256 + cp * 4) ^ ((r & 7) << 4);
      *(unsigned*)&ldsA[byte] = *(unsigned*)&h;
    }
  }
  __syncthreads();
  const int wave = t >> 6, l = t & 63;
  const int wr0 = wave * 16;
  const int lm = l & 15, q = l >> 4;
  floatx4 acc[8];
#pragma unroll
  for (int nt = 0; nt < 8; ++nt) acc[nt] = (floatx4){0.f, 0.f, 0.f, 0.f};
#pragma unroll
  for (int ks = 0; ks < 4; ++ks) {
    int arow = wr0 + lm;
    half8 a = *(const half8*)&ldsA[(arow * 256 + ks * 64 + q * 16) ^ ((arow & 7) << 4)];
#pragma unroll
    for (int nt = 0; nt < 8; ++nt) {
      int nn = nt * 16 + lm;
      half8 b = *(const half8*)&ldsB[(nn * 256 + ks * 64 + q * 16) ^ ((nn & 7) << 4)];
      acc[nt] = __builtin_amdgcn_mfma_f32_16x16x32_f16(a, b, acc[nt], 0, 0, 0);
    }
  }
#pragma unroll
  for (int nt = 0; nt < 8; ++nt) {
    int col = nt * 16 + lm;
#pragma unroll
    for (int r = 0; r < 4; ++r) {
      int gr = row0 + wr0 + q * 4 + r;
      if (gr < nrows)
        ((__half*)Ch)[(size_t)gr * NF + col] = __float2half(acc[nt][r]);
    }
  }
}

// ---------- aggregate: one wave per node, 8 gathers in flight, relu + fp16 out ----------
__global__ void aggregate_kernel(const unsigned* __restrict__ epair, const int* __restrict__ offL,
                                 const int* __restrict__ bexc, const float* __restrict__ dinv,
                                 const uint4* __restrict__ xw4, unsigned* __restrict__ hh, int n) {
  int w = (int)((blockIdx.x * (size_t)blockDim.x + threadIdx.x) >> 6);
  if (w >= n) return;
  int lane = threadIdx.x & 63;
  int q = lane >> 4, l16 = lane & 15;
  int n0 = offL[w] + bexc[w >> 10];
  int n1 = offL[w + 1] + bexc[(w + 1) >> 10];
  float acc[8] = {0.f, 0.f, 0.f, 0.f, 0.f, 0.f, 0.f, 0.f};
  if (q == 0) {
    float dv = dinv[w];
    float c2 = dv * dv;
    uint4 su = xw4[(size_t)w * 16 + l16];
    float2 f0 = __half22float2(*(const __half2*)&su.x);
    float2 f1 = __half22float2(*(const __half2*)&su.y);
    float2 f2 = __half22float2(*(const __half2*)&su.z);
    float2 f3 = __half22float2(*(const __half2*)&su.w);
    acc[0] = c2 * f0.x; acc[1] = c2 * f0.y; acc[2] = c2 * f1.x; acc[3] = c2 * f1.y;
    acc[4] = c2 * f2.x; acc[5] = c2 * f2.y; acc[6] = c2 * f3.x; acc[7] = c2 * f3.y;
  }
  int e = n0 + q;
  for (; e + 4 < n1; e += 8) {
    unsigned p0 = epair[e], p1 = epair[e + 4];
    uint4 u0 = xw4[(size_t)(p0 & 0xFFFFu) * 16 + l16];
    uint4 u1 = xw4[(size_t)(p1 & 0xFFFFu) * 16 + l16];
    float c0 = __half2float(__builtin_bit_cast(__half, (unsigned short)(p0 >> 16)));
    float c1 = __half2float(__builtin_bit_cast(__half, (unsigned short)(p1 >> 16)));
    float2 f0, f1, f2, f3;
    f0 = __half22float2(*(const __half2*)&u0.x); f1 = __half22float2(*(const __half2*)&u0.y);
    f2 = __half22float2(*(const __half2*)&u0.z); f3 = __half22float2(*(const __half2*)&u0.w);
    acc[0] = fmaf(c0, f0.x, acc[0]); acc[1] = fmaf(c0, f0.y, acc[1]);
    acc[2] = fmaf(c0, f1.x, acc[2]); acc[3] = fmaf(c0, f1.y, acc[3]);
    acc[4] = fmaf(c0, f2.x, acc[4]); acc[5] = fmaf(c0, f2.y, acc[5]);
    acc[6] = fmaf(c0, f3.x, acc[6]); acc[7] = fmaf(c0, f3.y, acc[7]);
    f0 = __half22float2(*(const __half2*)&u1.x); f1 = __half22float2(*(const __half2*)&u1.y);
    f2 = __half22float2(*(const __half2*)&u1.z); f3 = __half22float2(*(const __half2*)&u1.w);
    acc[0] = fmaf(c1, f0.x, acc[0]); acc[1] = fmaf(c1, f0.y, acc[1]);
    acc[2] = fmaf(c1, f1.x, acc[2]); acc[3] = fmaf(c1, f1.y, acc[3]);
    acc[4] = fmaf(c1, f2.x, acc[4]); acc[5] = fmaf(c1, f2.y, acc[5]);
    acc[6] = fmaf(c1, f3.x, acc[6]); acc[7] = fmaf(c1, f3.y, acc[7]);
  }
  for (; e < n1; e += 4) {
    unsigned p0 = epair[e];
    uint4 u0 = xw4[(size_t)(p0 & 0xFFFFu) * 16 + l16];
    float c0 = __half2float(__builtin_bit_cast(__half, (unsigned short)(p0 >> 16)));
    float2 f0 = __half22float2(*(const __half2*)&u0.x);
    float2 f1 = __half22float2(*(const __half2*)&u0.y);
    float2 f2 = __half22float2(*(const __half2*)&u0.z);
    float2 f3 = __half22float2(*(const __half2*)&u0.w);
    acc[0] = fmaf(c0, f0.x, acc[0]); acc[1] = fmaf(c0, f0.y, acc[1]);
    acc[2] = fmaf(c0, f1.x, acc[2]); acc[3] = fmaf(c0, f1.y, acc[3]);
    acc[4] = fmaf(c0, f2.x, acc[4]); acc[5] = fmaf(c0, f2.y, acc[5]);
    acc[6] = fmaf(c0, f3.x, acc[6]); acc[7] = fmaf(c0, f3.y, acc[7]);
  }
#pragma unroll
  for (int j = 0; j < 8; ++j) {
    float a = acc[j];
    a += __shfl_xor(a, 16, 64);
    a += __shfl_xor(a, 32, 64);
    acc[j] = a;
  }
  if (q == 0) {
    __half2 h0 = __floats2half2_rn(fmaxf(acc[0], 0.f), fmaxf(acc[1], 0.f));
    __half2 h1 = __floats2half2_rn(fmaxf(acc[2], 0.f), fmaxf(acc[3], 0.f));
    __half2 h2 = __floats2half2_rn(fmaxf(acc[4], 0.f), fmaxf(acc[5], 0.f));
    __half2 h3 = __floats2half2_rn(fmaxf(acc[6], 0.f), fmaxf(acc[7], 0.f));
    uint4 o;
    o.x = *(unsigned*)&h0; o.y = *(unsigned*)&h1; o.z = *(unsigned*)&h2; o.w = *(unsigned*)&h3;
    *(uint4*)&hh[(size_t)w * 64 + l16 * 4] = o;
  }
}

// ---------- MFMA GEMM (generic): C[m][n] = sum_k A[m][k]*Bt[n][k] ----------
template <int HIN, int HOUT, int BIAS>
__global__ __launch_bounds__(256) void gemm_mfma_kernel(const void* __restrict__ Ap,
                                                        const float* __restrict__ Bt,
                                                        const float* __restrict__ bias,
                                                        void* __restrict__ Cp, int nrows) {
  __shared__ char ldsA[64 * 256];
  __shared__ char ldsB[128 * 256];
  const int t = threadIdx.x;
  const int row0 = blockIdx.x * 64;
  {
    const float2* B2 = (const float2*)Bt;
#pragma unroll
    for (int i = 0; i < 32; ++i) {
      int idx = i * 256 + t;
      int nn = idx >> 6, kp = idx & 63;
      float2 v = B2[idx];
      __half2 h = __floats2half2_rn(v.x, v.y);
      int byte = (nn * 256 + kp * 4) ^ ((nn & 7) << 4);
      *(unsigned*)&ldsB[byte] = *(unsigned*)&h;
    }
  }
  if (HIN) {
    const unsigned* Ah = (const unsigned*)Ap;
#pragma unroll
    for (int i = 0; i < 16; ++i) {
      int idx = i * 256 + t;
      int r = idx >> 6, cp = idx & 63;
      int gr = row0 + r;
      unsigned v = (gr < nrows) ? Ah[(size_t)gr * 64 + cp] : 0u;
      int byte = (r * 256 + cp * 4) ^ ((r & 7) << 4);
      *(unsigned*)&ldsA[byte] = v;
    }
  } else {
    const float2* A2 = (const float2*)Ap;
#pragma unroll
    for (int i = 0; i < 16; ++i) {
      int idx = i * 256 + t;
      int r = idx >> 6, cp = idx & 63;
      int gr = row0 + r;
      float2 v = make_float2(0.f, 0.f);
      if (gr < nrows) v = A2[(size_t)gr * 64 + cp];
      __half2 h = __floats2half2_rn(v.x, v.y);
      int byte = (r * 256 + cp * 4) ^ ((r & 7) << 4);
      *(unsigned*)&ldsA[byte] = *(unsigned*)&h;
    }
  }
  __syncthreads();
  const int wave = t >> 6, l = t & 63;
  const int wr0 = wave * 16;
  const int lm = l & 15, q = l >> 4;
  floatx4 acc[8];
#pragma unroll
  for (int nt = 0; nt < 8; ++nt) acc[nt] = (floatx4){0.f, 0.f, 0.f, 0.f};
#pragma unroll
  for (int ks = 0; ks < 4; ++ks) {
    int arow = wr0 + lm;
    half8 a = *(const half8*)&ldsA[(arow * 256 + ks * 64 + q * 16) ^ ((arow & 7) << 4)];
#pragma unroll
    for (int nt = 0; nt < 8; ++nt) {
      int nn = nt * 16 + lm;
      half8 b = *(const half8*)&ldsB[(nn * 256 + ks * 64 + q * 16) ^ ((nn & 7) << 4)];
      acc[nt] = __builtin_amdgcn_mfma_f32_16x16x32_f16(a, b, acc[nt], 0, 0, 0);
    }
  }
#pragma unroll
  for (int nt = 0; nt < 8; ++nt) {
    int col = nt * 16 + lm;
    float bv = BIAS ? bias[col] : 0.f;
#pragma unroll
    for (int r = 0; r < 4; ++r) {
      int gr = row0 + wr0 + q * 4 + r;
      if (gr < nrows) {
        float v = acc[nt][r] + bv;
        if (HOUT) ((__half*)Cp)[(size_t)gr * NF + col] = __float2half(v);
        else ((float*)Cp)[(size_t)gr * NF + col] = v;
      }
    }
  }
}

extern "C" void kernel_launch(void* const* d_in, const int* in_sizes, int n_in,
                              void* d_out, int out_size, void* d_ws, size_t ws_size,
                              hipStream_t stream) {
  const float* x = (const float*)d_in[0];
  const int* ei = (const int*)d_in[1];
  const float* ew = (const float*)d_in[2];
  const float* p = (const float*)d_in[3];
  const float* w_ih = (const float*)d_in[4];
  const float* w_hh = (const float*)d_in[5];
  const float* b_ih = (const float*)d_in[6];
  const float* b_hh = (const float*)d_in[7];
  const float* W0 = (const float*)d_in[8];
  const float* W_lin = (const float*)d_in[9];
  const float* b_lin = (const float*)d_in[10];
  float* out = (float*)d_out;

  const int N = in_sizes[0] / NF;  // 50000 (< 65536 required for 16-bit rows)
  const int E = in_sizes[1] / 2;   // 800000

  char* w = (char*)d_ws;
  unsigned* xwh = (unsigned*)w;                                 // N*64 (fp16 xw)
  unsigned* hh = xwh + (size_t)N * 64;                          // N*64 (fp16 relu(h))
  float* score = (float*)(hh + (size_t)N * 64);                 // N
  unsigned* keys = (unsigned*)(score + N);                      // N
  unsigned long long* cnt64 = (unsigned long long*)(keys + N);  // ZERO region: N x 8B
  unsigned* bins = (unsigned*)(cnt64 + N);                      // 65536
  int* ncnt = (int*)(bins + 65536);                             // 1 (end of ZERO region)
  float* dinv = (float*)(ncnt + 1);                             // N
  unsigned* thrB = (unsigned*)(dinv + N);                       // 1
  int* candIdx = (int*)(thrB + 1);                              // N
  int* offL = candIdx + N;                                      // N+1
  int* bsum = offL + N + 1;                                     // 64
  int* bexc = bsum + 64;                                        // 64
  unsigned short* eslot = (unsigned short*)(bexc + 64);         // E x 2B
  unsigned* epair = (unsigned*)(eslot + E);                     // E x 4B
  float* WevT = (float*)(epair + E);                            // 128*128
  int* perm = (int*)(WevT + NF * NF);                           // 128
  float* tsc = (float*)(perm + NF);                             // 128

  const int nb = (N + SCAN_B - 1) / SCAN_B;
  const int nbEdge = (E + 255) / 256;
  const int nbGemm = (N + 63) / 64;
  const int nbScore = (N + 31) / 32;
  const int nOwnC = (N + 1023) / 1024;

  // edge-slice partition: 60% rides with score, remaining 40% over 4 stages
  const int eA1 = (int)(((long long)E * 3) / 5);
  const int perR = (E - eA1 + 3) / 4;
  const int eB1 = (eA1 + perR < E) ? eA1 + perR : E;
  const int eC1 = (eB1 + perR < E) ? eB1 + perR : E;
  const int eD1 = (eC1 + perR < E) ? eC1 + perR : E;
  const int bSA = (eA1 + 255) / 256;
  const int bSB = (eB1 - eA1 + 1023) / 1024;
  const int bSC = (eC1 - eB1 + 1023) / 1024;
  const int bSD = (eD1 - eC1 + 1023) / 1024;
  const int bSE = (E - eD1 + 127) / 128;

  // zero region: cnt64 (N*8) + bins (256KB) + ncnt (4), padded to 16B
  const int n4zero = (N * 8 + 65536 * 4 + 4 + 15) / 16;

  zero_kernel<<<64, 1024, 0, stream>>>((uint4*)cnt64, n4zero);
  score_edge_kernel<<<nbScore + bSA, 256, 0, stream>>>(x, p, score, keys, bins, N, nbScore,
                                                       ei, ew, cnt64, eslot, E, 0, eA1);
  findbin_edge_kernel<<<1 + bSB, 1024, 0, stream>>>(bins, thrB, ei, ew, cnt64, eslot, E, eA1, eB1);
  compact_edge_kernel<<<nOwnC + bSC, 1024, 0, stream>>>(keys, thrB, ncnt, candIdx, N, nOwnC,
                                                        ei, ew, cnt64, eslot, E, eB1, eC1);
  select_edge_kernel<<<1 + bSD, 1024, 0, stream>>>(keys, candIdx, ncnt, score, perm, tsc,
                                                   ei, ew, cnt64, eslot, E, eC1, eD1);
  gru_edge_kernel<<<NF + bSE, NF, 0, stream>>>(x, perm, tsc, W0, w_ih, w_hh, b_ih, b_hh, WevT,
                                               ei, ew, cnt64, eslot, E, eD1, E);
  scan1_kernel<<<nb, SCAN_B, 0, stream>>>(cnt64, offL, bsum, dinv, N);
  scan2_kernel<<<1, 64, 0, stream>>>(bsum, bexc, nb);
  gemm1_fill_kernel<<<nbGemm + nbEdge, 256, 0, stream>>>(x, WevT, xwh, N, nbGemm,
                                                         ei, ew, dinv, offL, bexc, eslot, epair, E);
  aggregate_kernel<<<(N + 3) / 4, 256, 0, stream>>>(epair, offL, bexc, dinv,
                                                    (const uint4*)xwh, hh, N);
  gemm_mfma_kernel<1, 0, 1><<<nbGemm, 256, 0, stream>>>(hh, W_lin, b_lin, out, N);
}

// Round 11
// 197.930 us; speedup vs baseline: 2.0898x; 1.0038x over previous
//
#include <hip/hip_runtime.h>
#include <hip/hip_fp16.h>

#define NF 128
#define TK 128

typedef _Float16 f16;
typedef f16 half8 __attribute__((ext_vector_type(8)));
typedef float floatx4 __attribute__((ext_vector_type(4)));

__device__ __forceinline__ unsigned okey(float f) {
  unsigned u = __float_as_uint(f);
  return (u & 0x80000000u) ? ~u : (u | 0x80000000u);
}

// edge-histogram slice: one edge per thread
__device__ __forceinline__ void edge_slice(const int* __restrict__ ei, const float* __restrict__ ew,
                                           unsigned long long* __restrict__ cnt64,
                                           unsigned short* __restrict__ eslot, int E, int e, int elim) {
  if (e < elim) {
    int c = ei[E + e];
    unsigned fx = __float2uint_rn(ew[e] * 16777216.0f);  // 2^24 fixed point
    unsigned long long old =
        atomicAdd(&cnt64[c], ((unsigned long long)1 << 32) | (unsigned long long)fx);
    eslot[e] = (unsigned short)(old >> 32);
  }
}

// ---------- zero workspace region ----------
__global__ void zero_kernel(uint4* __restrict__ dst, int n4) {
  int i = blockIdx.x * blockDim.x + threadIdx.x;
  int stride = gridDim.x * blockDim.x;
  uint4 z = make_uint4(0u, 0u, 0u, 0u);
  for (; i < n4; i += stride) dst[i] = z;
}

// ---------- scores: 2 rows/thread, 8 outstanding loads; co-scheduled edge slice ----------
__global__ void score_edge_kernel(const float* __restrict__ x, const float* __restrict__ p,
                                  float* __restrict__ score, unsigned* __restrict__ keys,
                                  unsigned* __restrict__ bins, int n, int nbScore,
                                  const int* __restrict__ ei, const float* __restrict__ ew,
                                  unsigned long long* __restrict__ cnt64,
                                  unsigned short* __restrict__ eslot, int E, int ebase, int elim) {
  if ((int)blockIdx.x >= nbScore) {
    edge_slice(ei, ew, cnt64, eslot, E,
               ebase + ((int)blockIdx.x - nbScore) * 256 + (int)threadIdx.x, elim);
    return;
  }
  int t = threadIdx.x;
  int rib = t >> 3;   // 0..31
  int l8 = t & 7;     // 8 lanes per row
  int rA = blockIdx.x * 64 + rib;
  int rB = rA + 32;
  bool vA = rA < n, vB = rB < n;
  const float4* pr = (const float4*)&p[l8 * 16];
  float4 p0 = pr[0], p1 = pr[1], p2 = pr[2], p3 = pr[3];
  float4 z4 = make_float4(0.f, 0.f, 0.f, 0.f);
  float4 a0 = z4, a1 = z4, a2 = z4, a3 = z4;
  float4 b0 = z4, b1 = z4, b2 = z4, b3 = z4;
  if (vA) {
    const float4* xa = (const float4*)&x[(size_t)rA * NF + l8 * 16];
    a0 = xa[0]; a1 = xa[1]; a2 = xa[2]; a3 = xa[3];
  }
  if (vB) {
    const float4* xb = (const float4*)&x[(size_t)rB * NF + l8 * 16];
    b0 = xb[0]; b1 = xb[1]; b2 = xb[2]; b3 = xb[3];
  }
  float dA = 0.f, dB = 0.f, pp = 0.f;
  dA = fmaf(a0.x, p0.x, dA); dA = fmaf(a0.y, p0.y, dA); dA = fmaf(a0.z, p0.z, dA); dA = fmaf(a0.w, p0.w, dA);
  dA = fmaf(a1.x, p1.x, dA); dA = fmaf(a1.y, p1.y, dA); dA = fmaf(a1.z, p1.z, dA); dA = fmaf(a1.w, p1.w, dA);
  dA = fmaf(a2.x, p2.x, dA); dA = fmaf(a2.y, p2.y, dA); dA = fmaf(a2.z, p2.z, dA); dA = fmaf(a2.w, p2.w, dA);
  dA = fmaf(a3.x, p3.x, dA); dA = fmaf(a3.y, p3.y, dA); dA = fmaf(a3.z, p3.z, dA); dA = fmaf(a3.w, p3.w, dA);
  dB = fmaf(b0.x, p0.x, dB); dB = fmaf(b0.y, p0.y, dB); dB = fmaf(b0.z, p0.z, dB); dB = fmaf(b0.w, p0.w, dB);
  dB = fmaf(b1.x, p1.x, dB); dB = fmaf(b1.y, p1.y, dB); dB = fmaf(b1.z, p1.z, dB); dB = fmaf(b1.w, p1.w, dB);
  dB = fmaf(b2.x, p2.x, dB); dB = fmaf(b2.y, p2.y, dB); dB = fmaf(b2.z, p2.z, dB); dB = fmaf(b2.w, p2.w, dB);
  dB = fmaf(b3.x, p3.x, dB); dB = fmaf(b3.y, p3.y, dB); dB = fmaf(b3.z, p3.z, dB); dB = fmaf(b3.w, p3.w, dB);
  pp = fmaf(p0.x, p0.x, pp); pp = fmaf(p0.y, p0.y, pp); pp = fmaf(p0.z, p0.z, pp); pp = fmaf(p0.w, p0.w, pp);
  pp = fmaf(p1.x, p1.x, pp); pp = fmaf(p1.y, p1.y, pp); pp = fmaf(p1.z, p1.z, pp); pp = fmaf(p1.w, p1.w, pp);
  pp = fmaf(p2.x, p2.x, pp); pp = fmaf(p2.y, p2.y, pp); pp = fmaf(p2.z, p2.z, pp); pp = fmaf(p2.w, p2.w, pp);
  pp = fmaf(p3.x, p3.x, pp); pp = fmaf(p3.y, p3.y, pp); pp = fmaf(p3.z, p3.z, pp); pp = fmaf(p3.w, p3.w, pp);
#pragma unroll
  for (int off = 4; off > 0; off >>= 1) {
    dA += __shfl_down(dA, off, 8);
    dB += __shfl_down(dB, off, 8);
    pp += __shfl_down(pp, off, 8);
  }
  if (l8 == 0) {
    float pni = 1.0f / sqrtf(pp);
    if (vA) {
      float s = tanhf(dA * pni);
      score[rA] = s;
      unsigned k = okey(s);
      keys[rA] = k;
      atomicAdd(&bins[k >> 16], 1u);
    }
    if (vB) {
      float s = tanhf(dB * pni);
      score[rB] = s;
      unsigned k = okey(s);
      keys[rB] = k;
      atomicAdd(&bins[k >> 16], 1u);
    }
  }
}

// ---------- findbin (block 0) + edge slice ----------
__global__ __launch_bounds__(1024) void findbin_edge_kernel(const unsigned* __restrict__ bins,
                                                            unsigned* __restrict__ thrB,
                                                            const int* __restrict__ ei,
                                                            const float* __restrict__ ew,
                                                            unsigned long long* __restrict__ cnt64,
                                                            unsigned short* __restrict__ eslot,
                                                            int E, int ebase, int elim) {
  if (blockIdx.x > 0) {
    edge_slice(ei, ew, cnt64, eslot, E, ebase + ((int)blockIdx.x - 1) * 1024 + (int)threadIdx.x, elim);
    return;
  }
  __shared__ unsigned csum[1024];
  int t = threadIdx.x;
  unsigned hv[64];
  unsigned s = 0;
  const unsigned* bp = bins + t * 64;
#pragma unroll
  for (int b = 0; b < 64; ++b) { hv[b] = bp[b]; s += hv[b]; }
  csum[t] = s;
  __syncthreads();
  for (int st = 1; st < 1024; st <<= 1) {
    unsigned add = (t + st < 1024) ? csum[t + st] : 0u;
    __syncthreads();
    csum[t] += add;
    __syncthreads();
  }
  unsigned mySum = csum[t];
  unsigned above = (t == 1023) ? 0u : csum[t + 1];
  if (mySum >= (unsigned)TK && above < (unsigned)TK) {
    unsigned cum = above;
    int b = 63;
    for (; b > 0; --b) {
      unsigned h = hv[b];
      if (cum + h >= (unsigned)TK) break;
      cum += h;
    }
    thrB[0] = (unsigned)(t * 64 + b);
  }
}

// ---------- compact candidates (blocks < nOwn) + edge slice ----------
__global__ __launch_bounds__(1024) void compact_edge_kernel(const unsigned* __restrict__ keys,
                                                            const unsigned* __restrict__ thrB,
                                                            int* __restrict__ ncnt,
                                                            int* __restrict__ candIdx, int n, int nOwn,
                                                            const int* __restrict__ ei,
                                                            const float* __restrict__ ew,
                                                            unsigned long long* __restrict__ cnt64,
                                                            unsigned short* __restrict__ eslot,
                                                            int E, int ebase, int elim) {
  if ((int)blockIdx.x >= nOwn) {
    edge_slice(ei, ew, cnt64, eslot, E,
               ebase + ((int)blockIdx.x - nOwn) * 1024 + (int)threadIdx.x, elim);
    return;
  }
  int i = blockIdx.x * 1024 + threadIdx.x;
  if (i < n) {
    if ((keys[i] >> 16) >= thrB[0]) {
      int pos = atomicAdd(ncnt, 1);
      candIdx[pos] = i;
    }
  }
}

// ---------- exact top-K select (block 0) + edge slice ----------
#define CCAP 6144
__global__ __launch_bounds__(1024) void select_edge_kernel(const unsigned* __restrict__ keys,
                                                           const int* __restrict__ candIdx,
                                                           const int* __restrict__ ncp,
                                                           const float* __restrict__ score,
                                                           int* __restrict__ perm,
                                                           float* __restrict__ tsc,
                                                           const int* __restrict__ ei,
                                                           const float* __restrict__ ew,
                                                           unsigned long long* __restrict__ cnt64,
                                                           unsigned short* __restrict__ eslot,
                                                           int E, int ebase, int elim) {
  if (blockIdx.x > 0) {
    edge_slice(ei, ew, cnt64, eslot, E, ebase + ((int)blockIdx.x - 1) * 1024 + (int)threadIdx.x, elim);
    return;
  }
  __shared__ unsigned sk[CCAP];
  __shared__ int si[CCAP];
  int nc = ncp[0];
  int t = threadIdx.x;
  int m = nc < CCAP ? nc : CCAP;
  for (int i = t; i < m; i += 1024) {
    int ci = candIdx[i];
    si[i] = ci;
    sk[i] = keys[ci];
  }
  __syncthreads();
  for (int ci = t; ci < nc; ci += 1024) {
    unsigned mk;
    int mi;
    if (ci < CCAP) { mk = sk[ci]; mi = si[ci]; }
    else { mi = candIdx[ci]; mk = keys[mi]; }
    int rank = 0;
    for (int j = 0; j < m; ++j) {
      unsigned kj = sk[j];
      int ij = si[j];
      rank += (kj > mk || (kj == mk && ij < mi)) ? 1 : 0;
    }
    for (int j = CCAP; j < nc; ++j) {
      int ij = candIdx[j];
      unsigned kj = keys[ij];
      rank += (kj > mk || (kj == mk && ij < mi)) ? 1 : 0;
    }
    if (rank < TK) {
      perm[rank] = mi;
      tsc[rank] = score[mi];
    }
  }
}

// ---------- GRU (blocks < 128, 128 thr) + edge slice; writes W transposed ----------
__global__ void gru_edge_kernel(const float* __restrict__ x, const int* __restrict__ perm,
                                const float* __restrict__ tsc, const float* __restrict__ W0,
                                const float* __restrict__ w_ih, const float* __restrict__ w_hh,
                                const float* __restrict__ b_ih, const float* __restrict__ b_hh,
                                float* __restrict__ WT,
                                const int* __restrict__ ei, const float* __restrict__ ew,
                                unsigned long long* __restrict__ cnt64,
                                unsigned short* __restrict__ eslot, int E, int ebase, int elim) {
  if ((int)blockIdx.x >= NF) {
    edge_slice(ei, ew, cnt64, eslot, E, ebase + ((int)blockIdx.x - NF) * 128 + (int)threadIdx.x, elim);
    return;
  }
  __shared__ float xs[NF], w0s[NF];
  int i = blockIdx.x, j = threadIdx.x;
  int pi = perm[i];
  float s = tsc[i];
  xs[j] = x[(size_t)pi * NF + j] * s;
  w0s[j] = W0[i * NF + j];
  __syncthreads();
  float gir = b_ih[j], giz = b_ih[NF + j], gin = b_ih[2 * NF + j];
  float ghr = b_hh[j], ghz = b_hh[NF + j], ghn = b_hh[2 * NF + j];
  const float* wr = w_ih + (size_t)j * NF;
  const float* wz = w_ih + (size_t)(NF + j) * NF;
  const float* wn = w_ih + (size_t)(2 * NF + j) * NF;
  const float* ur = w_hh + (size_t)j * NF;
  const float* uz = w_hh + (size_t)(NF + j) * NF;
  const float* un = w_hh + (size_t)(2 * NF + j) * NF;
#pragma unroll 4
  for (int k = 0; k < NF; ++k) {
    float xv = xs[k], wv = w0s[k];
    gir = fmaf(xv, wr[k], gir);
    giz = fmaf(xv, wz[k], giz);
    gin = fmaf(xv, wn[k], gin);
    ghr = fmaf(wv, ur[k], ghr);
    ghz = fmaf(wv, uz[k], ghz);
    ghn = fmaf(wv, un[k], ghn);
  }
  float r = 1.0f / (1.0f + expf(-(gir + ghr)));
  float z = 1.0f / (1.0f + expf(-(giz + ghz)));
  float nn = tanhf(gin + r * ghn);
  WT[(size_t)j * NF + i] = (1.0f - z) * nn + z * w0s[j];  // transposed: WT[n][k]
}

// ---------- scan over counts (block-local exclusive) + dinv ----------
#define SCAN_B 1024
__global__ __launch_bounds__(1024) void scan1_kernel(const unsigned long long* __restrict__ cnt64,
                                                     int* __restrict__ offL, int* __restrict__ bsum,
                                                     float* __restrict__ dinv, int n) {
  __shared__ int sd[SCAN_B];
  int t = threadIdx.x;
  int i = blockIdx.x * SCAN_B + t;
  int v = 0;
  if (i < n) {
    unsigned long long cv = cnt64[i];
    v = (int)(cv >> 32);
    float dsum = (float)((unsigned)cv) * (1.0f / 16777216.0f) + 1.0f;  // + self-loop
    dinv[i] = 1.0f / sqrtf(dsum);
  }
  sd[t] = v;
  __syncthreads();
  for (int s = 1; s < SCAN_B; s <<= 1) {
    int add = (t >= s) ? sd[t - s] : 0;
    __syncthreads();
    sd[t] += add;
    __syncthreads();
  }
  if (i <= n) offL[i] = sd[t] - v;  // block-local exclusive
  if (t == SCAN_B - 1) bsum[blockIdx.x] = sd[t];
}

// ---------- tiny: wave-scan of bsum -> bexc ----------
__global__ void scan2_kernel(const int* __restrict__ bsum, int* __restrict__ bexc, int nb) {
  int t = threadIdx.x;
  if (t < 64) {  // requires nb <= 63 (N <= 64K)
    int v = (t < nb) ? bsum[t] : 0;
    int incl = v;
#pragma unroll
    for (int s = 1; s < 64; s <<= 1) {
      int u = __shfl_up(incl, s, 64);
      if (t >= s) incl += u;
    }
    if (t <= nb) bexc[t] = incl - v;
  }
}

// ---------- GEMM1 (x f32 -> xw fp16) fused with CSR fill ----------
__global__ __launch_bounds__(256) void gemm1_fill_kernel(const float* __restrict__ x,
                                                         const float* __restrict__ Bt,
                                                         unsigned* __restrict__ Ch, int nrows,
                                                         int nbGemm,
                                                         const int* __restrict__ ei,
                                                         const float* __restrict__ ew,
                                                         const float* __restrict__ dinv,
                                                         const int* __restrict__ offL,
                                                         const int* __restrict__ bexc,
                                                         const unsigned short* __restrict__ eslot,
                                                         unsigned* __restrict__ epair, int E) {
  __shared__ char ldsA[64 * 256];
  __shared__ char ldsB[128 * 256];
  if ((int)blockIdx.x >= nbGemm) {
    int e = ((int)blockIdx.x - nbGemm) * 256 + (int)threadIdx.x;
    if (e < E) {
      int r = ei[e], c = ei[E + e];
      int pos = offL[c] + bexc[c >> 10] + (int)eslot[e];
      float cf = dinv[r] * ew[e] * dinv[c];
      unsigned hb = (unsigned)__builtin_bit_cast(unsigned short, __float2half(cf));
      epair[pos] = (unsigned)r | (hb << 16);
    }
    return;
  }
  const int t = threadIdx.x;
  const int row0 = blockIdx.x * 64;
  {  // stage Bt -> fp16 LDS
    const float2* B2 = (const float2*)Bt;
#pragma unroll
    for (int i = 0; i < 32; ++i) {
      int idx = i * 256 + t;
      int nn = idx >> 6, kp = idx & 63;
      float2 v = B2[idx];
      __half2 h = __floats2half2_rn(v.x, v.y);
      int byte = (nn * 256 + kp * 4) ^ ((nn & 7) << 4);
      *(unsigned*)&ldsB[byte] = *(unsigned*)&h;
    }
  }
  {  // stage A (f32 -> fp16)
    const float2* A2 = (const float2*)x;
#pragma unroll
    for (int i = 0; i < 16; ++i) {
      int idx = i * 256 + t;
      int r = idx >> 6, cp = idx & 63;
      int gr = row0 + r;
      float2 v = make_float2(0.f, 0.f);
      if (gr < nrows) v = A2[(size_t)gr * 64 + cp];
      __half2 h = __floats2half2_rn(v.x, v.y);
      int byte = (r * 256 + cp * 4) ^ ((r & 7) << 4);
      *(unsigned*)&ldsA[byte] = *(unsigned*)&h;
    }
  }
  __syncthreads();
  const int wave = t >> 6, l = t & 63;
  const int wr0 = wave * 16;
  const int lm = l & 15, q = l >> 4;
  floatx4 acc[8];
#pragma unroll
  for (int nt = 0; nt < 8; ++nt) acc[nt] = (floatx4){0.f, 0.f, 0.f, 0.f};
#pragma unroll
  for (int ks = 0; ks < 4; ++ks) {
    int arow = wr0 + lm;
    half8 a = *(const half8*)&ldsA[(arow * 256 + ks * 64 + q * 16) ^ ((arow & 7) << 4)];
#pragma unroll
    for (int nt = 0; nt < 8; ++nt) {
      int nn = nt * 16 + lm;
      half8 b = *(const half8*)&ldsB[(nn * 256 + ks * 64 + q * 16) ^ ((nn & 7) << 4)];
      acc[nt] = __builtin_amdgcn_mfma_f32_16x16x32_f16(a, b, acc[nt], 0, 0, 0);
    }
  }
#pragma unroll
  for (int nt = 0; nt < 8; ++nt) {
    int col = nt * 16 + lm;
#pragma unroll
    for (int r = 0; r < 4; ++r) {
      int gr = row0 + wr0 + q * 4 + r;
      if (gr < nrows)
        ((__half*)Ch)[(size_t)gr * NF + col] = __float2half(acc[nt][r]);
    }
  }
}

// ---------- aggregate: one wave per node, 8 gathers in flight, relu + fp16 out ----------
__global__ void aggregate_kernel(const unsigned* __restrict__ epair, const int* __restrict__ offL,
                                 const int* __restrict__ bexc, const float* __restrict__ dinv,
                                 const uint4* __restrict__ xw4, unsigned* __restrict__ hh, int n) {
  int w = (int)((blockIdx.x * (size_t)blockDim.x + threadIdx.x) >> 6);
  if (w >= n) return;
  int lane = threadIdx.x & 63;
  int q = lane >> 4, l16 = lane & 15;
  int n0 = offL[w] + bexc[w >> 10];
  int n1 = offL[w + 1] + bexc[(w + 1) >> 10];
  float acc[8] = {0.f, 0.f, 0.f, 0.f, 0.f, 0.f, 0.f, 0.f};
  if (q == 0) {
    float dv = dinv[w];
    float c2 = dv * dv;
    uint4 su = xw4[(size_t)w * 16 + l16];
    float2 f0 = __half22float2(*(const __half2*)&su.x);
    float2 f1 = __half22float2(*(const __half2*)&su.y);
    float2 f2 = __half22float2(*(const __half2*)&su.z);
    float2 f3 = __half22float2(*(const __half2*)&su.w);
    acc[0] = c2 * f0.x; acc[1] = c2 * f0.y; acc[2] = c2 * f1.x; acc[3] = c2 * f1.y;
    acc[4] = c2 * f2.x; acc[5] = c2 * f2.y; acc[6] = c2 * f3.x; acc[7] = c2 * f3.y;
  }
  int e = n0 + q;
  for (; e + 4 < n1; e += 8) {
    unsigned p0 = epair[e], p1 = epair[e + 4];
    uint4 u0 = xw4[(size_t)(p0 & 0xFFFFu) * 16 + l16];
    uint4 u1 = xw4[(size_t)(p1 & 0xFFFFu) * 16 + l16];
    float c0 = __half2float(__builtin_bit_cast(__half, (unsigned short)(p0 >> 16)));
    float c1 = __half2float(__builtin_bit_cast(__half, (unsigned short)(p1 >> 16)));
    float2 f0, f1, f2, f3;
    f0 = __half22float2(*(const __half2*)&u0.x); f1 = __half22float2(*(const __half2*)&u0.y);
    f2 = __half22float2(*(const __half2*)&u0.z); f3 = __half22float2(*(const __half2*)&u0.w);
    acc[0] = fmaf(c0, f0.x, acc[0]); acc[1] = fmaf(c0, f0.y, acc[1]);
    acc[2] = fmaf(c0, f1.x, acc[2]); acc[3] = fmaf(c0, f1.y, acc[3]);
    acc[4] = fmaf(c0, f2.x, acc[4]); acc[5] = fmaf(c0, f2.y, acc[5]);
    acc[6] = fmaf(c0, f3.x, acc[6]); acc[7] = fmaf(c0, f3.y, acc[7]);
    f0 = __half22float2(*(const __half2*)&u1.x); f1 = __half22float2(*(const __half2*)&u1.y);
    f2 = __half22float2(*(const __half2*)&u1.z); f3 = __half22float2(*(const __half2*)&u1.w);
    acc[0] = fmaf(c1, f0.x, acc[0]); acc[1] = fmaf(c1, f0.y, acc[1]);
    acc[2] = fmaf(c1, f1.x, acc[2]); acc[3] = fmaf(c1, f1.y, acc[3]);
    acc[4] = fmaf(c1, f2.x, acc[4]); acc[5] = fmaf(c1, f2.y, acc[5]);
    acc[6] = fmaf(c1, f3.x, acc[6]); acc[7] = fmaf(c1, f3.y, acc[7]);
  }
  for (; e < n1; e += 4) {
    unsigned p0 = epair[e];
    uint4 u0 = xw4[(size_t)(p0 & 0xFFFFu) * 16 + l16];
    float c0 = __half2float(__builtin_bit_cast(__half, (unsigned short)(p0 >> 16)));
    float2 f0 = __half22float2(*(const __half2*)&u0.x);
    float2 f1 = __half22float2(*(const __half2*)&u0.y);
    float2 f2 = __half22float2(*(const __half2*)&u0.z);
    float2 f3 = __half22float2(*(const __half2*)&u0.w);
    acc[0] = fmaf(c0, f0.x, acc[0]); acc[1] = fmaf(c0, f0.y, acc[1]);
    acc[2] = fmaf(c0, f1.x, acc[2]); acc[3] = fmaf(c0, f1.y, acc[3]);
    acc[4] = fmaf(c0, f2.x, acc[4]); acc[5] = fmaf(c0, f2.y, acc[5]);
    acc[6] = fmaf(c0, f3.x, acc[6]); acc[7] = fmaf(c0, f3.y, acc[7]);
  }
#pragma unroll
  for (int j = 0; j < 8; ++j) {
    float a = acc[j];
    a += __shfl_xor(a, 16, 64);
    a += __shfl_xor(a, 32, 64);
    acc[j] = a;
  }
  if (q == 0) {
    __half2 h0 = __floats2half2_rn(fmaxf(acc[0], 0.f), fmaxf(acc[1], 0.f));
    __half2 h1 = __floats2half2_rn(fmaxf(acc[2], 0.f), fmaxf(acc[3], 0.f));
    __half2 h2 = __floats2half2_rn(fmaxf(acc[4], 0.f), fmaxf(acc[5], 0.f));
    __half2 h3 = __floats2half2_rn(fmaxf(acc[6], 0.f), fmaxf(acc[7], 0.f));
    uint4 o;
    o.x = *(unsigned*)&h0; o.y = *(unsigned*)&h1; o.z = *(unsigned*)&h2; o.w = *(unsigned*)&h3;
    *(uint4*)&hh[(size_t)w * 64 + l16 * 4] = o;
  }
}

// ---------- MFMA GEMM (generic): C[m][n] = sum_k A[m][k]*Bt[n][k] ----------
template <int HIN, int HOUT, int BIAS>
__global__ __launch_bounds__(256) void gemm_mfma_kernel(const void* __restrict__ Ap,
                                                        const float* __restrict__ Bt,
                                                        const float* __restrict__ bias,
                                                        void* __restrict__ Cp, int nrows) {
  __shared__ char ldsA[64 * 256];
  __shared__ char ldsB[128 * 256];
  const int t = threadIdx.x;
  const int row0 = blockIdx.x * 64;
  {
    const float2* B2 = (const float2*)Bt;
#pragma unroll
    for (int i = 0; i < 32; ++i) {
      int idx = i * 256 + t;
      int nn = idx >> 6, kp = idx & 63;
      float2 v = B2[idx];
      __half2 h = __floats2half2_rn(v.x, v.y);
      int byte = (nn * 256 + kp * 4) ^ ((nn & 7) << 4);
      *(unsigned*)&ldsB[byte] = *(unsigned*)&h;
    }
  }
  if (HIN) {
    const unsigned* Ah = (const unsigned*)Ap;
#pragma unroll
    for (int i = 0; i < 16; ++i) {
      int idx = i * 256 + t;
      int r = idx >> 6, cp = idx & 63;
      int gr = row0 + r;
      unsigned v = (gr < nrows) ? Ah[(size_t)gr * 64 + cp] : 0u;
      int byte = (r * 256 + cp * 4) ^ ((r & 7) << 4);
      *(unsigned*)&ldsA[byte] = v;
    }
  } else {
    const float2* A2 = (const float2*)Ap;
#pragma unroll
    for (int i = 0; i < 16; ++i) {
      int idx = i * 256 + t;
      int r = idx >> 6, cp = idx & 63;
      int gr = row0 + r;
      float2 v = make_float2(0.f, 0.f);
      if (gr < nrows) v = A2[(size_t)gr * 64 + cp];
      __half2 h = __floats2half2_rn(v.x, v.y);
      int byte = (r * 256 + cp * 4) ^ ((r & 7) << 4);
      *(unsigned*)&ldsA[byte] = *(unsigned*)&h;
    }
  }
  __syncthreads();
  const int wave = t >> 6, l = t & 63;
  const int wr0 = wave * 16;
  const int lm = l & 15, q = l >> 4;
  floatx4 acc[8];
#pragma unroll
  for (int nt = 0; nt < 8; ++nt) acc[nt] = (floatx4){0.f, 0.f, 0.f, 0.f};
#pragma unroll
  for (int ks = 0; ks < 4; ++ks) {
    int arow = wr0 + lm;
    half8 a = *(const half8*)&ldsA[(arow * 256 + ks * 64 + q * 16) ^ ((arow & 7) << 4)];
#pragma unroll
    for (int nt = 0; nt < 8; ++nt) {
      int nn = nt * 16 + lm;
      half8 b = *(const half8*)&ldsB[(nn * 256 + ks * 64 + q * 16) ^ ((nn & 7) << 4)];
      acc[nt] = __builtin_amdgcn_mfma_f32_16x16x32_f16(a, b, acc[nt], 0, 0, 0);
    }
  }
#pragma unroll
  for (int nt = 0; nt < 8; ++nt) {
    int col = nt * 16 + lm;
    float bv = BIAS ? bias[col] : 0.f;
#pragma unroll
    for (int r = 0; r < 4; ++r) {
      int gr = row0 + wr0 + q * 4 + r;
      if (gr < nrows) {
        float v = acc[nt][r] + bv;
        if (HOUT) ((__half*)Cp)[(size_t)gr * NF + col] = __float2half(v);
        else ((float*)Cp)[(size_t)gr * NF + col] = v;
      }
    }
  }
}

extern "C" void kernel_launch(void* const* d_in, const int* in_sizes, int n_in,
                              void* d_out, int out_size, void* d_ws, size_t ws_size,
                              hipStream_t stream) {
  const float* x = (const float*)d_in[0];
  const int* ei = (const int*)d_in[1];
  const float* ew = (const float*)d_in[2];
  const float* p = (const float*)d_in[3];
  const float* w_ih = (const float*)d_in[4];
  const float* w_hh = (const float*)d_in[5];
  const float* b_ih = (const float*)d_in[6];
  const float* b_hh = (const float*)d_in[7];
  const float* W0 = (const float*)d_in[8];
  const float* W_lin = (const float*)d_in[9];
  const float* b_lin = (const float*)d_in[10];
  float* out = (float*)d_out;

  const int N = in_sizes[0] / NF;  // 50000 (< 65536 required for 16-bit rows)
  const int E = in_sizes[1] / 2;   // 800000

  char* w = (char*)d_ws;
  unsigned* xwh = (unsigned*)w;                                 // N*64 (fp16 xw)
  unsigned* hh = xwh + (size_t)N * 64;                          // N*64 (fp16 relu(h))
  float* score = (float*)(hh + (size_t)N * 64);                 // N
  unsigned* keys = (unsigned*)(score + N);                      // N
  unsigned long long* cnt64 = (unsigned long long*)(keys + N);  // ZERO region: N x 8B
  unsigned* bins = (unsigned*)(cnt64 + N);                      // 65536
  int* ncnt = (int*)(bins + 65536);                             // 1 (end of ZERO region)
  float* dinv = (float*)(ncnt + 1);                             // N
  unsigned* thrB = (unsigned*)(dinv + N);                       // 1
  int* candIdx = (int*)(thrB + 1);                              // N
  int* offL = candIdx + N;                                      // N+1
  int* bsum = offL + N + 1;                                     // 64
  int* bexc = bsum + 64;                                        // 64
  unsigned short* eslot = (unsigned short*)(bexc + 64);         // E x 2B
  unsigned* epair = (unsigned*)(eslot + E);                     // E x 4B
  float* WevT = (float*)(epair + E);                            // 128*128
  int* perm = (int*)(WevT + NF * NF);                           // 128
  float* tsc = (float*)(perm + NF);                             // 128

  const int nb = (N + SCAN_B - 1) / SCAN_B;
  const int nbEdge = (E + 255) / 256;
  const int nbGemm = (N + 63) / 64;
  const int nbScore = (N + 63) / 64;
  const int nOwnC = (N + 1023) / 1024;

  // edge-slice partition: 45% rides with score, remaining 55% over 4 stages
  const int eA1 = (int)(((long long)E * 9) / 20);
  const int perR = (E - eA1 + 3) / 4;
  const int eB1 = (eA1 + perR < E) ? eA1 + perR : E;
  const int eC1 = (eB1 + perR < E) ? eB1 + perR : E;
  const int eD1 = (eC1 + perR < E) ? eC1 + perR : E;
  const int bSA = (eA1 + 255) / 256;
  const int bSB = (eB1 - eA1 + 1023) / 1024;
  const int bSC = (eC1 - eB1 + 1023) / 1024;
  const int bSD = (eD1 - eC1 + 1023) / 1024;
  const int bSE = (E - eD1 + 127) / 128;

  // zero region: cnt64 (N*8) + bins (256KB) + ncnt (4), padded to 16B
  const int n4zero = (N * 8 + 65536 * 4 + 4 + 15) / 16;

  zero_kernel<<<64, 1024, 0, stream>>>((uint4*)cnt64, n4zero);
  score_edge_kernel<<<nbScore + bSA, 256, 0, stream>>>(x, p, score, keys, bins, N, nbScore,
                                                       ei, ew, cnt64, eslot, E, 0, eA1);
  findbin_edge_kernel<<<1 + bSB, 1024, 0, stream>>>(bins, thrB, ei, ew, cnt64, eslot, E, eA1, eB1);
  compact_edge_kernel<<<nOwnC + bSC, 1024, 0, stream>>>(keys, thrB, ncnt, candIdx, N, nOwnC,
                                                        ei, ew, cnt64, eslot, E, eB1, eC1);
  select_edge_kernel<<<1 + bSD, 1024, 0, stream>>>(keys, candIdx, ncnt, score, perm, tsc,
                                                   ei, ew, cnt64, eslot, E, eC1, eD1);
  gru_edge_kernel<<<NF + bSE, NF, 0, stream>>>(x, perm, tsc, W0, w_ih, w_hh, b_ih, b_hh, WevT,
                                               ei, ew, cnt64, eslot, E, eD1, E);
  scan1_kernel<<<nb, SCAN_B, 0, stream>>>(cnt64, offL, bsum, dinv, N);
  scan2_kernel<<<1, 64, 0, stream>>>(bsum, bexc, nb);
  gemm1_fill_kernel<<<nbGemm + nbEdge, 256, 0, stream>>>(x, WevT, xwh, N, nbGemm,
                                                         ei, ew, dinv, offL, bexc, eslot, epair, E);
  aggregate_kernel<<<(N + 3) / 4, 256, 0, stream>>>(epair, offL, bexc, dinv,
                                                    (const uint4*)xwh, hh, N);
  gemm_mfma_kernel<1, 0, 1><<<nbGemm, 256, 0, stream>>>(hh, W_lin, b_lin, out, N);
}